// Round 1
// baseline (12694.550 us; speedup 1.0000x reference)
//
#include <hip/hip_runtime.h>
#include <cstddef>
#include <cstdint>

// ---------------------------------------------------------------------------
// SPN forward for MI355X. B=4, H=W=256, NF=32, all f32.
// ---------------------------------------------------------------------------

// ---------- conv 3x3 (pad 1), optional fused ELU + skip-add ----------
// MODE 0: out = conv+bias
// MODE 1: out = elu(conv+bias) + skip
template<int MODE>
__global__ __launch_bounds__(256) void k_conv3x3(
    const float* __restrict__ in, const float* __restrict__ wgt,
    const float* __restrict__ bias, const float* __restrict__ skip,
    float* __restrict__ out, int Cin, int Cout, int H, int W)
{
  int hw = blockIdx.x * 256 + threadIdx.x;
  if (hw >= H * W) return;
  int w = hw % W, h = hw / W;
  int co = blockIdx.y, b = blockIdx.z;

  const float* wp = wgt + (size_t)co * Cin * 9;
  const float* ip = in + (size_t)b * Cin * H * W;
  float acc = bias[co];
  bool wl = (w > 0), wr = (w < W - 1);

  for (int ci = 0; ci < Cin; ++ci) {
    const float* pl = ip + (size_t)ci * H * W;
    const float* wc = wp + ci * 9;
#pragma unroll
    for (int kh = 0; kh < 3; ++kh) {
      int hh = h + kh - 1;
      if ((unsigned)hh < (unsigned)H) {
        const float* r = pl + (size_t)hh * W;
        acc += wc[kh * 3 + 1] * r[w];
        if (wl) acc += wc[kh * 3 + 0] * r[w - 1];
        if (wr) acc += wc[kh * 3 + 2] * r[w + 1];
      }
    }
  }
  size_t oidx = (((size_t)b * Cout + co) * H + h) * W + w;
  if (MODE == 1) {
    float e = acc > 0.f ? acc : expm1f(acc);
    out[oidx] = e + skip[oidx];
  } else {
    out[oidx] = acc;
  }
}

// ---------- conv 1x1 ----------
__global__ __launch_bounds__(256) void k_conv1x1(
    const float* __restrict__ in, const float* __restrict__ wgt,
    const float* __restrict__ bias, float* __restrict__ out,
    int Cin, int Cout, int H, int W)
{
  int hw = blockIdx.x * 256 + threadIdx.x;
  if (hw >= H * W) return;
  int co = blockIdx.y, b = blockIdx.z;
  const float* ip = in + (size_t)b * Cin * H * W + hw;
  const float* wp = wgt + (size_t)co * Cin;
  float acc = bias[co];
  for (int ci = 0; ci < Cin; ++ci) acc += wp[ci] * ip[(size_t)ci * H * W];
  out[((size_t)b * Cout + co) * H * W + hw] = acc;
}

// ---------- relu + maxpool 3x3 stride 2 pad 1 ----------
__global__ __launch_bounds__(256) void k_pool(
    const float* __restrict__ in, float* __restrict__ out, int C, int H, int W)
{
  int Ho = H >> 1, Wo = W >> 1;
  int hw = blockIdx.x * 256 + threadIdx.x;
  if (hw >= Ho * Wo) return;
  int ow = hw % Wo, oh = hw / Wo;
  int c = blockIdx.y, b = blockIdx.z;
  const float* p = in + ((size_t)(b * C + c) * H) * W;
  float m = 0.f;  // relu(x) >= 0 and window always non-empty -> 0 is a valid identity
#pragma unroll
  for (int dh = -1; dh <= 1; ++dh) {
    int ih = 2 * oh + dh;
    if ((unsigned)ih >= (unsigned)H) continue;
    const float* r = p + (size_t)ih * W;
#pragma unroll
    for (int dw = -1; dw <= 1; ++dw) {
      int iw = 2 * ow + dw;
      if ((unsigned)iw >= (unsigned)W) continue;
      m = fmaxf(m, r[iw]);
    }
  }
  out[((size_t)(b * C + c) * Ho + oh) * Wo + ow] = m;
}

// ---------- bilinear 2x upsample (half-pixel centers, clamped) ----------
// jax.image.resize 'bilinear' at 2x: out[2i]=.25 in[i-1]+.75 in[i]; out[2i+1]=.75 in[i]+.25 in[i+1]
__global__ __launch_bounds__(256) void k_up2(
    const float* __restrict__ in, float* __restrict__ out, int C, int H, int W)
{
  int Ho = H * 2, Wo = W * 2;
  int hw = blockIdx.x * 256 + threadIdx.x;
  if (hw >= Ho * Wo) return;
  int ow = hw % Wo, oh = hw / Wo;
  int c = blockIdx.y, b = blockIdx.z;
  int ih = oh >> 1, iw = ow >> 1;
  int ih0, ih1, iw0, iw1; float fh0, fw0;
  if (oh & 1) { ih0 = ih; ih1 = min(ih + 1, H - 1); fh0 = 0.75f; }
  else        { ih0 = max(ih - 1, 0); ih1 = ih;     fh0 = 0.25f; }
  if (ow & 1) { iw0 = iw; iw1 = min(iw + 1, W - 1); fw0 = 0.75f; }
  else        { iw0 = max(iw - 1, 0); iw1 = iw;     fw0 = 0.25f; }
  const float* p = in + ((size_t)(b * C + c) * H) * W;
  float v = fh0 * (fw0 * p[(size_t)ih0 * W + iw0] + (1.f - fw0) * p[(size_t)ih0 * W + iw1])
          + (1.f - fh0) * (fw0 * p[(size_t)ih1 * W + iw0] + (1.f - fw0) * p[(size_t)ih1 * W + iw1]);
  out[((size_t)(b * C + c) * Ho + oh) * Wo + ow] = v;
}

// ---------- gated recurrent propagation (one direction) ----------
// HOR=1: scan over w (t), lane i = row. HOR=0: scan over h (t), lane i = col.
// G chunk layout: (B, 96, H, W); g1 = ch [0,32), g2 = [32,64), g3 = [64,96).
// FIRST=1: out = h; FIRST=0: out = fmax(out, h).
template<int HOR, int REV, int FIRST>
__global__ __launch_bounds__(256) void k_prop(
    const float* __restrict__ X, const float* __restrict__ G,
    float* __restrict__ out, int H, int W)
{
  int plane = blockIdx.x;            // b*32 + c
  int i = threadIdx.x;               // perpendicular index, 0..255
  int b = plane >> 5, c = plane & 31;
  size_t ps = (size_t)H * W;
  const float* xp = X + (size_t)plane * ps;
  const float* g1 = G + ((size_t)b * 96 + c) * ps;
  const float* g2 = g1 + (size_t)32 * ps;
  const float* g3 = g1 + (size_t)64 * ps;
  float* op = out + (size_t)plane * ps;

  __shared__ float sh[258];
  sh[i + 1] = 0.f;
  if (i == 0) { sh[0] = 0.f; sh[257] = 0.f; }
  __syncthreads();

  int N = HOR ? W : H;
  for (int s = 0; s < N; ++s) {
    int t = REV ? (N - 1 - s) : s;
    size_t idx = HOR ? ((size_t)i * W + t) : ((size_t)t * W + i);
    float a1 = g1[idx], a2 = g2[idx], a3 = g3[idx], xv = xp[idx];
    float ss = fabsf(a1) + fabsf(a2) + fabsf(a3);
    if (ss >= 1.f) { float r = 1.f / ss; a1 *= r; a2 *= r; a3 *= r; }
    float hn = (1.f - a1 - a2 - a3) * xv + a1 * sh[i] + a2 * sh[i + 1] + a3 * sh[i + 2];
    __syncthreads();
    sh[i + 1] = hn;
    __syncthreads();
    if (FIRST) op[idx] = hn;
    else       op[idx] = fmaxf(op[idx], hn);
  }
}

// ---------------------------------------------------------------------------
extern "C" void kernel_launch(void* const* d_in, const int* in_sizes, int n_in,
                              void* d_out, int out_size, void* d_ws, size_t ws_size,
                              hipStream_t stream)
{
  const float* x   = (const float*)d_in[0];
  const float* rgb = (const float*)d_in[1];
  const float* mw  = (const float*)d_in[2];
  const float* mb  = (const float*)d_in[3];
  const float* c1w = (const float*)d_in[4];
  const float* c1b = (const float*)d_in[5];
  const float* c2w = (const float*)d_in[6];
  const float* c2b = (const float*)d_in[7];
  const float* c3w = (const float*)d_in[8];
  const float* c3b = (const float*)d_in[9];
  const float* c4w = (const float*)d_in[10];
  const float* c4b = (const float*)d_in[11];
  const float* d0w = (const float*)d_in[12];
  const float* d0b = (const float*)d_in[13];
  const float* d2w = (const float*)d_in[14];
  const float* d2b = (const float*)d_in[15];
  const float* d4w = (const float*)d_in[16];
  const float* d4b = (const float*)d_in[17];
  const float* d6w = (const float*)d_in[18];
  const float* d6b = (const float*)d_in[19];
  const float* d7w = (const float*)d_in[20];
  const float* d7b = (const float*)d_in[21];
  const float* pw  = (const float*)d_in[22];
  const float* pb  = (const float*)d_in[23];

  char* ws = (char*)d_ws;
  const size_t MB = 1024 * 1024;
  // Buffer plan (peak 216 MiB, with reuse):
  float* X   = (float*)(ws + 0);        // (4,32,256,256)  32 MiB  [live till props done]
  float* f1  = (float*)(ws + 32 * MB);  // (4,32,256,256)  32 MiB  [till o3]
  float* f2  = (float*)(ws + 64 * MB);  // (4,64,128,128)  16 MiB  [till o2]
  float* f3  = (float*)(ws + 80 * MB);  // (4,128,64,64)    8 MiB  [till o1]
  float* p1  = (float*)(ws + 88 * MB);  // (4,32,128,128)   8 MiB
  float* p2  = (float*)(ws + 96 * MB);  // (4,64,64,64)     4 MiB
  float* p3  = (float*)(ws + 100 * MB); // (4,128,32,32)    2 MiB
  float* f4  = (float*)(ws + 102 * MB); // (4,256,32,32)    4 MiB
  float* o0  = (float*)(ws + 106 * MB); // (4,128,32,32)    2 MiB
  float* u0  = (float*)(ws + 108 * MB); // (4,128,64,64)    8 MiB
  float* o1  = (float*)(ws + 116 * MB); // (4,128,64,64)    8 MiB
  float* u1  = (float*)(ws + 124 * MB); // (4,128,128,128) 32 MiB
  float* o2  = (float*)(ws + 156 * MB); // (4,64,128,128)  16 MiB
  float* u2  = (float*)(ws + 88 * MB);  // (4,64,256,256)  64 MiB  [reuse: p1..u1 dead]
  float* o3  = (float*)(ws + 184 * MB); // (4,32,256,256)  32 MiB
  float* gch = (float*)(ws + 88 * MB);  // (4,96,256,256)  96 MiB  [reuse: u2,o2 dead]
  float* om  = (float*)(ws + 32 * MB);  // (4,32,256,256)  32 MiB  [reuse: f1 dead]

  dim3 blk(256);

  // Encoder
  k_conv3x3<0><<<dim3(256, 32, 4), blk, 0, stream>>>(x,   mw,  mb,  nullptr, X,  3,   32,  256, 256);
  k_conv3x3<0><<<dim3(256, 32, 4), blk, 0, stream>>>(rgb, c1w, c1b, nullptr, f1, 3,   32,  256, 256);
  k_pool   <<<dim3(64, 32, 4),  blk, 0, stream>>>(f1, p1, 32, 256, 256);
  k_conv3x3<0><<<dim3(64, 64, 4),  blk, 0, stream>>>(p1, c2w, c2b, nullptr, f2, 32,  64,  128, 128);
  k_pool   <<<dim3(16, 64, 4),  blk, 0, stream>>>(f2, p2, 64, 128, 128);
  k_conv3x3<0><<<dim3(16, 128, 4), blk, 0, stream>>>(p2, c3w, c3b, nullptr, f3, 64,  128, 64,  64);
  k_pool   <<<dim3(4, 128, 4),  blk, 0, stream>>>(f3, p3, 128, 64, 64);
  k_conv3x3<0><<<dim3(4, 256, 4),  blk, 0, stream>>>(p3, c4w, c4b, nullptr, f4, 128, 256, 32,  32);
  k_conv1x1<<<dim3(4, 128, 4),  blk, 0, stream>>>(f4, d0w, d0b, o0, 256, 128, 32, 32);

  // Decoder (up2 -> conv -> elu -> +skip)
  k_up2    <<<dim3(16, 128, 4), blk, 0, stream>>>(o0, u0, 128, 32, 32);
  k_conv3x3<1><<<dim3(16, 128, 4), blk, 0, stream>>>(u0, d2w, d2b, f3, o1, 128, 128, 64, 64);
  k_up2    <<<dim3(64, 128, 4), blk, 0, stream>>>(o1, u1, 128, 64, 64);
  k_conv3x3<1><<<dim3(64, 64, 4),  blk, 0, stream>>>(u1, d4w, d4b, f2, o2, 128, 64, 128, 128);
  k_up2    <<<dim3(256, 64, 4), blk, 0, stream>>>(o2, u2, 64, 128, 128);
  k_conv3x3<1><<<dim3(256, 32, 4), blk, 0, stream>>>(u2, d6w, d6b, f1, o3, 64, 32, 256, 256);

  // Guide conv in 4 chunks of 96 channels, each feeding one direction's scan.
  // dirs: k=0 (hor,fwd), k=1 (hor,rev), k=2 (vert,fwd), k=3 (vert,rev)
  for (int k = 0; k < 4; ++k) {
    k_conv3x3<0><<<dim3(256, 96, 4), blk, 0, stream>>>(
        o3, d7w + (size_t)k * 96 * 32 * 9, d7b + k * 96, nullptr, gch, 32, 96, 256, 256);
    switch (k) {
      case 0: k_prop<1, 0, 1><<<dim3(128), blk, 0, stream>>>(X, gch, om, 256, 256); break;
      case 1: k_prop<1, 1, 0><<<dim3(128), blk, 0, stream>>>(X, gch, om, 256, 256); break;
      case 2: k_prop<0, 0, 0><<<dim3(128), blk, 0, stream>>>(X, gch, om, 256, 256); break;
      case 3: k_prop<0, 1, 0><<<dim3(128), blk, 0, stream>>>(X, gch, om, 256, 256); break;
    }
  }

  // Final conv
  k_conv3x3<0><<<dim3(256, 3, 4), blk, 0, stream>>>(om, pw, pb, nullptr, (float*)d_out, 32, 3, 256, 256);
}

// Round 3
// 4279.491 us; speedup vs baseline: 2.9664x; 2.9664x over previous
//
#include <hip/hip_runtime.h>
#include <cstddef>
#include <cstdint>

#define DEVINL __device__ __forceinline__

// ---------------------------------------------------------------------------
// SPN forward, MI355X gfx950. B=4, H=W=256, NF=32, f32.
// Round 3: fused-up2 tiled convs, transposed-gate scans, peak ws = 199 MiB.
// ---------------------------------------------------------------------------

// ---------- weight repack: OIHW -> [ci*9+k][Cout] ----------
__global__ __launch_bounds__(256) void k_repack(
    const float* __restrict__ src, float* __restrict__ dst, int Cin, int Cout)
{
  int n = Cout * Cin * 9;
  int e = blockIdx.x * 256 + threadIdx.x;
  if (e >= n) return;
  int co = e / (Cin * 9);
  int r  = e - co * Cin * 9;
  int ci = r / 9;
  int k  = r - ci * 9;
  dst[(ci * 9 + k) * Cout + co] = src[e];
}

// ---------- staged input sample (optionally through bilinear up2) ----------
// H,W are the conv-space (output-grid) dims. UP=1: input plane is H/2 x W/2.
template<int UP>
DEVINL float ld_in(const float* __restrict__ pl, int gh, int gw, int H, int W)
{
  if ((unsigned)gh >= (unsigned)H || (unsigned)gw >= (unsigned)W) return 0.f;
  if (UP == 0) return pl[(size_t)gh * W + gw];
  int Hi = H >> 1, Wi = W >> 1;
  int kh = gh >> 1, kw = gw >> 1;
  int ih0, ih1, iw0, iw1; float fh0, fw0;
  if (gh & 1) { ih0 = kh; ih1 = min(kh + 1, Hi - 1); fh0 = 0.75f; }
  else        { ih0 = max(kh - 1, 0); ih1 = kh;      fh0 = 0.25f; }
  if (gw & 1) { iw0 = kw; iw1 = min(kw + 1, Wi - 1); fw0 = 0.75f; }
  else        { iw0 = max(kw - 1, 0); iw1 = kw;      fw0 = 0.25f; }
  return fh0 * (fw0 * pl[(size_t)ih0 * Wi + iw0] + (1.f - fw0) * pl[(size_t)ih0 * Wi + iw1])
       + (1.f - fh0) * (fw0 * pl[(size_t)ih1 * Wi + iw0] + (1.f - fw0) * pl[(size_t)ih1 * Wi + iw1]);
}

// ---------- tiled conv 3x3 (pad 1), 16x16 spatial tile, CO channels/thread ----
// MODE 0: out = conv+bias (NCHW)
// MODE 1: out = elu(conv+bias) + skip (NCHW)
// MODE 2: out = conv+bias, stored TRANSPOSED per plane: out[ch][w][h]
// UP 1  : input is half-res; bilinear up2 fused into staging.
// wr layout: [ci*9+k][wstride], channel base = wco0 + blockIdx.y*CO.
template<int CI, int CO, int MODE, int UP>
__global__ __launch_bounds__(256) void k_conv3x3t(
    const float* __restrict__ in, const float* __restrict__ wr,
    const float* __restrict__ bias, const float* __restrict__ skip,
    float* __restrict__ out,
    int Cin, int H, int W, int wstride, int wco0, int outC, int oco0base)
{
  const int ntx = W >> 4;
  const int tid = threadIdx.x;
  const int tx = tid & 15, ty = tid >> 4;
  const int tile = blockIdx.x;
  const int tx0 = (tile % ntx) << 4, ty0 = (tile / ntx) << 4;
  const int b = blockIdx.z;
  const int wbase = wco0 + blockIdx.y * CO;
  const int oco0 = oco0base + blockIdx.y * CO;
  const int ips = UP ? ((H >> 1) * (W >> 1)) : (H * W);

  __shared__ float sh[CI * 324];  // CI x 18 x 18

  float acc[CO];
#pragma unroll
  for (int co = 0; co < CO; ++co) acc[co] = bias[wbase + co];

  const float* inb = in + (size_t)b * Cin * ips;

  for (int cb = 0; cb < Cin; cb += CI) {
    __syncthreads();
    for (int e = tid; e < CI * 324; e += 256) {
      int ci = e / 324;
      int rr = e - ci * 324;
      int r = rr / 18;
      int c = rr - r * 18;
      sh[e] = ld_in<UP>(inb + (size_t)(cb + ci) * ips, ty0 + r - 1, tx0 + c - 1, H, W);
    }
    __syncthreads();
#pragma unroll 1
    for (int ci = 0; ci < CI; ++ci) {
      float v[9];
      const float* sp = sh + ci * 324 + ty * 18 + tx;
#pragma unroll
      for (int kh = 0; kh < 3; ++kh)
#pragma unroll
        for (int kw = 0; kw < 3; ++kw)
          v[kh * 3 + kw] = sp[kh * 18 + kw];
      const float* wp = wr + (size_t)((cb + ci) * 9) * wstride + wbase;
#pragma unroll
      for (int k = 0; k < 9; ++k) {
#pragma unroll
        for (int co = 0; co < CO; ++co)
          acc[co] = fmaf(wp[(size_t)k * wstride + co], v[k], acc[co]);
      }
    }
  }

  if (MODE == 2) {
    // transposed store via LDS, 4 channels at a time, coalesced along h
#pragma unroll 1
    for (int cog = 0; cog < CO; cog += 4) {
      __syncthreads();
#pragma unroll
      for (int j = 0; j < 4; ++j)
        sh[j * 272 + tx * 17 + ty] = acc[cog + j];
      __syncthreads();
#pragma unroll
      for (int j = 0; j < 4; ++j) {
        size_t oidx = ((size_t)(b * outC + oco0 + cog + j) * W + (tx0 + ty)) * (size_t)H
                    + (ty0 + tx);
        out[oidx] = sh[j * 272 + ty * 17 + tx];
      }
    }
  } else {
#pragma unroll
    for (int co = 0; co < CO; ++co) {
      size_t oidx = ((size_t)(b * outC + oco0 + co) * H + (ty0 + ty)) * W + (tx0 + tx);
      float a = acc[co];
      if (MODE == 1) {
        float e = a > 0.f ? a : expm1f(a);
        out[oidx] = e + skip[oidx];
      } else {
        out[oidx] = a;
      }
    }
  }
}

// ---------- conv 1x1 ----------
__global__ __launch_bounds__(256) void k_conv1x1(
    const float* __restrict__ in, const float* __restrict__ wgt,
    const float* __restrict__ bias, float* __restrict__ out,
    int Cin, int Cout, int H, int W)
{
  int hw = blockIdx.x * 256 + threadIdx.x;
  if (hw >= H * W) return;
  int co = blockIdx.y, b = blockIdx.z;
  const float* ip = in + (size_t)b * Cin * H * W + hw;
  const float* wp = wgt + (size_t)co * Cin;
  float acc = bias[co];
  for (int ci = 0; ci < Cin; ++ci) acc += wp[ci] * ip[(size_t)ci * H * W];
  out[((size_t)b * Cout + co) * H * W + hw] = acc;
}

// ---------- relu + maxpool 3x3 stride 2 pad 1 ----------
__global__ __launch_bounds__(256) void k_pool(
    const float* __restrict__ in, float* __restrict__ out, int C, int H, int W)
{
  int Ho = H >> 1, Wo = W >> 1;
  int hw = blockIdx.x * 256 + threadIdx.x;
  if (hw >= Ho * Wo) return;
  int ow = hw % Wo, oh = hw / Wo;
  int c = blockIdx.y, b = blockIdx.z;
  const float* p = in + ((size_t)(b * C + c) * H) * W;
  float m = 0.f;  // relu >= 0 makes 0 a valid identity
#pragma unroll
  for (int dh = -1; dh <= 1; ++dh) {
    int ih = 2 * oh + dh;
    if ((unsigned)ih >= (unsigned)H) continue;
    const float* r = p + (size_t)ih * W;
#pragma unroll
    for (int dw = -1; dw <= 1; ++dw) {
      int iw = 2 * ow + dw;
      if ((unsigned)iw >= (unsigned)W) continue;
      m = fmaxf(m, r[iw]);
    }
  }
  out[((size_t)(b * C + c) * Ho + oh) * Wo + ow] = m;
}

// ---------- gated scan helpers ----------
DEVINL void gl_lds16(const float* g, float* lds) {
  __builtin_amdgcn_global_load_lds(
      (const __attribute__((address_space(1))) unsigned int*)g,
      (__attribute__((address_space(3))) unsigned int*)lds, 16, 0, 0);
}

DEVINL float prop_step(float xv, float a1, float a2, float a3,
                       float hu, float hc, float hd) {
  float ss = fabsf(a1) + fabsf(a2) + fabsf(a3);
  if (ss >= 1.f) { float r = 1.f / ss; a1 *= r; a2 *= r; a3 *= r; }
  return (1.f - a1 - a2 - a3) * xv + a1 * hu + a2 * hc + a3 * hd;
}

// ---------- vertical scan (scan axis = h). X, G, out all natural NCHW. ----------
// G chunk (B,96,H,W): g1 = plane c, g2 = c+32, g3 = c+64. 1 wave/block, 1 plane/block.
template<int REV, int FIRST>
__global__ __launch_bounds__(64) void k_propv(
    const float* __restrict__ X, const float* __restrict__ G,
    float* __restrict__ out, int S, int P)
{
  const int plane = blockIdx.x;             // b*32 + c
  const int b = plane >> 5, c = plane & 31;
  const int lane = threadIdx.x;
  const size_t ps = (size_t)S * P;
  const float* xp = X + (size_t)plane * ps;
  const float* g1 = G + ((size_t)b * 96 + c) * ps;
  const float* g2 = g1 + (size_t)32 * ps;
  const float* g3 = g1 + (size_t)64 * ps;
  float* op = out + (size_t)plane * ps;

  __shared__ __align__(16) float bx[2][4096];
  __shared__ __align__(16) float b1[2][4096];
  __shared__ __align__(16) float b2[2][4096];
  __shared__ __align__(16) float b3[2][4096];
  __shared__ __align__(16) float bo[4096];

  float h0 = 0.f, h1 = 0.f, h2 = 0.f, h3 = 0.f;
  int cur = 0;

  auto stage = [&](int buf, int t0) {
#pragma unroll
    for (int u = 0; u < 16; ++u) {
      int s = REV ? (S - 1 - (t0 + u)) : (t0 + u);
      size_t ro = (size_t)s * P + lane * 4;
      gl_lds16(xp + ro, &bx[buf][u * 256]);
      gl_lds16(g1 + ro, &b1[buf][u * 256]);
      gl_lds16(g2 + ro, &b2[buf][u * 256]);
      gl_lds16(g3 + ro, &b3[buf][u * 256]);
    }
  };

  stage(0, 0);
  const int NT = S / 16;
  for (int t = 0; t < NT; ++t) {
    asm volatile("s_waitcnt vmcnt(0)" ::: "memory");
    if (t + 1 < NT) stage(cur ^ 1, (t + 1) * 16);

    for (int u = 0; u < 16; ++u) {
      const float* px = &bx[cur][u * 256];
      const float* p1 = &b1[cur][u * 256];
      const float* p2 = &b2[cur][u * 256];
      const float* p3 = &b3[cur][u * 256];
      float x0 = px[lane], x1 = px[lane + 64], x2 = px[lane + 128], x3 = px[lane + 192];
      float a10 = p1[lane], a11 = p1[lane + 64], a12 = p1[lane + 128], a13 = p1[lane + 192];
      float a20 = p2[lane], a21 = p2[lane + 64], a22 = p2[lane + 128], a23 = p2[lane + 192];
      float a30 = p3[lane], a31 = p3[lane + 64], a32 = p3[lane + 128], a33 = p3[lane + 192];

      float su0 = __shfl_up(h0, 1), su1 = __shfl_up(h1, 1);
      float su2 = __shfl_up(h2, 1), su3 = __shfl_up(h3, 1);
      float sd0 = __shfl_down(h0, 1), sd1 = __shfl_down(h1, 1);
      float sd2 = __shfl_down(h2, 1), sd3 = __shfl_down(h3, 1);
      float t63_0 = __shfl(h0, 63), t63_1 = __shfl(h1, 63), t63_2 = __shfl(h2, 63);
      float t0_1 = __shfl(h1, 0), t0_2 = __shfl(h2, 0), t0_3 = __shfl(h3, 0);

      float hu0 = lane ? su0 : 0.f;
      float hu1 = lane ? su1 : t63_0;
      float hu2 = lane ? su2 : t63_1;
      float hu3 = lane ? su3 : t63_2;
      float hd0 = (lane < 63) ? sd0 : t0_1;
      float hd1 = (lane < 63) ? sd1 : t0_2;
      float hd2 = (lane < 63) ? sd2 : t0_3;
      float hd3 = (lane < 63) ? sd3 : 0.f;

      h0 = prop_step(x0, a10, a20, a30, hu0, h0, hd0);
      h1 = prop_step(x1, a11, a21, a31, hu1, h1, hd1);
      h2 = prop_step(x2, a12, a22, a32, hu2, h2, hd2);
      h3 = prop_step(x3, a13, a23, a33, hu3, h3, hd3);

      float* po = &bo[u * 256];
      po[lane] = h0; po[lane + 64] = h1; po[lane + 128] = h2; po[lane + 192] = h3;
    }

    for (int u = 0; u < 16; ++u) {
      int s = REV ? (S - 1 - (t * 16 + u)) : (t * 16 + u);
      float4 v = *(const float4*)&bo[u * 256 + lane * 4];
      float4* dst = (float4*)(op + (size_t)s * P + lane * 4);
      if (FIRST) {
        *dst = v;
      } else {
        float4 o = *dst;
        o.x = fmaxf(o.x, v.x); o.y = fmaxf(o.y, v.y);
        o.z = fmaxf(o.z, v.z); o.w = fmaxf(o.w, v.w);
        *dst = o;
      }
    }
    cur ^= 1;
  }
}

// ---------- horizontal scan (scan axis = w). ----------
// X, out natural NCHW [p][s]; G TRANSPOSED per plane [s][p] (from MODE-2 conv).
// Output fmax-RMW (vertical scans ran first). 1 wave/block, 1 plane/block.
template<int REV>
__global__ __launch_bounds__(64) void k_proph(
    const float* __restrict__ X, const float* __restrict__ G,
    float* __restrict__ out, int S, int P)
{
  const int plane = blockIdx.x;
  const int b = plane >> 5, c = plane & 31;
  const int lane = threadIdx.x;
  const size_t ps = (size_t)S * P;
  const float* xp = X + (size_t)plane * ps;
  const float* g1 = G + ((size_t)b * 96 + c) * ps;
  const float* g2 = g1 + (size_t)32 * ps;
  const float* g3 = g1 + (size_t)64 * ps;
  float* op = out + (size_t)plane * ps;

  __shared__ __align__(16) float b1[2][4096];
  __shared__ __align__(16) float b2[2][4096];
  __shared__ __align__(16) float b3[2][4096];

  float h0 = 0.f, h1 = 0.f, h2 = 0.f, h3 = 0.f;
  int cur = 0;

  auto stage = [&](int buf, int t0) {
#pragma unroll
    for (int u = 0; u < 16; ++u) {
      int s = REV ? (S - 1 - (t0 + u)) : (t0 + u);
      size_t ro = (size_t)s * P + lane * 4;
      gl_lds16(g1 + ro, &b1[buf][u * 256]);
      gl_lds16(g2 + ro, &b2[buf][u * 256]);
      gl_lds16(g3 + ro, &b3[buf][u * 256]);
    }
  };

  stage(0, 0);
  const int NT = S / 16;
  for (int t = 0; t < NT; ++t) {
    const int s0 = REV ? (S - 16 - t * 16) : (t * 16);  // ascending-16 window

    asm volatile("s_waitcnt vmcnt(0)" ::: "memory");
    if (t + 1 < NT) stage(cur ^ 1, (t + 1) * 16);

    // X rows for this tile: per q, 16 consecutive floats [s0, s0+16)
    float xv[4][16];
#pragma unroll
    for (int q = 0; q < 4; ++q) {
      const float* row = xp + (size_t)(lane + 64 * q) * S + s0;
#pragma unroll
      for (int j = 0; j < 4; ++j) {
        float4 v = *(const float4*)(row + 4 * j);
        xv[q][4 * j + 0] = v.x; xv[q][4 * j + 1] = v.y;
        xv[q][4 * j + 2] = v.z; xv[q][4 * j + 3] = v.w;
      }
    }

    float vo[4][16];
#pragma unroll
    for (int u = 0; u < 16; ++u) {
      const int e = REV ? (15 - u) : u;  // position of step u within window
      const float* p1 = &b1[cur][u * 256];
      const float* p2 = &b2[cur][u * 256];
      const float* p3 = &b3[cur][u * 256];
      float a10 = p1[lane], a11 = p1[lane + 64], a12 = p1[lane + 128], a13 = p1[lane + 192];
      float a20 = p2[lane], a21 = p2[lane + 64], a22 = p2[lane + 128], a23 = p2[lane + 192];
      float a30 = p3[lane], a31 = p3[lane + 64], a32 = p3[lane + 128], a33 = p3[lane + 192];

      float su0 = __shfl_up(h0, 1), su1 = __shfl_up(h1, 1);
      float su2 = __shfl_up(h2, 1), su3 = __shfl_up(h3, 1);
      float sd0 = __shfl_down(h0, 1), sd1 = __shfl_down(h1, 1);
      float sd2 = __shfl_down(h2, 1), sd3 = __shfl_down(h3, 1);
      float t63_0 = __shfl(h0, 63), t63_1 = __shfl(h1, 63), t63_2 = __shfl(h2, 63);
      float t0_1 = __shfl(h1, 0), t0_2 = __shfl(h2, 0), t0_3 = __shfl(h3, 0);

      float hu0 = lane ? su0 : 0.f;
      float hu1 = lane ? su1 : t63_0;
      float hu2 = lane ? su2 : t63_1;
      float hu3 = lane ? su3 : t63_2;
      float hd0 = (lane < 63) ? sd0 : t0_1;
      float hd1 = (lane < 63) ? sd1 : t0_2;
      float hd2 = (lane < 63) ? sd2 : t0_3;
      float hd3 = (lane < 63) ? sd3 : 0.f;

      h0 = prop_step(xv[0][e], a10, a20, a30, hu0, h0, hd0);
      h1 = prop_step(xv[1][e], a11, a21, a31, hu1, h1, hd1);
      h2 = prop_step(xv[2][e], a12, a22, a32, hu2, h2, hd2);
      h3 = prop_step(xv[3][e], a13, a23, a33, hu3, h3, hd3);

      vo[0][e] = h0; vo[1][e] = h1; vo[2][e] = h2; vo[3][e] = h3;
    }

    // transposed fmax-RMW writes: per row p, 16 consecutive floats
#pragma unroll
    for (int q = 0; q < 4; ++q) {
      float* row = op + (size_t)(lane + 64 * q) * S + s0;
#pragma unroll
      for (int j = 0; j < 4; ++j) {
        float4 o = *(const float4*)(row + 4 * j);
        o.x = fmaxf(o.x, vo[q][4 * j + 0]);
        o.y = fmaxf(o.y, vo[q][4 * j + 1]);
        o.z = fmaxf(o.z, vo[q][4 * j + 2]);
        o.w = fmaxf(o.w, vo[q][4 * j + 3]);
        *(float4*)(row + 4 * j) = o;
      }
    }
    cur ^= 1;
  }
}

// ---------------------------------------------------------------------------
extern "C" void kernel_launch(void* const* d_in, const int* in_sizes, int n_in,
                              void* d_out, int out_size, void* d_ws, size_t ws_size,
                              hipStream_t stream)
{
  const float* x   = (const float*)d_in[0];
  const float* rgb = (const float*)d_in[1];
  const float* mw  = (const float*)d_in[2];
  const float* mb  = (const float*)d_in[3];
  const float* c1w = (const float*)d_in[4];
  const float* c1b = (const float*)d_in[5];
  const float* c2w = (const float*)d_in[6];
  const float* c2b = (const float*)d_in[7];
  const float* c3w = (const float*)d_in[8];
  const float* c3b = (const float*)d_in[9];
  const float* c4w = (const float*)d_in[10];
  const float* c4b = (const float*)d_in[11];
  const float* d0w = (const float*)d_in[12];
  const float* d0b = (const float*)d_in[13];
  const float* d2w = (const float*)d_in[14];
  const float* d2b = (const float*)d_in[15];
  const float* d4w = (const float*)d_in[16];
  const float* d4b = (const float*)d_in[17];
  const float* d6w = (const float*)d_in[18];
  const float* d6b = (const float*)d_in[19];
  const float* d7w = (const float*)d_in[20];
  const float* d7b = (const float*)d_in[21];
  const float* pw  = (const float*)d_in[22];
  const float* pb  = (const float*)d_in[23];

  char* ws = (char*)d_ws;
  const size_t MB = 1024 * 1024;
  // Layout (peak 199 MiB; round-1 proved ws >= 216 MiB):
  float* X    = (float*)(ws + 0);         // (4,32,256,256)  0-32
  float* f1   = (float*)(ws + 32 * MB);   // (4,32,256,256)  32-64
  float* f2   = (float*)(ws + 64 * MB);   // (4,64,128,128)  64-80
  float* f3   = (float*)(ws + 80 * MB);   // (4,128,64,64)   80-88
  float* p1   = (float*)(ws + 88 * MB);   // (4,32,128,128)  88-96
  float* p2   = (float*)(ws + 96 * MB);   // (4,64,64,64)    96-100
  float* p3   = (float*)(ws + 100 * MB);  // (4,128,32,32)   100-102
  float* f4   = (float*)(ws + 102 * MB);  // (4,256,32,32)   102-106
  float* o0   = (float*)(ws + 106 * MB);  // (4,128,32,32)   106-108
  float* o1   = (float*)(ws + 108 * MB);  // (4,128,64,64)   108-116
  float* o2   = (float*)(ws + 116 * MB);  // (4,64,128,128)  116-132
  float* o3   = (float*)(ws + 132 * MB);  // (4,32,256,256)  132-164
  float* gbuf = (float*)(ws + 32 * MB);   // (4,96,256,256)  32-128 [f1..o2 dead]
  float* om   = (float*)(ws + 164 * MB);  // (4,32,256,256)  164-196
  float* wrep = (float*)(ws + 196 * MB);  // repacked weights ~2.9 MB
  float* wm  = wrep;
  float* wc1 = wm  + 864;
  float* wc2 = wc1 + 864;
  float* wc3 = wc2 + 18432;
  float* wc4 = wc3 + 73728;
  float* wd2 = wc4 + 294912;
  float* wd4 = wd2 + 147456;
  float* wd6 = wd4 + 73728;
  float* wd7 = wd6 + 18432;
  float* wpk = wd7 + 110592;

  dim3 blk(256);
  auto rep = [&](const float* s, float* d, int ci, int co) {
    int n = co * ci * 9;
    k_repack<<<dim3((n + 255) / 256), blk, 0, stream>>>(s, d, ci, co);
  };
  rep(mw, wm, 3, 32);      rep(c1w, wc1, 3, 32);
  rep(c2w, wc2, 32, 64);   rep(c3w, wc3, 64, 128);
  rep(c4w, wc4, 128, 256);
  rep(d2w, wd2, 128, 128); rep(d4w, wd4, 128, 64);
  rep(d6w, wd6, 64, 32);   rep(d7w, wd7, 32, 384);
  rep(pw, wpk, 32, 3);

  // X = conv(x)
  k_conv3x3t<3, 32, 0, 0><<<dim3(256, 1, 4), blk, 0, stream>>>(x, wm, mb, nullptr, X, 3, 256, 256, 32, 0, 32, 0);

  // Encoder
  k_conv3x3t<3, 32, 0, 0><<<dim3(256, 1, 4), blk, 0, stream>>>(rgb, wc1, c1b, nullptr, f1, 3, 256, 256, 32, 0, 32, 0);
  k_pool<<<dim3(64, 32, 4), blk, 0, stream>>>(f1, p1, 32, 256, 256);
  k_conv3x3t<32, 64, 0, 0><<<dim3(64, 1, 4), blk, 0, stream>>>(p1, wc2, c2b, nullptr, f2, 32, 128, 128, 64, 0, 64, 0);
  k_pool<<<dim3(16, 64, 4), blk, 0, stream>>>(f2, p2, 64, 128, 128);
  k_conv3x3t<32, 64, 0, 0><<<dim3(16, 2, 4), blk, 0, stream>>>(p2, wc3, c3b, nullptr, f3, 64, 64, 64, 128, 0, 128, 0);
  k_pool<<<dim3(4, 128, 4), blk, 0, stream>>>(f3, p3, 128, 64, 64);
  k_conv3x3t<32, 64, 0, 0><<<dim3(4, 4, 4), blk, 0, stream>>>(p3, wc4, c4b, nullptr, f4, 128, 32, 32, 256, 0, 256, 0);
  k_conv1x1<<<dim3(4, 128, 4), blk, 0, stream>>>(f4, d0w, d0b, o0, 256, 128, 32, 32);

  // Decoder (up2 fused into conv staging)
  k_conv3x3t<32, 64, 1, 1><<<dim3(16, 2, 4), blk, 0, stream>>>(o0, wd2, d2b, f3, o1, 128, 64, 64, 128, 0, 128, 0);
  k_conv3x3t<32, 64, 1, 1><<<dim3(64, 1, 4), blk, 0, stream>>>(o1, wd4, d4b, f2, o2, 128, 128, 128, 64, 0, 64, 0);
  k_conv3x3t<32, 32, 1, 1><<<dim3(256, 1, 4), blk, 0, stream>>>(o2, wd6, d6b, f1, o3, 64, 256, 256, 32, 0, 32, 0);

  // Guide conv chunks + scans.
  // dirs: k=0 (hor,fwd), k=1 (hor,rev), k=2 (vert,fwd), k=3 (vert,rev).
  // Vertical first (om FIRST), then horizontal (transposed gates, fmax-RMW).
  k_conv3x3t<32, 48, 0, 0><<<dim3(256, 2, 4), blk, 0, stream>>>(o3, wd7, d7b, nullptr, gbuf, 32, 256, 256, 384, 192, 96, 0);
  k_propv<0, 1><<<dim3(128), dim3(64), 0, stream>>>(X, gbuf, om, 256, 256);
  k_conv3x3t<32, 48, 0, 0><<<dim3(256, 2, 4), blk, 0, stream>>>(o3, wd7, d7b, nullptr, gbuf, 32, 256, 256, 384, 288, 96, 0);
  k_propv<1, 0><<<dim3(128), dim3(64), 0, stream>>>(X, gbuf, om, 256, 256);
  k_conv3x3t<32, 48, 2, 0><<<dim3(256, 2, 4), blk, 0, stream>>>(o3, wd7, d7b, nullptr, gbuf, 32, 256, 256, 384, 0, 96, 0);
  k_proph<0><<<dim3(128), dim3(64), 0, stream>>>(X, gbuf, om, 256, 256);
  k_conv3x3t<32, 48, 2, 0><<<dim3(256, 2, 4), blk, 0, stream>>>(o3, wd7, d7b, nullptr, gbuf, 32, 256, 256, 384, 96, 96, 0);
  k_proph<1><<<dim3(128), dim3(64), 0, stream>>>(X, gbuf, om, 256, 256);

  // Final conv
  k_conv3x3t<32, 3, 0, 0><<<dim3(256, 1, 4), blk, 0, stream>>>(om, wpk, pb, nullptr, (float*)d_out, 32, 256, 256, 3, 0, 3, 0);
}

// Round 5
// 2387.469 us; speedup vs baseline: 5.3172x; 1.7925x over previous
//
#include <hip/hip_runtime.h>
#include <cstddef>
#include <cstdint>

#define DEVINL __device__ __forceinline__

typedef __attribute__((ext_vector_type(8))) short short8v;
typedef __attribute__((ext_vector_type(16))) float f32x16;

// ---------------------------------------------------------------------------
// SPN forward, MI355X gfx950. B=4, H=W=256, NF=32.
// Round 5: split-bf16 (bf16x3) MFMA implicit-GEMM for Cin>=32 3x3 convs.
//   a*b ~= ah*bh + al*bh + ah*bl  (al*bl ~ 2^-17 dropped) -> ~f32 precision.
// ---------------------------------------------------------------------------

DEVINL unsigned bf16b(float f) {  // f32 -> bf16 bits, RNE
  union { float f; unsigned u; } x; x.f = f;
  unsigned r = x.u + 0x7FFF + ((x.u >> 16) & 1);
  return r >> 16;
}
DEVINL float bf16f(unsigned bits) {
  union { float f; unsigned u; } x; x.u = bits << 16; return x.f;
}

// ---------- f32 weight repack: OIHW -> [ci*9+k][Cout] (small convs) ----------
__global__ __launch_bounds__(256) void k_repack(
    const float* __restrict__ src, float* __restrict__ dst, int Cin, int Cout)
{
  int n = Cout * Cin * 9;
  int e = blockIdx.x * 256 + threadIdx.x;
  if (e >= n) return;
  int co = e / (Cin * 9);
  int r  = e - co * Cin * 9;
  int ci = r / 9;
  int k  = r - ci * 9;
  dst[(ci * 9 + k) * Cout + co] = src[e];
}

// ---------- bf16 hi/lo weight pack: OIHW -> [cb][n][152], k = tap*16 + ci ----------
__global__ __launch_bounds__(256) void k_packw2(
    const float* __restrict__ src, unsigned short* __restrict__ dhi,
    unsigned short* __restrict__ dlo, int Cin, int Cout)
{
  int chunks = Cin >> 4;
  int total = Cout * chunks * 144;
  int e = blockIdx.x * 256 + threadIdx.x;
  if (e >= total) return;
  int n  = e / (chunks * 144);
  int r2 = e - n * chunks * 144;
  int cb = r2 / 144;
  int k  = r2 - cb * 144;
  int tap = k >> 4, ci = k & 15;
  float v = src[((size_t)n * Cin + cb * 16 + ci) * 9 + tap];
  unsigned hb = bf16b(v);
  unsigned lb = bf16b(v - bf16f(hb));
  size_t o = ((size_t)cb * Cout + n) * 152 + k;
  dhi[o] = (unsigned short)hb;
  dlo[o] = (unsigned short)lb;
}

// ---------- split-bf16 MFMA implicit-GEMM conv 3x3 pad 1 ----------
// M_BLK x N_BLK output tile, NTHR = (M_BLK/32)*(N_BLK/32)*64 threads.
// Spatial tile: (M_BLK/16) rows x 16 cols. K chunk = 16 channels (144 taps).
// MODE 0: out = conv+bias (NCHW)
// MODE 1: out = elu(conv+bias)+skip (NCHW)
// MODE 2: out = conv+bias stored transposed per plane: out[ch][x][y]
template<int M_BLK, int N_BLK, int NTHR, int MODE>
__global__ __launch_bounds__(NTHR) void k_convmfma(
    const float* __restrict__ in, const unsigned short* __restrict__ whi,
    const unsigned short* __restrict__ wlo,
    const float* __restrict__ bias, const float* __restrict__ skip,
    float* __restrict__ out,
    int Cin, int H, int W, int wCout, int n0, int outC, int oco0)
{
  constexpr int KT = 152;
  constexpr int MLOG = (M_BLK == 64) ? 6 : 7;
  constexpr int NWM = M_BLK / 32;
  const int tid = threadIdx.x;
  const int wave = tid >> 6;
  const int lane = tid & 63;
  const int wm = wave % NWM;
  const int wn = wave / NWM;
  const int tiles_x = W >> 4;
  const int tx0 = (blockIdx.x % tiles_x) << 4;
  const int ty0 = (blockIdx.x / tiles_x) * (M_BLK / 16);
  const int b = blockIdx.z;
  const int nb  = n0 + blockIdx.y * N_BLK;
  const int ocb = oco0 + blockIdx.y * N_BLK;

  __shared__ unsigned short Ahi[M_BLK * KT];
  __shared__ unsigned short Alo[M_BLK * KT];
  __shared__ unsigned short Bhi[N_BLK * KT];
  __shared__ unsigned short Blo[N_BLK * KT];

  f32x16 acc = {};

  const float* inb = in + (size_t)b * Cin * H * W;
  const size_t ps = (size_t)H * W;
  const int nchunks = Cin >> 4;

  for (int cb = 0; cb < nchunks; ++cb) {
    __syncthreads();
    // ---- stage A (im2col, split bf16) ----
    for (int e = tid; e < M_BLK * 18; e += NTHR) {
      int m = e & (M_BLK - 1);
      int oct = e >> MLOG;                 // 0..17
      int tap = oct >> 1, cih = oct & 1;
      int gy = ty0 + (m >> 4) + tap / 3 - 1;
      int gx = tx0 + (m & 15) + tap % 3 - 1;
      bool ok = (unsigned)gy < (unsigned)H && (unsigned)gx < (unsigned)W;
      const float* src = inb + (size_t)(cb * 16 + cih * 8) * ps + (size_t)gy * W + gx;
      unsigned ph[4], pl[4];
#pragma unroll
      for (int j = 0; j < 4; ++j) {
        float v0 = ok ? src[(size_t)(2 * j) * ps] : 0.f;
        float v1 = ok ? src[(size_t)(2 * j + 1) * ps] : 0.f;
        unsigned h0 = bf16b(v0), h1 = bf16b(v1);
        unsigned l0 = bf16b(v0 - bf16f(h0)), l1 = bf16b(v1 - bf16f(h1));
        ph[j] = h0 | (h1 << 16);
        pl[j] = l0 | (l1 << 16);
      }
      *(uint4*)&Ahi[m * KT + oct * 8] = *(const uint4*)ph;
      *(uint4*)&Alo[m * KT + oct * 8] = *(const uint4*)pl;
    }
    // ---- stage B (copy pre-packed hi/lo rows) ----
    const unsigned short* bsh = whi + ((size_t)cb * wCout + nb) * KT;
    const unsigned short* bsl = wlo + ((size_t)cb * wCout + nb) * KT;
    for (int e = tid; e < N_BLK * 19; e += NTHR) {
      int n = e / 19, o = e - n * 19;
      *(uint4*)&Bhi[n * KT + o * 8] = *(const uint4*)(bsh + (size_t)n * KT + o * 8);
      *(uint4*)&Blo[n * KT + o * 8] = *(const uint4*)(bsl + (size_t)n * KT + o * 8);
    }
    __syncthreads();
    // ---- MFMA inner loop: 9 K-steps x 3 MFMA ----
    const int am = wm * 32 + (lane & 31);
    const int bn = wn * 32 + (lane & 31);
    const int half = lane >> 5;
    const short* Ahp = (const short*)Ahi + am * KT + half * 8;
    const short* Alp = (const short*)Alo + am * KT + half * 8;
    const short* Bhp = (const short*)Bhi + bn * KT + half * 8;
    const short* Blp = (const short*)Blo + bn * KT + half * 8;
#pragma unroll
    for (int ks = 0; ks < 9; ++ks) {
      short8v ah = *(const short8v*)(Ahp + ks * 16);
      short8v al = *(const short8v*)(Alp + ks * 16);
      short8v bh = *(const short8v*)(Bhp + ks * 16);
      short8v bl = *(const short8v*)(Blp + ks * 16);
      acc = __builtin_amdgcn_mfma_f32_32x32x16_bf16(ah, bh, acc, 0, 0, 0);
      acc = __builtin_amdgcn_mfma_f32_32x32x16_bf16(al, bh, acc, 0, 0, 0);
      acc = __builtin_amdgcn_mfma_f32_32x32x16_bf16(ah, bl, acc, 0, 0, 0);
    }
  }

  // ---- epilogue ----
  const int nloc = wn * 32 + (lane & 31);
  const int oc = ocb + nloc;
  const float bv = bias[nb + nloc];
#pragma unroll
  for (int i = 0; i < 16; ++i) {
    int m = wm * 32 + (i & 3) + 8 * (i >> 2) + 4 * (lane >> 5);
    int y = ty0 + (m >> 4), x = tx0 + (m & 15);
    float v = acc[i] + bv;
    size_t idx;
    if (MODE == 2) idx = (((size_t)b * outC + oc) * W + x) * (size_t)H + y;
    else           idx = (((size_t)b * outC + oc) * H + y) * (size_t)W + x;
    if (MODE == 1) {
      float e = v > 0.f ? v : expm1f(v);
      v = e + skip[idx];
    }
    out[idx] = v;
  }
}

// ---------- f32 tiled conv 3x3 (Cin=3 or Cout=3 small convs) ----------
template<int CI, int CO>
__global__ __launch_bounds__(256) void k_conv3x3f(
    const float* __restrict__ in, const float* __restrict__ wr,
    const float* __restrict__ bias, float* __restrict__ out,
    int Cin, int H, int W, int wstride, int outC)
{
  const int ntx = W >> 4;
  const int tid = threadIdx.x;
  const int tx = tid & 15, ty = tid >> 4;
  const int tx0 = (blockIdx.x % ntx) << 4, ty0 = (blockIdx.x / ntx) << 4;
  const int b = blockIdx.z;

  __shared__ float sh[CI * 324];

  float acc[CO];
#pragma unroll
  for (int co = 0; co < CO; ++co) acc[co] = bias[co];

  const float* inb = in + (size_t)b * Cin * H * W;

  for (int cb = 0; cb < Cin; cb += CI) {
    __syncthreads();
    for (int e = tid; e < CI * 324; e += 256) {
      int ci = e / 324;
      int rr = e - ci * 324;
      int r = rr / 18, c = rr - r * 18;
      int gh = ty0 + r - 1, gw = tx0 + c - 1;
      float v = 0.f;
      if ((unsigned)gh < (unsigned)H && (unsigned)gw < (unsigned)W)
        v = inb[(size_t)(cb + ci) * H * W + (size_t)gh * W + gw];
      sh[e] = v;
    }
    __syncthreads();
#pragma unroll 1
    for (int ci = 0; ci < CI; ++ci) {
      float v[9];
      const float* sp = sh + ci * 324 + ty * 18 + tx;
#pragma unroll
      for (int kh = 0; kh < 3; ++kh)
#pragma unroll
        for (int kw = 0; kw < 3; ++kw)
          v[kh * 3 + kw] = sp[kh * 18 + kw];
      const float* wp = wr + (size_t)((cb + ci) * 9) * wstride;
#pragma unroll
      for (int k = 0; k < 9; ++k)
#pragma unroll
        for (int co = 0; co < CO; ++co)
          acc[co] = fmaf(wp[(size_t)k * wstride + co], v[k], acc[co]);
    }
  }
#pragma unroll
  for (int co = 0; co < CO; ++co)
    out[(((size_t)b * outC + co) * H + ty0 + ty) * W + tx0 + tx] = acc[co];
}

// ---------- conv 1x1 (f32) ----------
__global__ __launch_bounds__(256) void k_conv1x1(
    const float* __restrict__ in, const float* __restrict__ wgt,
    const float* __restrict__ bias, float* __restrict__ out,
    int Cin, int Cout, int H, int W)
{
  int hw = blockIdx.x * 256 + threadIdx.x;
  if (hw >= H * W) return;
  int co = blockIdx.y, b = blockIdx.z;
  const float* ip = in + (size_t)b * Cin * H * W + hw;
  const float* wp = wgt + (size_t)co * Cin;
  float acc = bias[co];
  for (int ci = 0; ci < Cin; ++ci) acc += wp[ci] * ip[(size_t)ci * H * W];
  out[((size_t)b * Cout + co) * H * W + hw] = acc;
}

// ---------- relu + maxpool 3x3 stride 2 pad 1 ----------
__global__ __launch_bounds__(256) void k_pool(
    const float* __restrict__ in, float* __restrict__ out, int C, int H, int W)
{
  int Ho = H >> 1, Wo = W >> 1;
  int hw = blockIdx.x * 256 + threadIdx.x;
  if (hw >= Ho * Wo) return;
  int ow = hw % Wo, oh = hw / Wo;
  int c = blockIdx.y, b = blockIdx.z;
  const float* p = in + ((size_t)(b * C + c) * H) * W;
  float m = 0.f;
#pragma unroll
  for (int dh = -1; dh <= 1; ++dh) {
    int ih = 2 * oh + dh;
    if ((unsigned)ih >= (unsigned)H) continue;
    const float* r = p + (size_t)ih * W;
#pragma unroll
    for (int dw = -1; dw <= 1; ++dw) {
      int iw = 2 * ow + dw;
      if ((unsigned)iw >= (unsigned)W) continue;
      m = fmaxf(m, r[iw]);
    }
  }
  out[((size_t)(b * C + c) * Ho + oh) * Wo + ow] = m;
}

// ---------- bilinear 2x upsample ----------
__global__ __launch_bounds__(256) void k_up2(
    const float* __restrict__ in, float* __restrict__ out, int C, int H, int W)
{
  int Ho = H * 2, Wo = W * 2;
  int hw = blockIdx.x * 256 + threadIdx.x;
  if (hw >= Ho * Wo) return;
  int ow = hw % Wo, oh = hw / Wo;
  int c = blockIdx.y, b = blockIdx.z;
  int ih = oh >> 1, iw = ow >> 1;
  int ih0, ih1, iw0, iw1; float fh0, fw0;
  if (oh & 1) { ih0 = ih; ih1 = min(ih + 1, H - 1); fh0 = 0.75f; }
  else        { ih0 = max(ih - 1, 0); ih1 = ih;     fh0 = 0.25f; }
  if (ow & 1) { iw0 = iw; iw1 = min(iw + 1, W - 1); fw0 = 0.75f; }
  else        { iw0 = max(iw - 1, 0); iw1 = iw;     fw0 = 0.25f; }
  const float* p = in + ((size_t)(b * C + c) * H) * W;
  float v = fh0 * (fw0 * p[(size_t)ih0 * W + iw0] + (1.f - fw0) * p[(size_t)ih0 * W + iw1])
          + (1.f - fh0) * (fw0 * p[(size_t)ih1 * W + iw0] + (1.f - fw0) * p[(size_t)ih1 * W + iw1]);
  out[((size_t)(b * C + c) * Ho + oh) * Wo + ow] = v;
}

// ---------- gated scan helpers ----------
DEVINL void gl_lds16(const float* g, float* lds) {
  __builtin_amdgcn_global_load_lds(
      (const __attribute__((address_space(1))) unsigned int*)g,
      (__attribute__((address_space(3))) unsigned int*)lds, 16, 0, 0);
}

DEVINL float prop_step(float xv, float a1, float a2, float a3,
                       float hu, float hc, float hd) {
  float ss = fabsf(a1) + fabsf(a2) + fabsf(a3);
  if (ss >= 1.f) { float r = 1.f / ss; a1 *= r; a2 *= r; a3 *= r; }
  return (1.f - a1 - a2 - a3) * xv + a1 * hu + a2 * hc + a3 * hd;
}

// ---------- vertical scan (natural layout) ----------
template<int REV, int FIRST>
__global__ __launch_bounds__(64) void k_propv(
    const float* __restrict__ X, const float* __restrict__ G,
    float* __restrict__ out, int S, int P)
{
  const int plane = blockIdx.x;
  const int b = plane >> 5, c = plane & 31;
  const int lane = threadIdx.x;
  const size_t ps = (size_t)S * P;
  const float* xp = X + (size_t)plane * ps;
  const float* g1 = G + ((size_t)b * 96 + c) * ps;
  const float* g2 = g1 + (size_t)32 * ps;
  const float* g3 = g1 + (size_t)64 * ps;
  float* op = out + (size_t)plane * ps;

  __shared__ __align__(16) float bx[2][4096];
  __shared__ __align__(16) float b1[2][4096];
  __shared__ __align__(16) float b2[2][4096];
  __shared__ __align__(16) float b3[2][4096];
  __shared__ __align__(16) float bo[4096];

  float h0 = 0.f, h1 = 0.f, h2 = 0.f, h3 = 0.f;
  int cur = 0;

  auto stage = [&](int buf, int t0) {
#pragma unroll
    for (int u = 0; u < 16; ++u) {
      int s = REV ? (S - 1 - (t0 + u)) : (t0 + u);
      size_t ro = (size_t)s * P + lane * 4;
      gl_lds16(xp + ro, &bx[buf][u * 256]);
      gl_lds16(g1 + ro, &b1[buf][u * 256]);
      gl_lds16(g2 + ro, &b2[buf][u * 256]);
      gl_lds16(g3 + ro, &b3[buf][u * 256]);
    }
  };

  stage(0, 0);
  const int NT = S / 16;
  for (int t = 0; t < NT; ++t) {
    asm volatile("s_waitcnt vmcnt(0)" ::: "memory");
    if (t + 1 < NT) stage(cur ^ 1, (t + 1) * 16);

    for (int u = 0; u < 16; ++u) {
      const float* px = &bx[cur][u * 256];
      const float* p1 = &b1[cur][u * 256];
      const float* p2 = &b2[cur][u * 256];
      const float* p3 = &b3[cur][u * 256];
      float x0 = px[lane], x1 = px[lane + 64], x2 = px[lane + 128], x3 = px[lane + 192];
      float a10 = p1[lane], a11 = p1[lane + 64], a12 = p1[lane + 128], a13 = p1[lane + 192];
      float a20 = p2[lane], a21 = p2[lane + 64], a22 = p2[lane + 128], a23 = p2[lane + 192];
      float a30 = p3[lane], a31 = p3[lane + 64], a32 = p3[lane + 128], a33 = p3[lane + 192];

      float su0 = __shfl_up(h0, 1), su1 = __shfl_up(h1, 1);
      float su2 = __shfl_up(h2, 1), su3 = __shfl_up(h3, 1);
      float sd0 = __shfl_down(h0, 1), sd1 = __shfl_down(h1, 1);
      float sd2 = __shfl_down(h2, 1), sd3 = __shfl_down(h3, 1);
      float t63_0 = __shfl(h0, 63), t63_1 = __shfl(h1, 63), t63_2 = __shfl(h2, 63);
      float t0_1 = __shfl(h1, 0), t0_2 = __shfl(h2, 0), t0_3 = __shfl(h3, 0);

      float hu0 = lane ? su0 : 0.f;
      float hu1 = lane ? su1 : t63_0;
      float hu2 = lane ? su2 : t63_1;
      float hu3 = lane ? su3 : t63_2;
      float hd0 = (lane < 63) ? sd0 : t0_1;
      float hd1 = (lane < 63) ? sd1 : t0_2;
      float hd2 = (lane < 63) ? sd2 : t0_3;
      float hd3 = (lane < 63) ? sd3 : 0.f;

      h0 = prop_step(x0, a10, a20, a30, hu0, h0, hd0);
      h1 = prop_step(x1, a11, a21, a31, hu1, h1, hd1);
      h2 = prop_step(x2, a12, a22, a32, hu2, h2, hd2);
      h3 = prop_step(x3, a13, a23, a33, hu3, h3, hd3);

      float* po = &bo[u * 256];
      po[lane] = h0; po[lane + 64] = h1; po[lane + 128] = h2; po[lane + 192] = h3;
    }

    for (int u = 0; u < 16; ++u) {
      int s = REV ? (S - 1 - (t * 16 + u)) : (t * 16 + u);
      float4 v = *(const float4*)&bo[u * 256 + lane * 4];
      float4* dst = (float4*)(op + (size_t)s * P + lane * 4);
      if (FIRST) {
        *dst = v;
      } else {
        float4 o = *dst;
        o.x = fmaxf(o.x, v.x); o.y = fmaxf(o.y, v.y);
        o.z = fmaxf(o.z, v.z); o.w = fmaxf(o.w, v.w);
        *dst = o;
      }
    }
    cur ^= 1;
  }
}

// ---------- horizontal scan: X/out natural, G transposed per plane [s][p] ----------
template<int REV>
__global__ __launch_bounds__(64) void k_proph(
    const float* __restrict__ X, const float* __restrict__ G,
    float* __restrict__ out, int S, int P)
{
  const int plane = blockIdx.x;
  const int b = plane >> 5, c = plane & 31;
  const int lane = threadIdx.x;
  const size_t ps = (size_t)S * P;
  const float* xp = X + (size_t)plane * ps;
  const float* g1 = G + ((size_t)b * 96 + c) * ps;
  const float* g2 = g1 + (size_t)32 * ps;
  const float* g3 = g1 + (size_t)64 * ps;
  float* op = out + (size_t)plane * ps;

  __shared__ __align__(16) float b1[2][4096];
  __shared__ __align__(16) float b2[2][4096];
  __shared__ __align__(16) float b3[2][4096];

  float h0 = 0.f, h1 = 0.f, h2 = 0.f, h3 = 0.f;
  int cur = 0;

  auto stage = [&](int buf, int t0) {
#pragma unroll
    for (int u = 0; u < 16; ++u) {
      int s = REV ? (S - 1 - (t0 + u)) : (t0 + u);
      size_t ro = (size_t)s * P + lane * 4;
      gl_lds16(g1 + ro, &b1[buf][u * 256]);
      gl_lds16(g2 + ro, &b2[buf][u * 256]);
      gl_lds16(g3 + ro, &b3[buf][u * 256]);
    }
  };

  stage(0, 0);
  const int NT = S / 16;
  for (int t = 0; t < NT; ++t) {
    const int s0 = REV ? (S - 16 - t * 16) : (t * 16);

    asm volatile("s_waitcnt vmcnt(0)" ::: "memory");
    if (t + 1 < NT) stage(cur ^ 1, (t + 1) * 16);

    float xv[4][16];
#pragma unroll
    for (int q = 0; q < 4; ++q) {
      const float* row = xp + (size_t)(lane + 64 * q) * S + s0;
#pragma unroll
      for (int j = 0; j < 4; ++j) {
        float4 v = *(const float4*)(row + 4 * j);
        xv[q][4 * j + 0] = v.x; xv[q][4 * j + 1] = v.y;
        xv[q][4 * j + 2] = v.z; xv[q][4 * j + 3] = v.w;
      }
    }

    float vo[4][16];
#pragma unroll
    for (int u = 0; u < 16; ++u) {
      const int e = REV ? (15 - u) : u;
      const float* p1 = &b1[cur][u * 256];
      const float* p2 = &b2[cur][u * 256];
      const float* p3 = &b3[cur][u * 256];
      float a10 = p1[lane], a11 = p1[lane + 64], a12 = p1[lane + 128], a13 = p1[lane + 192];
      float a20 = p2[lane], a21 = p2[lane + 64], a22 = p2[lane + 128], a23 = p2[lane + 192];
      float a30 = p3[lane], a31 = p3[lane + 64], a32 = p3[lane + 128], a33 = p3[lane + 192];

      float su0 = __shfl_up(h0, 1), su1 = __shfl_up(h1, 1);
      float su2 = __shfl_up(h2, 1), su3 = __shfl_up(h3, 1);
      float sd0 = __shfl_down(h0, 1), sd1 = __shfl_down(h1, 1);
      float sd2 = __shfl_down(h2, 1), sd3 = __shfl_down(h3, 1);
      float t63_0 = __shfl(h0, 63), t63_1 = __shfl(h1, 63), t63_2 = __shfl(h2, 63);
      float t0_1 = __shfl(h1, 0), t0_2 = __shfl(h2, 0), t0_3 = __shfl(h3, 0);

      float hu0 = lane ? su0 : 0.f;
      float hu1 = lane ? su1 : t63_0;
      float hu2 = lane ? su2 : t63_1;
      float hu3 = lane ? su3 : t63_2;
      float hd0 = (lane < 63) ? sd0 : t0_1;
      float hd1 = (lane < 63) ? sd1 : t0_2;
      float hd2 = (lane < 63) ? sd2 : t0_3;
      float hd3 = (lane < 63) ? sd3 : 0.f;

      h0 = prop_step(xv[0][e], a10, a20, a30, hu0, h0, hd0);
      h1 = prop_step(xv[1][e], a11, a21, a31, hu1, h1, hd1);
      h2 = prop_step(xv[2][e], a12, a22, a32, hu2, h2, hd2);
      h3 = prop_step(xv[3][e], a13, a23, a33, hu3, h3, hd3);

      vo[0][e] = h0; vo[1][e] = h1; vo[2][e] = h2; vo[3][e] = h3;
    }

#pragma unroll
    for (int q = 0; q < 4; ++q) {
      float* row = op + (size_t)(lane + 64 * q) * S + s0;
#pragma unroll
      for (int j = 0; j < 4; ++j) {
        float4 o = *(const float4*)(row + 4 * j);
        o.x = fmaxf(o.x, vo[q][4 * j + 0]);
        o.y = fmaxf(o.y, vo[q][4 * j + 1]);
        o.z = fmaxf(o.z, vo[q][4 * j + 2]);
        o.w = fmaxf(o.w, vo[q][4 * j + 3]);
        *(float4*)(row + 4 * j) = o;
      }
    }
    cur ^= 1;
  }
}

// ---------------------------------------------------------------------------
extern "C" void kernel_launch(void* const* d_in, const int* in_sizes, int n_in,
                              void* d_out, int out_size, void* d_ws, size_t ws_size,
                              hipStream_t stream)
{
  const float* x   = (const float*)d_in[0];
  const float* rgb = (const float*)d_in[1];
  const float* mw  = (const float*)d_in[2];
  const float* mb  = (const float*)d_in[3];
  const float* c1w = (const float*)d_in[4];
  const float* c1b = (const float*)d_in[5];
  const float* c2w = (const float*)d_in[6];
  const float* c2b = (const float*)d_in[7];
  const float* c3w = (const float*)d_in[8];
  const float* c3b = (const float*)d_in[9];
  const float* c4w = (const float*)d_in[10];
  const float* c4b = (const float*)d_in[11];
  const float* d0w = (const float*)d_in[12];
  const float* d0b = (const float*)d_in[13];
  const float* d2w = (const float*)d_in[14];
  const float* d2b = (const float*)d_in[15];
  const float* d4w = (const float*)d_in[16];
  const float* d4b = (const float*)d_in[17];
  const float* d6w = (const float*)d_in[18];
  const float* d6b = (const float*)d_in[19];
  const float* d7w = (const float*)d_in[20];
  const float* d7b = (const float*)d_in[21];
  const float* pw  = (const float*)d_in[22];
  const float* pb  = (const float*)d_in[23];

  char* ws = (char*)d_ws;
  const size_t MB = 1024 * 1024;
  // Workspace (peak 216 MiB, proven in round 1):
  float* X    = (float*)(ws + 0);         // (4,32,256,256)  0-32
  float* f1   = (float*)(ws + 32 * MB);   // skip for d6     32-64
  float* f2   = (float*)(ws + 64 * MB);   // skip for d4     64-80
  float* f3   = (float*)(ws + 80 * MB);   // skip for d2     80-88
  float* p1   = (float*)(ws + 88 * MB);   // 88-96
  float* p2   = (float*)(ws + 96 * MB);   // 96-100
  float* p3   = (float*)(ws + 100 * MB);  // 100-102
  float* f4   = (float*)(ws + 102 * MB);  // 102-106
  float* o0   = (float*)(ws + 106 * MB);  // 106-108
  float* u0   = (float*)(ws + 108 * MB);  // (4,128,64,64)   108-116
  float* o1   = (float*)(ws + 132 * MB);  // (4,128,64,64)   132-140
  float* u1   = (float*)(ws + 80 * MB);   // (4,128,128,128) 80-112 [f3,p*,f4,o0,u0 dead]
  float* o2   = (float*)(ws + 200 * MB);  // (4,64,128,128)  200-216
  float* u2   = (float*)(ws + 64 * MB);   // (4,64,256,256)  64-128 [f2,u1 dead]
  float* o3   = (float*)(ws + 132 * MB);  // (4,32,256,256)  132-164 [o1 dead]
  float* gbuf = (float*)(ws + 32 * MB);   // (4,96,256,256)  32-128 [f1,u2 dead]
  float* om   = (float*)(ws + 164 * MB);  // 164-196
  // pack zone @196 MiB (~3.2 MB, ends < 200 MiB where o2 starts)
  char* wz = ws + 196 * MB;
  float* wmf  = (float*)wz;              // 864
  float* wc1f = wmf + 864;               // 864
  float* wpkf = wc1f + 864;              // 864
  unsigned short* wp0 = (unsigned short*)(wpkf + 864);
  unsigned short* wc2h = wp0;            unsigned short* wc2l = wc2h + 19456;
  unsigned short* wc3h = wc2l + 19456;   unsigned short* wc3l = wc3h + 77824;
  unsigned short* wc4h = wc3l + 77824;   unsigned short* wc4l = wc4h + 311296;
  unsigned short* wd2h = wc4l + 311296;  unsigned short* wd2l = wd2h + 155648;
  unsigned short* wd4h = wd2l + 155648;  unsigned short* wd4l = wd4h + 77824;
  unsigned short* wd6h = wd4l + 77824;   unsigned short* wd6l = wd6h + 19456;
  unsigned short* wd7h = wd6l + 19456;   unsigned short* wd7l = wd7h + 116736;

  dim3 blk(256);
  auto repf = [&](const float* s, float* d, int ci, int co) {
    int n = co * ci * 9;
    k_repack<<<dim3((n + 255) / 256), blk, 0, stream>>>(s, d, ci, co);
  };
  auto packb = [&](const float* s, unsigned short* dh, unsigned short* dl, int ci, int co) {
    int n = co * (ci / 16) * 144;
    k_packw2<<<dim3((n + 255) / 256), blk, 0, stream>>>(s, dh, dl, ci, co);
  };
  repf(mw, wmf, 3, 32);
  repf(c1w, wc1f, 3, 32);
  repf(pw, wpkf, 32, 3);
  packb(c2w, wc2h, wc2l, 32, 64);
  packb(c3w, wc3h, wc3l, 64, 128);
  packb(c4w, wc4h, wc4l, 128, 256);
  packb(d2w, wd2h, wd2l, 128, 128);
  packb(d4w, wd4h, wd4l, 128, 64);
  packb(d6w, wd6h, wd6l, 64, 32);
  packb(d7w, wd7h, wd7l, 32, 384);

  // X = conv(x); f1 = conv(rgb)  (f32, Cin=3)
  k_conv3x3f<3, 32><<<dim3(256, 1, 4), blk, 0, stream>>>(x,   wmf,  mb,  X,  3, 256, 256, 32, 32);
  k_conv3x3f<3, 32><<<dim3(256, 1, 4), blk, 0, stream>>>(rgb, wc1f, c1b, f1, 3, 256, 256, 32, 32);

  // Encoder (split-bf16 MFMA)
  k_pool<<<dim3(64, 32, 4), blk, 0, stream>>>(f1, p1, 32, 256, 256);
  k_convmfma<64, 64, 256, 0><<<dim3(256, 1, 4), blk, 0, stream>>>(p1, wc2h, wc2l, c2b, nullptr, f2, 32, 128, 128, 64, 0, 64, 0);
  k_pool<<<dim3(16, 64, 4), blk, 0, stream>>>(f2, p2, 64, 128, 128);
  k_convmfma<64, 64, 256, 0><<<dim3(64, 2, 4), blk, 0, stream>>>(p2, wc3h, wc3l, c3b, nullptr, f3, 64, 64, 64, 128, 0, 128, 0);
  k_pool<<<dim3(4, 128, 4), blk, 0, stream>>>(f3, p3, 128, 64, 64);
  k_convmfma<64, 64, 256, 0><<<dim3(16, 4, 4), blk, 0, stream>>>(p3, wc4h, wc4l, c4b, nullptr, f4, 128, 32, 32, 256, 0, 256, 0);
  k_conv1x1<<<dim3(4, 128, 4), blk, 0, stream>>>(f4, d0w, d0b, o0, 256, 128, 32, 32);

  // Decoder: up2 then MFMA conv (elu+skip fused)
  k_up2<<<dim3(16, 128, 4), blk, 0, stream>>>(o0, u0, 128, 32, 32);
  k_convmfma<64, 64, 256, 1><<<dim3(64, 2, 4), blk, 0, stream>>>(u0, wd2h, wd2l, d2b, f3, o1, 128, 64, 64, 128, 0, 128, 0);
  k_up2<<<dim3(64, 128, 4), blk, 0, stream>>>(o1, u1, 128, 64, 64);
  k_convmfma<64, 64, 256, 1><<<dim3(256, 1, 4), blk, 0, stream>>>(u1, wd4h, wd4l, d4b, f2, o2, 128, 128, 128, 64, 0, 64, 0);
  k_up2<<<dim3(256, 64, 4), blk, 0, stream>>>(o2, u2, 64, 128, 128);
  k_convmfma<64, 32, 128, 1><<<dim3(1024, 1, 4), dim3(128), 0, stream>>>(u2, wd6h, wd6l, d6b, f1, o3, 64, 256, 256, 32, 0, 32, 0);

  // Guide conv (d7) per direction + scans.
  // dirs: k=0 hor fwd, k=1 hor rev (MODE 2 transposed gates), k=2 vert fwd, k=3 vert rev.
  // Vertical first (FIRST write of om), then horizontal (fmax RMW).
  // k=2:
  k_convmfma<64, 64, 256, 0><<<dim3(1024, 1, 4), blk, 0, stream>>>(o3, wd7h, wd7l, d7b, nullptr, gbuf, 32, 256, 256, 384, 192, 96, 0);
  k_convmfma<64, 32, 128, 0><<<dim3(1024, 1, 4), dim3(128), 0, stream>>>(o3, wd7h, wd7l, d7b, nullptr, gbuf, 32, 256, 256, 384, 256, 96, 64);
  k_propv<0, 1><<<dim3(128), dim3(64), 0, stream>>>(X, gbuf, om, 256, 256);
  // k=3:
  k_convmfma<64, 64, 256, 0><<<dim3(1024, 1, 4), blk, 0, stream>>>(o3, wd7h, wd7l, d7b, nullptr, gbuf, 32, 256, 256, 384, 288, 96, 0);
  k_convmfma<64, 32, 128, 0><<<dim3(1024, 1, 4), dim3(128), 0, stream>>>(o3, wd7h, wd7l, d7b, nullptr, gbuf, 32, 256, 256, 384, 352, 96, 64);
  k_propv<1, 0><<<dim3(128), dim3(64), 0, stream>>>(X, gbuf, om, 256, 256);
  // k=0 (transposed gates):
  k_convmfma<64, 64, 256, 2><<<dim3(1024, 1, 4), blk, 0, stream>>>(o3, wd7h, wd7l, d7b, nullptr, gbuf, 32, 256, 256, 384, 0, 96, 0);
  k_convmfma<64, 32, 128, 2><<<dim3(1024, 1, 4), dim3(128), 0, stream>>>(o3, wd7h, wd7l, d7b, nullptr, gbuf, 32, 256, 256, 384, 64, 96, 64);
  k_proph<0><<<dim3(128), dim3(64), 0, stream>>>(X, gbuf, om, 256, 256);
  // k=1 (transposed gates):
  k_convmfma<64, 64, 256, 2><<<dim3(1024, 1, 4), blk, 0, stream>>>(o3, wd7h, wd7l, d7b, nullptr, gbuf, 32, 256, 256, 384, 96, 96, 0);
  k_convmfma<64, 32, 128, 2><<<dim3(1024, 1, 4), dim3(128), 0, stream>>>(o3, wd7h, wd7l, d7b, nullptr, gbuf, 32, 256, 256, 384, 160, 96, 64);
  k_proph<1><<<dim3(128), dim3(64), 0, stream>>>(X, gbuf, om, 256, 256);

  // Final conv (f32, Cout=3)
  k_conv3x3f<32, 3><<<dim3(256, 1, 4), blk, 0, stream>>>(om, wpkf, pb, (float*)d_out, 32, 256, 256, 3, 3);
}

// Round 6
// 2183.060 us; speedup vs baseline: 5.8150x; 1.0936x over previous
//
#include <hip/hip_runtime.h>
#include <cstddef>
#include <cstdint>

#define DEVINL __device__ __forceinline__

typedef __attribute__((ext_vector_type(8))) _Float16 half8v;
typedef __attribute__((ext_vector_type(16))) float f32x16;

// ---------------------------------------------------------------------------
// SPN forward, MI355X gfx950. B=4, H=W=256, NF=32.
// Round 6: single-fp16 MFMA implicit-GEMM (stage-once LDS halo, 9 shifted
// tap-reads), B-panel preload where it fits. fp16 error ~2^-11/conv -> OK.
// ---------------------------------------------------------------------------

// ---------- f32 weight repack: OIHW -> [ci*9+k][Cout] (small convs) ----------
__global__ __launch_bounds__(256) void k_repack(
    const float* __restrict__ src, float* __restrict__ dst, int Cin, int Cout)
{
  int n = Cout * Cin * 9;
  int e = blockIdx.x * 256 + threadIdx.x;
  if (e >= n) return;
  int co = e / (Cin * 9);
  int r  = e - co * Cin * 9;
  int ci = r / 9;
  int k  = r - ci * 9;
  dst[(ci * 9 + k) * Cout + co] = src[e];
}

// ---------- fp16 weight pack: OIHW -> [cb][n][152], k = tap*16 + ci ----------
__global__ __launch_bounds__(256) void k_packwh(
    const float* __restrict__ src, _Float16* __restrict__ dst, int Cin, int Cout)
{
  int chunks = Cin >> 4;
  int total = Cout * chunks * 144;
  int e = blockIdx.x * 256 + threadIdx.x;
  if (e >= total) return;
  int n  = e / (chunks * 144);
  int r2 = e - n * chunks * 144;
  int cb = r2 / 144;
  int k  = r2 - cb * 144;
  int tap = k >> 4, ci = k & 15;
  float v = src[((size_t)n * Cin + cb * 16 + ci) * 9 + tap];
  dst[((size_t)cb * Cout + n) * 152 + k] = (_Float16)v;
}

// ---------- fp16 MFMA implicit-GEMM conv 3x3 pad 1, stage-once halo ----------
// Tile: M_BLK = NWM*32 pixels = (NWM*2) rows x 16 cols. N_BLK = NWN*NACC*32.
// A LDS: halo (rows+2) x 18 x 16ci fp16, natural layout; taps = shifted reads.
// B LDS: [n][152] fp16 (k = tap*16+ci), preloaded for all chunks if PREB.
// MODE 0: out = conv+bias. MODE 1: elu(conv+bias)+skip. MODE 2: transposed.
template<int NWM, int NWN, int NACC, int CHUNKS, int PREB, int MODE>
__global__ __launch_bounds__(NWM * NWN * 64) void k_convh(
    const float* __restrict__ in, const _Float16* __restrict__ wpk,
    const float* __restrict__ bias, const float* __restrict__ skip,
    float* __restrict__ out,
    int H, int W, int wCout, int n0, int outC, int oco0)
{
  constexpr int NTHR = NWM * NWN * 64;
  constexpr int ROWS = NWM * 2;
  constexpr int RH = ROWS + 2;
  constexpr int N_BLK = NWN * NACC * 32;
  const int tid = threadIdx.x;
  const int wave = tid >> 6, lane = tid & 63;
  const int wm = wave % NWM, wn = wave / NWM;
  const int tiles_x = W >> 4;
  const int tx0 = (blockIdx.x % tiles_x) << 4;
  const int ty0 = (blockIdx.x / tiles_x) * ROWS;
  const int b = blockIdx.z;
  const int nb = n0 + blockIdx.y * N_BLK;
  const int ocb = oco0 + blockIdx.y * N_BLK;

  __shared__ _Float16 Ah[RH * 18 * 16];
  __shared__ _Float16 Bh[(PREB ? CHUNKS : 1) * N_BLK * 152];

  f32x16 acc[NACC] = {};

  const size_t ps = (size_t)H * W;
  const float* inb = in + (size_t)b * (CHUNKS * 16) * ps;

  if (PREB) {
    const _Float16* wsrc = wpk + (size_t)nb * 152;  // rows n0..n0+N_BLK for cb=0
    for (int e = tid; e < CHUNKS * N_BLK * 19; e += NTHR) {
      int cb = e / (N_BLK * 19);
      int r  = e - cb * N_BLK * 19;
      *(uint4*)&Bh[(size_t)cb * N_BLK * 152 + r * 8] =
          *(const uint4*)(wsrc + ((size_t)cb * wCout) * 152 + r * 8);
    }
  }

  for (int cb = 0; cb < CHUNKS; ++cb) {
    __syncthreads();
    // ---- stage A: halo tile, 16 channels, natural layout ----
    for (int e = tid; e < RH * 18; e += NTHR) {
      int r = e / 18, c = e - r * 18;
      int gy = ty0 + r - 1, gx = tx0 + c - 1;
      bool ok = (unsigned)gy < (unsigned)H && (unsigned)gx < (unsigned)W;
      const float* src = inb + (size_t)(cb * 16) * ps + (size_t)gy * W + gx;
      half8v v0, v1;
#pragma unroll
      for (int j = 0; j < 8; ++j)
        v0[j] = ok ? (_Float16)src[(size_t)j * ps] : (_Float16)0.f;
#pragma unroll
      for (int j = 0; j < 8; ++j)
        v1[j] = ok ? (_Float16)src[(size_t)(j + 8) * ps] : (_Float16)0.f;
      *(half8v*)&Ah[e * 16] = v0;
      *(half8v*)&Ah[e * 16 + 8] = v1;
    }
    // ---- stage B (per-chunk path) ----
    if (!PREB) {
      const _Float16* wsrc = wpk + ((size_t)cb * wCout + nb) * 152;
      for (int e = tid; e < N_BLK * 19; e += NTHR)
        *(uint4*)&Bh[e * 8] = *(const uint4*)(wsrc + e * 8);
    }
    __syncthreads();
    // ---- MFMA: 9 shifted tap-reads x NACC ----
    const int am = wm * 32 + (lane & 31);
    const int r0 = am >> 4, c0 = am & 15;
    const int kh = lane >> 5;
    const _Float16* Ab = Ah + kh * 8;
    const _Float16* Bb = Bh + (PREB ? (size_t)cb * N_BLK * 152 : 0) + kh * 8;
#pragma unroll
    for (int ks = 0; ks < 9; ++ks) {
      const int dy = ks / 3, dx = ks - dy * 3;
      half8v af = *(const half8v*)(Ab + ((r0 + dy) * 18 + (c0 + dx)) * 16);
#pragma unroll
      for (int na = 0; na < NACC; ++na) {
        const int bn = (wn * NACC + na) * 32 + (lane & 31);
        half8v bf = *(const half8v*)(Bb + bn * 152 + ks * 16);
        acc[na] = __builtin_amdgcn_mfma_f32_32x32x16_f16(af, bf, acc[na], 0, 0, 0);
      }
    }
  }

  // ---- epilogue ----
#pragma unroll
  for (int na = 0; na < NACC; ++na) {
    const int nloc = (wn * NACC + na) * 32 + (lane & 31);
    const int oc = ocb + nloc;
    const float bv = bias[nb + nloc];
#pragma unroll
    for (int i = 0; i < 16; ++i) {
      int m = wm * 32 + (i & 3) + 8 * (i >> 2) + 4 * (lane >> 5);
      int y = ty0 + (m >> 4), x = tx0 + (m & 15);
      float v = acc[na][i] + bv;
      size_t idx;
      if (MODE == 2) idx = (((size_t)b * outC + oc) * W + x) * (size_t)H + y;
      else           idx = (((size_t)b * outC + oc) * H + y) * (size_t)W + x;
      if (MODE == 1) {
        float e = v > 0.f ? v : expm1f(v);
        v = e + skip[idx];
      }
      out[idx] = v;
    }
  }
}

// ---------- f32 tiled conv 3x3 (Cin=3 or Cout=3 small convs) ----------
template<int CI, int CO>
__global__ __launch_bounds__(256) void k_conv3x3f(
    const float* __restrict__ in, const float* __restrict__ wr,
    const float* __restrict__ bias, float* __restrict__ out,
    int Cin, int H, int W, int wstride, int outC)
{
  const int ntx = W >> 4;
  const int tid = threadIdx.x;
  const int tx = tid & 15, ty = tid >> 4;
  const int tx0 = (blockIdx.x % ntx) << 4, ty0 = (blockIdx.x / ntx) << 4;
  const int b = blockIdx.z;

  __shared__ float sh[CI * 324];

  float acc[CO];
#pragma unroll
  for (int co = 0; co < CO; ++co) acc[co] = bias[co];

  const float* inb = in + (size_t)b * Cin * H * W;

  for (int cb = 0; cb < Cin; cb += CI) {
    __syncthreads();
    for (int e = tid; e < CI * 324; e += 256) {
      int ci = e / 324;
      int rr = e - ci * 324;
      int r = rr / 18, c = rr - r * 18;
      int gh = ty0 + r - 1, gw = tx0 + c - 1;
      float v = 0.f;
      if ((unsigned)gh < (unsigned)H && (unsigned)gw < (unsigned)W)
        v = inb[(size_t)(cb + ci) * H * W + (size_t)gh * W + gw];
      sh[e] = v;
    }
    __syncthreads();
#pragma unroll 1
    for (int ci = 0; ci < CI; ++ci) {
      float v[9];
      const float* sp = sh + ci * 324 + ty * 18 + tx;
#pragma unroll
      for (int kh = 0; kh < 3; ++kh)
#pragma unroll
        for (int kw = 0; kw < 3; ++kw)
          v[kh * 3 + kw] = sp[kh * 18 + kw];
      const float* wp = wr + (size_t)((cb + ci) * 9) * wstride;
#pragma unroll
      for (int k = 0; k < 9; ++k)
#pragma unroll
        for (int co = 0; co < CO; ++co)
          acc[co] = fmaf(wp[(size_t)k * wstride + co], v[k], acc[co]);
    }
  }
#pragma unroll
  for (int co = 0; co < CO; ++co)
    out[(((size_t)b * outC + co) * H + ty0 + ty) * W + tx0 + tx] = acc[co];
}

// ---------- conv 1x1 (f32) ----------
__global__ __launch_bounds__(256) void k_conv1x1(
    const float* __restrict__ in, const float* __restrict__ wgt,
    const float* __restrict__ bias, float* __restrict__ out,
    int Cin, int Cout, int H, int W)
{
  int hw = blockIdx.x * 256 + threadIdx.x;
  if (hw >= H * W) return;
  int co = blockIdx.y, b = blockIdx.z;
  const float* ip = in + (size_t)b * Cin * H * W + hw;
  const float* wp = wgt + (size_t)co * Cin;
  float acc = bias[co];
  for (int ci = 0; ci < Cin; ++ci) acc += wp[ci] * ip[(size_t)ci * H * W];
  out[((size_t)b * Cout + co) * H * W + hw] = acc;
}

// ---------- relu + maxpool 3x3 stride 2 pad 1 ----------
__global__ __launch_bounds__(256) void k_pool(
    const float* __restrict__ in, float* __restrict__ out, int C, int H, int W)
{
  int Ho = H >> 1, Wo = W >> 1;
  int hw = blockIdx.x * 256 + threadIdx.x;
  if (hw >= Ho * Wo) return;
  int ow = hw % Wo, oh = hw / Wo;
  int c = blockIdx.y, b = blockIdx.z;
  const float* p = in + ((size_t)(b * C + c) * H) * W;
  float m = 0.f;
#pragma unroll
  for (int dh = -1; dh <= 1; ++dh) {
    int ih = 2 * oh + dh;
    if ((unsigned)ih >= (unsigned)H) continue;
    const float* r = p + (size_t)ih * W;
#pragma unroll
    for (int dw = -1; dw <= 1; ++dw) {
      int iw = 2 * ow + dw;
      if ((unsigned)iw >= (unsigned)W) continue;
      m = fmaxf(m, r[iw]);
    }
  }
  out[((size_t)(b * C + c) * Ho + oh) * Wo + ow] = m;
}

// ---------- bilinear 2x upsample ----------
__global__ __launch_bounds__(256) void k_up2(
    const float* __restrict__ in, float* __restrict__ out, int C, int H, int W)
{
  int Ho = H * 2, Wo = W * 2;
  int hw = blockIdx.x * 256 + threadIdx.x;
  if (hw >= Ho * Wo) return;
  int ow = hw % Wo, oh = hw / Wo;
  int c = blockIdx.y, b = blockIdx.z;
  int ih = oh >> 1, iw = ow >> 1;
  int ih0, ih1, iw0, iw1; float fh0, fw0;
  if (oh & 1) { ih0 = ih; ih1 = min(ih + 1, H - 1); fh0 = 0.75f; }
  else        { ih0 = max(ih - 1, 0); ih1 = ih;     fh0 = 0.25f; }
  if (ow & 1) { iw0 = iw; iw1 = min(iw + 1, W - 1); fw0 = 0.75f; }
  else        { iw0 = max(iw - 1, 0); iw1 = iw;     fw0 = 0.25f; }
  const float* p = in + ((size_t)(b * C + c) * H) * W;
  float v = fh0 * (fw0 * p[(size_t)ih0 * W + iw0] + (1.f - fw0) * p[(size_t)ih0 * W + iw1])
          + (1.f - fh0) * (fw0 * p[(size_t)ih1 * W + iw0] + (1.f - fw0) * p[(size_t)ih1 * W + iw1]);
  out[((size_t)(b * C + c) * Ho + oh) * Wo + ow] = v;
}

// ---------- gated scan helpers ----------
DEVINL void gl_lds16(const float* g, float* lds) {
  __builtin_amdgcn_global_load_lds(
      (const __attribute__((address_space(1))) unsigned int*)g,
      (__attribute__((address_space(3))) unsigned int*)lds, 16, 0, 0);
}

DEVINL float prop_step(float xv, float a1, float a2, float a3,
                       float hu, float hc, float hd) {
  float ss = fabsf(a1) + fabsf(a2) + fabsf(a3);
  if (ss >= 1.f) { float r = 1.f / ss; a1 *= r; a2 *= r; a3 *= r; }
  return (1.f - a1 - a2 - a3) * xv + a1 * hu + a2 * hc + a3 * hd;
}

// ---------- vertical scan (natural layout) ----------
template<int REV, int FIRST>
__global__ __launch_bounds__(64) void k_propv(
    const float* __restrict__ X, const float* __restrict__ G,
    float* __restrict__ out, int S, int P)
{
  const int plane = blockIdx.x;
  const int b = plane >> 5, c = plane & 31;
  const int lane = threadIdx.x;
  const size_t ps = (size_t)S * P;
  const float* xp = X + (size_t)plane * ps;
  const float* g1 = G + ((size_t)b * 96 + c) * ps;
  const float* g2 = g1 + (size_t)32 * ps;
  const float* g3 = g1 + (size_t)64 * ps;
  float* op = out + (size_t)plane * ps;

  __shared__ __align__(16) float bx[2][4096];
  __shared__ __align__(16) float b1[2][4096];
  __shared__ __align__(16) float b2[2][4096];
  __shared__ __align__(16) float b3[2][4096];
  __shared__ __align__(16) float bo[4096];

  float h0 = 0.f, h1 = 0.f, h2 = 0.f, h3 = 0.f;
  int cur = 0;

  auto stage = [&](int buf, int t0) {
#pragma unroll
    for (int u = 0; u < 16; ++u) {
      int s = REV ? (S - 1 - (t0 + u)) : (t0 + u);
      size_t ro = (size_t)s * P + lane * 4;
      gl_lds16(xp + ro, &bx[buf][u * 256]);
      gl_lds16(g1 + ro, &b1[buf][u * 256]);
      gl_lds16(g2 + ro, &b2[buf][u * 256]);
      gl_lds16(g3 + ro, &b3[buf][u * 256]);
    }
  };

  stage(0, 0);
  const int NT = S / 16;
  for (int t = 0; t < NT; ++t) {
    asm volatile("s_waitcnt vmcnt(0)" ::: "memory");
    if (t + 1 < NT) stage(cur ^ 1, (t + 1) * 16);

    for (int u = 0; u < 16; ++u) {
      const float* px = &bx[cur][u * 256];
      const float* p1 = &b1[cur][u * 256];
      const float* p2 = &b2[cur][u * 256];
      const float* p3 = &b3[cur][u * 256];
      float x0 = px[lane], x1 = px[lane + 64], x2 = px[lane + 128], x3 = px[lane + 192];
      float a10 = p1[lane], a11 = p1[lane + 64], a12 = p1[lane + 128], a13 = p1[lane + 192];
      float a20 = p2[lane], a21 = p2[lane + 64], a22 = p2[lane + 128], a23 = p2[lane + 192];
      float a30 = p3[lane], a31 = p3[lane + 64], a32 = p3[lane + 128], a33 = p3[lane + 192];

      float su0 = __shfl_up(h0, 1), su1 = __shfl_up(h1, 1);
      float su2 = __shfl_up(h2, 1), su3 = __shfl_up(h3, 1);
      float sd0 = __shfl_down(h0, 1), sd1 = __shfl_down(h1, 1);
      float sd2 = __shfl_down(h2, 1), sd3 = __shfl_down(h3, 1);
      float t63_0 = __shfl(h0, 63), t63_1 = __shfl(h1, 63), t63_2 = __shfl(h2, 63);
      float t0_1 = __shfl(h1, 0), t0_2 = __shfl(h2, 0), t0_3 = __shfl(h3, 0);

      float hu0 = lane ? su0 : 0.f;
      float hu1 = lane ? su1 : t63_0;
      float hu2 = lane ? su2 : t63_1;
      float hu3 = lane ? su3 : t63_2;
      float hd0 = (lane < 63) ? sd0 : t0_1;
      float hd1 = (lane < 63) ? sd1 : t0_2;
      float hd2 = (lane < 63) ? sd2 : t0_3;
      float hd3 = (lane < 63) ? sd3 : 0.f;

      h0 = prop_step(x0, a10, a20, a30, hu0, h0, hd0);
      h1 = prop_step(x1, a11, a21, a31, hu1, h1, hd1);
      h2 = prop_step(x2, a12, a22, a32, hu2, h2, hd2);
      h3 = prop_step(x3, a13, a23, a33, hu3, h3, hd3);

      float* po = &bo[u * 256];
      po[lane] = h0; po[lane + 64] = h1; po[lane + 128] = h2; po[lane + 192] = h3;
    }

    for (int u = 0; u < 16; ++u) {
      int s = REV ? (S - 1 - (t * 16 + u)) : (t * 16 + u);
      float4 v = *(const float4*)&bo[u * 256 + lane * 4];
      float4* dst = (float4*)(op + (size_t)s * P + lane * 4);
      if (FIRST) {
        *dst = v;
      } else {
        float4 o = *dst;
        o.x = fmaxf(o.x, v.x); o.y = fmaxf(o.y, v.y);
        o.z = fmaxf(o.z, v.z); o.w = fmaxf(o.w, v.w);
        *dst = o;
      }
    }
    cur ^= 1;
  }
}

// ---------- horizontal scan: X/out natural, G transposed per plane [s][p] ----------
template<int REV>
__global__ __launch_bounds__(64) void k_proph(
    const float* __restrict__ X, const float* __restrict__ G,
    float* __restrict__ out, int S, int P)
{
  const int plane = blockIdx.x;
  const int b = plane >> 5, c = plane & 31;
  const int lane = threadIdx.x;
  const size_t ps = (size_t)S * P;
  const float* xp = X + (size_t)plane * ps;
  const float* g1 = G + ((size_t)b * 96 + c) * ps;
  const float* g2 = g1 + (size_t)32 * ps;
  const float* g3 = g1 + (size_t)64 * ps;
  float* op = out + (size_t)plane * ps;

  __shared__ __align__(16) float b1[2][4096];
  __shared__ __align__(16) float b2[2][4096];
  __shared__ __align__(16) float b3[2][4096];

  float h0 = 0.f, h1 = 0.f, h2 = 0.f, h3 = 0.f;
  int cur = 0;

  auto stage = [&](int buf, int t0) {
#pragma unroll
    for (int u = 0; u < 16; ++u) {
      int s = REV ? (S - 1 - (t0 + u)) : (t0 + u);
      size_t ro = (size_t)s * P + lane * 4;
      gl_lds16(g1 + ro, &b1[buf][u * 256]);
      gl_lds16(g2 + ro, &b2[buf][u * 256]);
      gl_lds16(g3 + ro, &b3[buf][u * 256]);
    }
  };

  stage(0, 0);
  const int NT = S / 16;
  for (int t = 0; t < NT; ++t) {
    const int s0 = REV ? (S - 16 - t * 16) : (t * 16);

    asm volatile("s_waitcnt vmcnt(0)" ::: "memory");
    if (t + 1 < NT) stage(cur ^ 1, (t + 1) * 16);

    float xv[4][16];
#pragma unroll
    for (int q = 0; q < 4; ++q) {
      const float* row = xp + (size_t)(lane + 64 * q) * S + s0;
#pragma unroll
      for (int j = 0; j < 4; ++j) {
        float4 v = *(const float4*)(row + 4 * j);
        xv[q][4 * j + 0] = v.x; xv[q][4 * j + 1] = v.y;
        xv[q][4 * j + 2] = v.z; xv[q][4 * j + 3] = v.w;
      }
    }

    float vo[4][16];
#pragma unroll
    for (int u = 0; u < 16; ++u) {
      const int e = REV ? (15 - u) : u;
      const float* p1 = &b1[cur][u * 256];
      const float* p2 = &b2[cur][u * 256];
      const float* p3 = &b3[cur][u * 256];
      float a10 = p1[lane], a11 = p1[lane + 64], a12 = p1[lane + 128], a13 = p1[lane + 192];
      float a20 = p2[lane], a21 = p2[lane + 64], a22 = p2[lane + 128], a23 = p2[lane + 192];
      float a30 = p3[lane], a31 = p3[lane + 64], a32 = p3[lane + 128], a33 = p3[lane + 192];

      float su0 = __shfl_up(h0, 1), su1 = __shfl_up(h1, 1);
      float su2 = __shfl_up(h2, 1), su3 = __shfl_up(h3, 1);
      float sd0 = __shfl_down(h0, 1), sd1 = __shfl_down(h1, 1);
      float sd2 = __shfl_down(h2, 1), sd3 = __shfl_down(h3, 1);
      float t63_0 = __shfl(h0, 63), t63_1 = __shfl(h1, 63), t63_2 = __shfl(h2, 63);
      float t0_1 = __shfl(h1, 0), t0_2 = __shfl(h2, 0), t0_3 = __shfl(h3, 0);

      float hu0 = lane ? su0 : 0.f;
      float hu1 = lane ? su1 : t63_0;
      float hu2 = lane ? su2 : t63_1;
      float hu3 = lane ? su3 : t63_2;
      float hd0 = (lane < 63) ? sd0 : t0_1;
      float hd1 = (lane < 63) ? sd1 : t0_2;
      float hd2 = (lane < 63) ? sd2 : t0_3;
      float hd3 = (lane < 63) ? sd3 : 0.f;

      h0 = prop_step(xv[0][e], a10, a20, a30, hu0, h0, hd0);
      h1 = prop_step(xv[1][e], a11, a21, a31, hu1, h1, hd1);
      h2 = prop_step(xv[2][e], a12, a22, a32, hu2, h2, hd2);
      h3 = prop_step(xv[3][e], a13, a23, a33, hu3, h3, hd3);

      vo[0][e] = h0; vo[1][e] = h1; vo[2][e] = h2; vo[3][e] = h3;
    }

#pragma unroll
    for (int q = 0; q < 4; ++q) {
      float* row = op + (size_t)(lane + 64 * q) * S + s0;
#pragma unroll
      for (int j = 0; j < 4; ++j) {
        float4 o = *(const float4*)(row + 4 * j);
        o.x = fmaxf(o.x, vo[q][4 * j + 0]);
        o.y = fmaxf(o.y, vo[q][4 * j + 1]);
        o.z = fmaxf(o.z, vo[q][4 * j + 2]);
        o.w = fmaxf(o.w, vo[q][4 * j + 3]);
        *(float4*)(row + 4 * j) = o;
      }
    }
    cur ^= 1;
  }
}

// ---------------------------------------------------------------------------
extern "C" void kernel_launch(void* const* d_in, const int* in_sizes, int n_in,
                              void* d_out, int out_size, void* d_ws, size_t ws_size,
                              hipStream_t stream)
{
  const float* x   = (const float*)d_in[0];
  const float* rgb = (const float*)d_in[1];
  const float* mw  = (const float*)d_in[2];
  const float* mb  = (const float*)d_in[3];
  const float* c1w = (const float*)d_in[4];
  const float* c1b = (const float*)d_in[5];
  const float* c2w = (const float*)d_in[6];
  const float* c2b = (const float*)d_in[7];
  const float* c3w = (const float*)d_in[8];
  const float* c3b = (const float*)d_in[9];
  const float* c4w = (const float*)d_in[10];
  const float* c4b = (const float*)d_in[11];
  const float* d0w = (const float*)d_in[12];
  const float* d0b = (const float*)d_in[13];
  const float* d2w = (const float*)d_in[14];
  const float* d2b = (const float*)d_in[15];
  const float* d4w = (const float*)d_in[16];
  const float* d4b = (const float*)d_in[17];
  const float* d6w = (const float*)d_in[18];
  const float* d6b = (const float*)d_in[19];
  const float* d7w = (const float*)d_in[20];
  const float* d7b = (const float*)d_in[21];
  const float* pw  = (const float*)d_in[22];
  const float* pb  = (const float*)d_in[23];

  char* ws = (char*)d_ws;
  const size_t MB = 1024 * 1024;
  // Workspace (peak 216 MiB, proven):
  float* X    = (float*)(ws + 0);         // (4,32,256,256)  0-32
  float* f1   = (float*)(ws + 32 * MB);   // skip for d6     32-64
  float* f2   = (float*)(ws + 64 * MB);   // skip for d4     64-80
  float* f3   = (float*)(ws + 80 * MB);   // skip for d2     80-88
  float* p1   = (float*)(ws + 88 * MB);   // 88-96
  float* p2   = (float*)(ws + 96 * MB);   // 96-100
  float* p3   = (float*)(ws + 100 * MB);  // 100-102
  float* f4   = (float*)(ws + 102 * MB);  // 102-106
  float* o0   = (float*)(ws + 106 * MB);  // 106-108
  float* u0   = (float*)(ws + 108 * MB);  // (4,128,64,64)   108-116
  float* o1   = (float*)(ws + 132 * MB);  // (4,128,64,64)   132-140
  float* u1   = (float*)(ws + 80 * MB);   // (4,128,128,128) 80-112 [f3,p*,f4,o0,u0 dead]
  float* o2   = (float*)(ws + 200 * MB);  // (4,64,128,128)  200-216
  float* u2   = (float*)(ws + 64 * MB);   // (4,64,256,256)  64-128 [f2,u1 dead]
  float* o3   = (float*)(ws + 132 * MB);  // (4,32,256,256)  132-164 [o1 dead]
  float* gbuf = (float*)(ws + 32 * MB);   // (4,96,256,256)  32-128 [f1,u2 dead]
  float* om   = (float*)(ws + 164 * MB);  // 164-196
  // pack zone @196 MiB (~1.6 MB, ends < 200 MiB where o2 starts)
  char* wz = ws + 196 * MB;
  float* wmf  = (float*)wz;              // 864
  float* wc1f = wmf + 864;               // 864
  float* wpkf = wc1f + 864;              // 864
  _Float16* wc2p = (_Float16*)(wpkf + 864);
  _Float16* wc3p = wc2p + 19456;   // 2*64*152
  _Float16* wc4p = wc3p + 77824;   // 4*128*152
  _Float16* wd2p = wc4p + 311296;  // 8*256*152
  _Float16* wd4p = wd2p + 155648;  // 8*128*152
  _Float16* wd6p = wd4p + 77824;   // 8*64*152
  _Float16* wd7p = wd6p + 19456;   // 4*32*152
  // wd7p: 2*384*152 = 116736

  dim3 blk(256);
  auto repf = [&](const float* s, float* d, int ci, int co) {
    int n = co * ci * 9;
    k_repack<<<dim3((n + 255) / 256), blk, 0, stream>>>(s, d, ci, co);
  };
  auto packh = [&](const float* s, _Float16* d, int ci, int co) {
    int n = co * (ci / 16) * 144;
    k_packwh<<<dim3((n + 255) / 256), blk, 0, stream>>>(s, d, ci, co);
  };
  repf(mw, wmf, 3, 32);
  repf(c1w, wc1f, 3, 32);
  repf(pw, wpkf, 32, 3);
  packh(c2w, wc2p, 32, 64);
  packh(c3w, wc3p, 64, 128);
  packh(c4w, wc4p, 128, 256);
  packh(d2w, wd2p, 128, 128);
  packh(d4w, wd4p, 128, 64);
  packh(d6w, wd6p, 64, 32);
  packh(d7w, wd7p, 32, 384);

  // X = conv(x); f1 = conv(rgb)  (f32, Cin=3)
  k_conv3x3f<3, 32><<<dim3(256, 1, 4), blk, 0, stream>>>(x,   wmf,  mb,  X,  3, 256, 256, 32, 32);
  k_conv3x3f<3, 32><<<dim3(256, 1, 4), blk, 0, stream>>>(rgb, wc1f, c1b, f1, 3, 256, 256, 32, 32);

  // Encoder (fp16 MFMA)
  k_pool<<<dim3(64, 32, 4), blk, 0, stream>>>(f1, p1, 32, 256, 256);
  k_convh<2, 1, 2, 2, 1, 0><<<dim3(256, 1, 4), dim3(128), 0, stream>>>(p1, wc2p, c2b, nullptr, f2, 128, 128, 64, 0, 64, 0);
  k_pool<<<dim3(16, 64, 4), blk, 0, stream>>>(f2, p2, 64, 128, 128);
  k_convh<2, 1, 2, 4, 0, 0><<<dim3(64, 2, 4), dim3(128), 0, stream>>>(p2, wc3p, c3b, nullptr, f3, 64, 64, 128, 0, 128, 0);
  k_pool<<<dim3(4, 128, 4), blk, 0, stream>>>(f3, p3, 128, 64, 64);
  k_convh<2, 1, 2, 8, 0, 0><<<dim3(16, 4, 4), dim3(128), 0, stream>>>(p3, wc4p, c4b, nullptr, f4, 32, 32, 256, 0, 256, 0);
  k_conv1x1<<<dim3(4, 128, 4), blk, 0, stream>>>(f4, d0w, d0b, o0, 256, 128, 32, 32);

  // Decoder: up2 then MFMA conv (elu+skip fused)
  k_up2<<<dim3(16, 128, 4), blk, 0, stream>>>(o0, u0, 128, 32, 32);
  k_convh<2, 1, 2, 8, 0, 1><<<dim3(64, 2, 4), dim3(128), 0, stream>>>(u0, wd2p, d2b, f3, o1, 64, 64, 128, 0, 128, 0);
  k_up2<<<dim3(64, 128, 4), blk, 0, stream>>>(o1, u1, 128, 64, 64);
  k_convh<2, 1, 2, 8, 0, 1><<<dim3(256, 1, 4), dim3(128), 0, stream>>>(u1, wd4p, d4b, f2, o2, 128, 128, 64, 0, 64, 0);
  k_up2<<<dim3(256, 64, 4), blk, 0, stream>>>(o2, u2, 64, 128, 128);
  k_convh<2, 1, 1, 4, 1, 1><<<dim3(1024, 1, 4), dim3(128), 0, stream>>>(u2, wd6p, d6b, f1, o3, 256, 256, 32, 0, 32, 0);

  // Guide conv (d7), one dispatch per direction (N=96) + scans.
  // dirs: k=0 hor fwd, k=1 hor rev (MODE 2 transposed gates), k=2/3 vertical.
  // Vertical first (FIRST write of om), then horizontal (fmax RMW).
  k_convh<2, 1, 3, 2, 1, 0><<<dim3(1024, 1, 4), dim3(128), 0, stream>>>(o3, wd7p, d7b, nullptr, gbuf, 256, 256, 384, 192, 96, 0);
  k_propv<0, 1><<<dim3(128), dim3(64), 0, stream>>>(X, gbuf, om, 256, 256);
  k_convh<2, 1, 3, 2, 1, 0><<<dim3(1024, 1, 4), dim3(128), 0, stream>>>(o3, wd7p, d7b, nullptr, gbuf, 256, 256, 384, 288, 96, 0);
  k_propv<1, 0><<<dim3(128), dim3(64), 0, stream>>>(X, gbuf, om, 256, 256);
  k_convh<2, 1, 3, 2, 1, 2><<<dim3(1024, 1, 4), dim3(128), 0, stream>>>(o3, wd7p, d7b, nullptr, gbuf, 256, 256, 384, 0, 96, 0);
  k_proph<0><<<dim3(128), dim3(64), 0, stream>>>(X, gbuf, om, 256, 256);
  k_convh<2, 1, 3, 2, 1, 2><<<dim3(1024, 1, 4), dim3(128), 0, stream>>>(o3, wd7p, d7b, nullptr, gbuf, 256, 256, 384, 96, 96, 0);
  k_proph<1><<<dim3(128), dim3(64), 0, stream>>>(X, gbuf, om, 256, 256);

  // Final conv (f32, Cout=3)
  k_conv3x3f<32, 3><<<dim3(256, 1, 4), blk, 0, stream>>>(om, wpkf, pb, (float*)d_out, 32, 256, 256, 3, 3);
}

// Round 8
// 1552.821 us; speedup vs baseline: 8.1752x; 1.4059x over previous
//
#include <hip/hip_runtime.h>
#include <cstddef>
#include <cstdint>

#define DEVINL __device__ __forceinline__

typedef __attribute__((ext_vector_type(8))) _Float16 half8v;
typedef __attribute__((ext_vector_type(16))) float f32x16;

// ---------------------------------------------------------------------------
// SPN forward, MI355X gfx950. B=4, H=W=256, NF=32.
// Round 8: round-7 design with the d2/d4/d6 template-arg fix (MODE=1, GATES=0).
// ---------------------------------------------------------------------------

// ---------- f32 weight repack: OIHW -> [ci*9+k][Cout] (small convs) ----------
__global__ __launch_bounds__(256) void k_repack(
    const float* __restrict__ src, float* __restrict__ dst, int Cin, int Cout)
{
  int n = Cout * Cin * 9;
  int e = blockIdx.x * 256 + threadIdx.x;
  if (e >= n) return;
  int co = e / (Cin * 9);
  int r  = e - co * Cin * 9;
  int ci = r / 9;
  int k  = r - ci * 9;
  dst[(ci * 9 + k) * Cout + co] = src[e];
}

// ---------- fp16 weight pack: OIHW -> [cb][n][152], k = tap*16 + ci ----------
__global__ __launch_bounds__(256) void k_packwh(
    const float* __restrict__ src, _Float16* __restrict__ dst, int Cin, int Cout)
{
  int chunks = Cin >> 4;
  int total = Cout * chunks * 144;
  int e = blockIdx.x * 256 + threadIdx.x;
  if (e >= total) return;
  int n  = e / (chunks * 144);
  int r2 = e - n * chunks * 144;
  int cb = r2 / 144;
  int k  = r2 - cb * 144;
  int tap = k >> 4, ci = k & 15;
  float v = src[((size_t)n * Cin + cb * 16 + ci) * 9 + tap];
  dst[((size_t)cb * Cout + n) * 152 + k] = (_Float16)v;
}

// ---------- fp16 MFMA implicit-GEMM conv 3x3 pad 1, stage-once halo ----------
// M tile = NWM*32 px = (NWM*2) rows x 16 cols. N_BLK = NWN*NACC*32.
// MODE 0: f32 out = conv+bias. MODE 1: f32 out = elu(conv+bias)+skip.
// MODE 2 (+GATES): transposed per-plane store out[ch][x][y].
// GATES=1 (needs NWN=1, NACC=3): per-lane g1,g2,g3 -> normalize -> fp16 store.
template<int NWM, int NWN, int NACC, int CHUNKS, int MODE, int GATES>
__global__ __launch_bounds__(NWM * NWN * 64) void k_convh(
    const float* __restrict__ in, const _Float16* __restrict__ wpk,
    const float* __restrict__ bias, const float* __restrict__ skip,
    void* __restrict__ outv,
    int H, int W, int wCout, int n0, int outC, int oco0)
{
  constexpr int NTHR = NWM * NWN * 64;
  constexpr int ROWS = NWM * 2;
  constexpr int RH = ROWS + 2;
  constexpr int N_BLK = NWN * NACC * 32;
  const int tid = threadIdx.x;
  const int wave = tid >> 6, lane = tid & 63;
  const int wm = wave % NWM, wn = wave / NWM;
  const int tiles_x = W >> 4;
  const int tx0 = (blockIdx.x % tiles_x) << 4;
  const int ty0 = (blockIdx.x / tiles_x) * ROWS;
  const int b = blockIdx.z;
  const int nb = n0 + blockIdx.y * N_BLK;
  const int ocb = oco0 + blockIdx.y * N_BLK;

  __shared__ _Float16 Ah[RH * 18 * 16];
  __shared__ _Float16 Bh[N_BLK * 152];

  f32x16 acc[NACC] = {};

  const size_t ps = (size_t)H * W;
  const float* inb = in + (size_t)b * (CHUNKS * 16) * ps;

  for (int cb = 0; cb < CHUNKS; ++cb) {
    __syncthreads();
    // ---- stage A: halo tile, 16 channels, natural layout ----
    for (int e = tid; e < RH * 18; e += NTHR) {
      int r = e / 18, c = e - r * 18;
      int gy = ty0 + r - 1, gx = tx0 + c - 1;
      bool ok = (unsigned)gy < (unsigned)H && (unsigned)gx < (unsigned)W;
      const float* src = inb + (size_t)(cb * 16) * ps + (size_t)gy * W + gx;
      half8v v0, v1;
#pragma unroll
      for (int j = 0; j < 8; ++j)
        v0[j] = ok ? (_Float16)src[(size_t)j * ps] : (_Float16)0.f;
#pragma unroll
      for (int j = 0; j < 8; ++j)
        v1[j] = ok ? (_Float16)src[(size_t)(j + 8) * ps] : (_Float16)0.f;
      *(half8v*)&Ah[e * 16] = v0;
      *(half8v*)&Ah[e * 16 + 8] = v1;
    }
    // ---- stage B (per chunk) ----
    {
      const _Float16* wsrc = wpk + ((size_t)cb * wCout + nb) * 152;
      for (int e = tid; e < N_BLK * 19; e += NTHR)
        *(uint4*)&Bh[e * 8] = *(const uint4*)(wsrc + e * 8);
    }
    __syncthreads();
    // ---- MFMA: 9 shifted tap-reads x NACC ----
    const int am = wm * 32 + (lane & 31);
    const int r0 = am >> 4, c0 = am & 15;
    const int kh = lane >> 5;
    const _Float16* Ab = Ah + kh * 8;
    const _Float16* Bb = Bh + kh * 8;
#pragma unroll
    for (int ks = 0; ks < 9; ++ks) {
      const int dy = ks / 3, dx = ks - dy * 3;
      half8v af = *(const half8v*)(Ab + ((r0 + dy) * 18 + (c0 + dx)) * 16);
#pragma unroll
      for (int na = 0; na < NACC; ++na) {
        const int bn = (wn * NACC + na) * 32 + (lane & 31);
        half8v bf = *(const half8v*)(Bb + bn * 152 + ks * 16);
        acc[na] = __builtin_amdgcn_mfma_f32_32x32x16_f16(af, bf, acc[na], 0, 0, 0);
      }
    }
  }

  // ---- epilogue ----
  if (GATES) {
    _Float16* outh = (_Float16*)outv;
    const int c = lane & 31;
    const float bv0 = bias[nb + c];
    const float bv1 = bias[nb + 32 + c];
    const float bv2 = bias[nb + 64 + c];
#pragma unroll
    for (int i = 0; i < 16; ++i) {
      int m = wm * 32 + (i & 3) + 8 * (i >> 2) + 4 * (lane >> 5);
      int y = ty0 + (m >> 4), x = tx0 + (m & 15);
      float g1 = acc[0][i] + bv0;
      float g2 = acc[NACC > 1 ? 1 : 0][i] + bv1;
      float g3 = acc[NACC > 2 ? 2 : 0][i] + bv2;
      float s = fabsf(g1) + fabsf(g2) + fabsf(g3);
      if (s >= 1.f) { float r = 1.f / s; g1 *= r; g2 *= r; g3 *= r; }
      size_t idx = (MODE == 2) ? ((size_t)(b * 96 + c) * W + x) * (size_t)H + y
                               : ((size_t)(b * 96 + c) * H + y) * (size_t)W + x;
      outh[idx] = (_Float16)g1;
      outh[idx + 32 * ps] = (_Float16)g2;
      outh[idx + 64 * ps] = (_Float16)g3;
    }
  } else {
    float* out = (float*)outv;
#pragma unroll
    for (int na = 0; na < NACC; ++na) {
      const int nloc = (wn * NACC + na) * 32 + (lane & 31);
      const int oc = ocb + nloc;
      const float bv = bias[nb + nloc];
#pragma unroll
      for (int i = 0; i < 16; ++i) {
        int m = wm * 32 + (i & 3) + 8 * (i >> 2) + 4 * (lane >> 5);
        int y = ty0 + (m >> 4), x = tx0 + (m & 15);
        float v = acc[na][i] + bv;
        size_t idx = (((size_t)b * outC + oc) * H + y) * (size_t)W + x;
        if (MODE == 1) {
          float e = v > 0.f ? v : expm1f(v);
          v = e + skip[idx];
        }
        out[idx] = v;
      }
    }
  }
}

// ---------- f32 tiled conv 3x3 (Cin=3 or Cout=3 small convs) ----------
template<int CI, int CO>
__global__ __launch_bounds__(256) void k_conv3x3f(
    const float* __restrict__ in, const float* __restrict__ wr,
    const float* __restrict__ bias, float* __restrict__ out,
    int Cin, int H, int W, int wstride, int outC)
{
  const int ntx = W >> 4;
  const int tid = threadIdx.x;
  const int tx = tid & 15, ty = tid >> 4;
  const int tx0 = (blockIdx.x % ntx) << 4, ty0 = (blockIdx.x / ntx) << 4;
  const int b = blockIdx.z;

  __shared__ float sh[CI * 324];

  float acc[CO];
#pragma unroll
  for (int co = 0; co < CO; ++co) acc[co] = bias[co];

  const float* inb = in + (size_t)b * Cin * H * W;

  for (int cb = 0; cb < Cin; cb += CI) {
    __syncthreads();
    for (int e = tid; e < CI * 324; e += 256) {
      int ci = e / 324;
      int rr = e - ci * 324;
      int r = rr / 18, c = rr - r * 18;
      int gh = ty0 + r - 1, gw = tx0 + c - 1;
      float v = 0.f;
      if ((unsigned)gh < (unsigned)H && (unsigned)gw < (unsigned)W)
        v = inb[(size_t)(cb + ci) * H * W + (size_t)gh * W + gw];
      sh[e] = v;
    }
    __syncthreads();
#pragma unroll 1
    for (int ci = 0; ci < CI; ++ci) {
      float v[9];
      const float* sp = sh + ci * 324 + ty * 18 + tx;
#pragma unroll
      for (int kh = 0; kh < 3; ++kh)
#pragma unroll
        for (int kw = 0; kw < 3; ++kw)
          v[kh * 3 + kw] = sp[kh * 18 + kw];
      const float* wp = wr + (size_t)((cb + ci) * 9) * wstride;
#pragma unroll
      for (int k = 0; k < 9; ++k)
#pragma unroll
        for (int co = 0; co < CO; ++co)
          acc[co] = fmaf(wp[(size_t)k * wstride + co], v[k], acc[co]);
    }
  }
#pragma unroll
  for (int co = 0; co < CO; ++co)
    out[(((size_t)b * outC + co) * H + ty0 + ty) * W + tx0 + tx] = acc[co];
}

// ---------- conv 1x1 (f32) ----------
__global__ __launch_bounds__(256) void k_conv1x1(
    const float* __restrict__ in, const float* __restrict__ wgt,
    const float* __restrict__ bias, float* __restrict__ out,
    int Cin, int Cout, int H, int W)
{
  int hw = blockIdx.x * 256 + threadIdx.x;
  if (hw >= H * W) return;
  int co = blockIdx.y, b = blockIdx.z;
  const float* ip = in + (size_t)b * Cin * H * W + hw;
  const float* wp = wgt + (size_t)co * Cin;
  float acc = bias[co];
  for (int ci = 0; ci < Cin; ++ci) acc += wp[ci] * ip[(size_t)ci * H * W];
  out[((size_t)b * Cout + co) * H * W + hw] = acc;
}

// ---------- relu + maxpool 3x3 stride 2 pad 1 ----------
__global__ __launch_bounds__(256) void k_pool(
    const float* __restrict__ in, float* __restrict__ out, int C, int H, int W)
{
  int Ho = H >> 1, Wo = W >> 1;
  int hw = blockIdx.x * 256 + threadIdx.x;
  if (hw >= Ho * Wo) return;
  int ow = hw % Wo, oh = hw / Wo;
  int c = blockIdx.y, b = blockIdx.z;
  const float* p = in + ((size_t)(b * C + c) * H) * W;
  float m = 0.f;
#pragma unroll
  for (int dh = -1; dh <= 1; ++dh) {
    int ih = 2 * oh + dh;
    if ((unsigned)ih >= (unsigned)H) continue;
    const float* r = p + (size_t)ih * W;
#pragma unroll
    for (int dw = -1; dw <= 1; ++dw) {
      int iw = 2 * ow + dw;
      if ((unsigned)iw >= (unsigned)W) continue;
      m = fmaxf(m, r[iw]);
    }
  }
  out[((size_t)(b * C + c) * Ho + oh) * Wo + ow] = m;
}

// ---------- bilinear 2x upsample ----------
__global__ __launch_bounds__(256) void k_up2(
    const float* __restrict__ in, float* __restrict__ out, int C, int H, int W)
{
  int Ho = H * 2, Wo = W * 2;
  int hw = blockIdx.x * 256 + threadIdx.x;
  if (hw >= Ho * Wo) return;
  int ow = hw % Wo, oh = hw / Wo;
  int c = blockIdx.y, b = blockIdx.z;
  int ih = oh >> 1, iw = ow >> 1;
  int ih0, ih1, iw0, iw1; float fh0, fw0;
  if (oh & 1) { ih0 = ih; ih1 = min(ih + 1, H - 1); fh0 = 0.75f; }
  else        { ih0 = max(ih - 1, 0); ih1 = ih;     fh0 = 0.25f; }
  if (ow & 1) { iw0 = iw; iw1 = min(iw + 1, W - 1); fw0 = 0.75f; }
  else        { iw0 = max(iw - 1, 0); iw1 = iw;     fw0 = 0.25f; }
  const float* p = in + ((size_t)(b * C + c) * H) * W;
  float v = fh0 * (fw0 * p[(size_t)ih0 * W + iw0] + (1.f - fw0) * p[(size_t)ih0 * W + iw1])
          + (1.f - fh0) * (fw0 * p[(size_t)ih1 * W + iw0] + (1.f - fw0) * p[(size_t)ih1 * W + iw1]);
  out[((size_t)(b * C + c) * Ho + oh) * Wo + ow] = v;
}

// ---------- gated scan helpers ----------
DEVINL void gl_lds16p(const void* g, void* lds) {
  __builtin_amdgcn_global_load_lds(
      (const __attribute__((address_space(1))) unsigned int*)g,
      (__attribute__((address_space(3))) unsigned int*)lds, 16, 0, 0);
}

DEVINL float prop_step(float xv, float a1, float a2, float a3,
                       float hu, float hc, float hd) {
  return (1.f - a1 - a2 - a3) * xv + a1 * hu + a2 * hc + a3 * hd;
}

// ---------- vertical scan (natural layout), fp16 pre-normalized gates ----------
template<int REV, int FIRST>
__global__ __launch_bounds__(64) void k_propv(
    const float* __restrict__ X, const _Float16* __restrict__ G,
    float* __restrict__ out, int S, int P)
{
  const int plane = blockIdx.x;
  const int b = plane >> 5, c = plane & 31;
  const int lane = threadIdx.x;
  const size_t ps = (size_t)S * P;
  const float* xp = X + (size_t)plane * ps;
  const _Float16* g1 = G + ((size_t)b * 96 + c) * ps;
  const _Float16* g2 = g1 + (size_t)32 * ps;
  const _Float16* g3 = g1 + (size_t)64 * ps;
  float* op = out + (size_t)plane * ps;

  __shared__ __align__(16) float bx[2][4096];
  __shared__ __align__(16) _Float16 h1[2][4096];
  __shared__ __align__(16) _Float16 h2[2][4096];
  __shared__ __align__(16) _Float16 h3[2][4096];
  __shared__ __align__(16) float bo[4096];

  float r0 = 0.f, r1 = 0.f, r2 = 0.f, r3 = 0.f;
  int cur = 0;

  auto stage = [&](int buf, int s0) {
#pragma unroll
    for (int u = 0; u < 16; ++u)
      gl_lds16p(xp + (size_t)(s0 + u) * P + lane * 4, &bx[buf][u * 256]);
#pragma unroll
    for (int v = 0; v < 8; ++v) {
      size_t ro = (size_t)(s0 + 2 * v) * P + lane * 8;
      gl_lds16p(g1 + ro, &h1[buf][v * 512]);
      gl_lds16p(g2 + ro, &h2[buf][v * 512]);
      gl_lds16p(g3 + ro, &h3[buf][v * 512]);
    }
  };

  stage(0, REV ? (S - 16) : 0);
  const int NT = S / 16;
  for (int t = 0; t < NT; ++t) {
    const int s0 = REV ? (S - 16 - t * 16) : (t * 16);
    asm volatile("s_waitcnt vmcnt(0)" ::: "memory");
    if (t + 1 < NT) stage(cur ^ 1, REV ? (s0 - 16) : (s0 + 16));

    for (int u = 0; u < 16; ++u) {
      const int e = REV ? (15 - u) : u;
      const float* px = &bx[cur][e * 256];
      const _Float16* p1 = &h1[cur][e * 256];
      const _Float16* p2 = &h2[cur][e * 256];
      const _Float16* p3 = &h3[cur][e * 256];
      float x0 = px[lane], x1 = px[lane + 64], x2 = px[lane + 128], x3 = px[lane + 192];
      float a10 = p1[lane], a11 = p1[lane + 64], a12 = p1[lane + 128], a13 = p1[lane + 192];
      float a20 = p2[lane], a21 = p2[lane + 64], a22 = p2[lane + 128], a23 = p2[lane + 192];
      float a30 = p3[lane], a31 = p3[lane + 64], a32 = p3[lane + 128], a33 = p3[lane + 192];

      float su0 = __shfl_up(r0, 1), su1 = __shfl_up(r1, 1);
      float su2 = __shfl_up(r2, 1), su3 = __shfl_up(r3, 1);
      float sd0 = __shfl_down(r0, 1), sd1 = __shfl_down(r1, 1);
      float sd2 = __shfl_down(r2, 1), sd3 = __shfl_down(r3, 1);
      float t63_0 = __shfl(r0, 63), t63_1 = __shfl(r1, 63), t63_2 = __shfl(r2, 63);
      float t0_1 = __shfl(r1, 0), t0_2 = __shfl(r2, 0), t0_3 = __shfl(r3, 0);

      float hu0 = lane ? su0 : 0.f;
      float hu1 = lane ? su1 : t63_0;
      float hu2 = lane ? su2 : t63_1;
      float hu3 = lane ? su3 : t63_2;
      float hd0 = (lane < 63) ? sd0 : t0_1;
      float hd1 = (lane < 63) ? sd1 : t0_2;
      float hd2 = (lane < 63) ? sd2 : t0_3;
      float hd3 = (lane < 63) ? sd3 : 0.f;

      r0 = prop_step(x0, a10, a20, a30, hu0, r0, hd0);
      r1 = prop_step(x1, a11, a21, a31, hu1, r1, hd1);
      r2 = prop_step(x2, a12, a22, a32, hu2, r2, hd2);
      r3 = prop_step(x3, a13, a23, a33, hu3, r3, hd3);

      float* po = &bo[e * 256];
      po[lane] = r0; po[lane + 64] = r1; po[lane + 128] = r2; po[lane + 192] = r3;
    }

    for (int j = 0; j < 16; ++j) {
      float4 v = *(const float4*)&bo[j * 256 + lane * 4];
      float4* dst = (float4*)(op + (size_t)(s0 + j) * P + lane * 4);
      if (FIRST) {
        *dst = v;
      } else {
        float4 o = *dst;
        o.x = fmaxf(o.x, v.x); o.y = fmaxf(o.y, v.y);
        o.z = fmaxf(o.z, v.z); o.w = fmaxf(o.w, v.w);
        *dst = o;
      }
    }
    cur ^= 1;
  }
}

// ---------- horizontal scan: X/out natural, fp16 gates transposed [x][y] ----------
template<int REV>
__global__ __launch_bounds__(64) void k_proph(
    const float* __restrict__ X, const _Float16* __restrict__ G,
    float* __restrict__ out, int S, int P)
{
  const int plane = blockIdx.x;
  const int b = plane >> 5, c = plane & 31;
  const int lane = threadIdx.x;
  const size_t ps = (size_t)S * P;
  const float* xp = X + (size_t)plane * ps;
  const _Float16* g1 = G + ((size_t)b * 96 + c) * ps;
  const _Float16* g2 = g1 + (size_t)32 * ps;
  const _Float16* g3 = g1 + (size_t)64 * ps;
  float* op = out + (size_t)plane * ps;

  __shared__ __align__(16) _Float16 h1[2][4096];
  __shared__ __align__(16) _Float16 h2[2][4096];
  __shared__ __align__(16) _Float16 h3[2][4096];

  float r0 = 0.f, r1 = 0.f, r2 = 0.f, r3 = 0.f;
  int cur = 0;

  auto stage = [&](int buf, int s0) {
#pragma unroll
    for (int v = 0; v < 8; ++v) {
      size_t ro = (size_t)(s0 + 2 * v) * P + lane * 8;
      gl_lds16p(g1 + ro, &h1[buf][v * 512]);
      gl_lds16p(g2 + ro, &h2[buf][v * 512]);
      gl_lds16p(g3 + ro, &h3[buf][v * 512]);
    }
  };

  stage(0, REV ? (S - 16) : 0);
  const int NT = S / 16;
  for (int t = 0; t < NT; ++t) {
    const int s0 = REV ? (S - 16 - t * 16) : (t * 16);

    asm volatile("s_waitcnt vmcnt(0)" ::: "memory");
    if (t + 1 < NT) stage(cur ^ 1, REV ? (s0 - 16) : (s0 + 16));

    float xv[4][16];
#pragma unroll
    for (int q = 0; q < 4; ++q) {
      const float* row = xp + (size_t)(lane + 64 * q) * S + s0;
#pragma unroll
      for (int j = 0; j < 4; ++j) {
        float4 v = *(const float4*)(row + 4 * j);
        xv[q][4 * j + 0] = v.x; xv[q][4 * j + 1] = v.y;
        xv[q][4 * j + 2] = v.z; xv[q][4 * j + 3] = v.w;
      }
    }

    float vo[4][16];
#pragma unroll
    for (int u = 0; u < 16; ++u) {
      const int e = REV ? (15 - u) : u;
      const _Float16* p1 = &h1[cur][e * 256];
      const _Float16* p2 = &h2[cur][e * 256];
      const _Float16* p3 = &h3[cur][e * 256];
      float a10 = p1[lane], a11 = p1[lane + 64], a12 = p1[lane + 128], a13 = p1[lane + 192];
      float a20 = p2[lane], a21 = p2[lane + 64], a22 = p2[lane + 128], a23 = p2[lane + 192];
      float a30 = p3[lane], a31 = p3[lane + 64], a32 = p3[lane + 128], a33 = p3[lane + 192];

      float su0 = __shfl_up(r0, 1), su1 = __shfl_up(r1, 1);
      float su2 = __shfl_up(r2, 1), su3 = __shfl_up(r3, 1);
      float sd0 = __shfl_down(r0, 1), sd1 = __shfl_down(r1, 1);
      float sd2 = __shfl_down(r2, 1), sd3 = __shfl_down(r3, 1);
      float t63_0 = __shfl(r0, 63), t63_1 = __shfl(r1, 63), t63_2 = __shfl(r2, 63);
      float t0_1 = __shfl(r1, 0), t0_2 = __shfl(r2, 0), t0_3 = __shfl(r3, 0);

      float hu0 = lane ? su0 : 0.f;
      float hu1 = lane ? su1 : t63_0;
      float hu2 = lane ? su2 : t63_1;
      float hu3 = lane ? su3 : t63_2;
      float hd0 = (lane < 63) ? sd0 : t0_1;
      float hd1 = (lane < 63) ? sd1 : t0_2;
      float hd2 = (lane < 63) ? sd2 : t0_3;
      float hd3 = (lane < 63) ? sd3 : 0.f;

      r0 = prop_step(xv[0][e], a10, a20, a30, hu0, r0, hd0);
      r1 = prop_step(xv[1][e], a11, a21, a31, hu1, r1, hd1);
      r2 = prop_step(xv[2][e], a12, a22, a32, hu2, r2, hd2);
      r3 = prop_step(xv[3][e], a13, a23, a33, hu3, r3, hd3);

      vo[0][e] = r0; vo[1][e] = r1; vo[2][e] = r2; vo[3][e] = r3;
    }

#pragma unroll
    for (int q = 0; q < 4; ++q) {
      float* row = op + (size_t)(lane + 64 * q) * S + s0;
#pragma unroll
      for (int j = 0; j < 4; ++j) {
        float4 o = *(const float4*)(row + 4 * j);
        o.x = fmaxf(o.x, vo[q][4 * j + 0]);
        o.y = fmaxf(o.y, vo[q][4 * j + 1]);
        o.z = fmaxf(o.z, vo[q][4 * j + 2]);
        o.w = fmaxf(o.w, vo[q][4 * j + 3]);
        *(float4*)(row + 4 * j) = o;
      }
    }
    cur ^= 1;
  }
}

// ---------------------------------------------------------------------------
extern "C" void kernel_launch(void* const* d_in, const int* in_sizes, int n_in,
                              void* d_out, int out_size, void* d_ws, size_t ws_size,
                              hipStream_t stream)
{
  const float* x   = (const float*)d_in[0];
  const float* rgb = (const float*)d_in[1];
  const float* mw  = (const float*)d_in[2];
  const float* mb  = (const float*)d_in[3];
  const float* c1w = (const float*)d_in[4];
  const float* c1b = (const float*)d_in[5];
  const float* c2w = (const float*)d_in[6];
  const float* c2b = (const float*)d_in[7];
  const float* c3w = (const float*)d_in[8];
  const float* c3b = (const float*)d_in[9];
  const float* c4w = (const float*)d_in[10];
  const float* c4b = (const float*)d_in[11];
  const float* d0w = (const float*)d_in[12];
  const float* d0b = (const float*)d_in[13];
  const float* d2w = (const float*)d_in[14];
  const float* d2b = (const float*)d_in[15];
  const float* d4w = (const float*)d_in[16];
  const float* d4b = (const float*)d_in[17];
  const float* d6w = (const float*)d_in[18];
  const float* d6b = (const float*)d_in[19];
  const float* d7w = (const float*)d_in[20];
  const float* d7b = (const float*)d_in[21];
  const float* pw  = (const float*)d_in[22];
  const float* pb  = (const float*)d_in[23];

  char* ws = (char*)d_ws;
  const size_t MB = 1024 * 1024;
  // Workspace (peak 216 MiB, proven):
  float* X    = (float*)(ws + 0);          // (4,32,256,256)  0-32
  float* f1   = (float*)(ws + 32 * MB);    // skip for d6     32-64
  float* f2   = (float*)(ws + 64 * MB);    // skip for d4     64-80
  float* f3   = (float*)(ws + 80 * MB);    // skip for d2     80-88
  float* p1   = (float*)(ws + 88 * MB);    // 88-96
  float* p2   = (float*)(ws + 96 * MB);    // 96-100
  float* p3   = (float*)(ws + 100 * MB);   // 100-102
  float* f4   = (float*)(ws + 102 * MB);   // 102-106
  float* o0   = (float*)(ws + 106 * MB);   // 106-108
  float* u0   = (float*)(ws + 108 * MB);   // (4,128,64,64)   108-116
  float* o1   = (float*)(ws + 132 * MB);   // (4,128,64,64)   132-140
  float* u1   = (float*)(ws + 80 * MB);    // (4,128,128,128) 80-112
  float* o2   = (float*)(ws + 200 * MB);   // (4,64,128,128)  200-216
  float* u2   = (float*)(ws + 64 * MB);    // (4,64,256,256)  64-128
  float* o3   = (float*)(ws + 132 * MB);   // (4,32,256,256)  132-164
  _Float16* ghalf = (_Float16*)(ws + 32 * MB); // (4,96,256,256) fp16 32-80
  float* om   = (float*)(ws + 164 * MB);   // 164-196
  // pack zone @196 MiB (~1.6 MB)
  char* wz = ws + 196 * MB;
  float* wmf  = (float*)wz;
  float* wc1f = wmf + 864;
  float* wpkf = wc1f + 864;
  _Float16* wc2p = (_Float16*)(wpkf + 864);
  _Float16* wc3p = wc2p + 19456;   // 2*64*152
  _Float16* wc4p = wc3p + 77824;   // 4*128*152
  _Float16* wd2p = wc4p + 311296;  // 8*256*152
  _Float16* wd4p = wd2p + 155648;  // 8*128*152
  _Float16* wd6p = wd4p + 77824;   // 8*64*152
  _Float16* wd7p = wd6p + 19456;   // 4*32*152
  // wd7p: 2*384*152

  dim3 blk(256);
  auto repf = [&](const float* s, float* d, int ci, int co) {
    int n = co * ci * 9;
    k_repack<<<dim3((n + 255) / 256), blk, 0, stream>>>(s, d, ci, co);
  };
  auto packh = [&](const float* s, _Float16* d, int ci, int co) {
    int n = co * (ci / 16) * 144;
    k_packwh<<<dim3((n + 255) / 256), blk, 0, stream>>>(s, d, ci, co);
  };
  repf(mw, wmf, 3, 32);
  repf(c1w, wc1f, 3, 32);
  repf(pw, wpkf, 32, 3);
  packh(c2w, wc2p, 32, 64);
  packh(c3w, wc3p, 64, 128);
  packh(c4w, wc4p, 128, 256);
  packh(d2w, wd2p, 128, 128);
  packh(d4w, wd4p, 128, 64);
  packh(d6w, wd6p, 64, 32);
  packh(d7w, wd7p, 32, 384);

  // X = conv(x); f1 = conv(rgb)  (f32, Cin=3)
  k_conv3x3f<3, 32><<<dim3(256, 1, 4), blk, 0, stream>>>(x,   wmf,  mb,  X,  3, 256, 256, 32, 32);
  k_conv3x3f<3, 32><<<dim3(256, 1, 4), blk, 0, stream>>>(rgb, wc1f, c1b, f1, 3, 256, 256, 32, 32);

  // Encoder (fp16 MFMA)
  k_pool<<<dim3(64, 32, 4), blk, 0, stream>>>(f1, p1, 32, 256, 256);
  k_convh<4, 1, 2, 2, 0, 0><<<dim3(128, 1, 4), dim3(256), 0, stream>>>(p1, wc2p, c2b, nullptr, f2, 128, 128, 64, 0, 64, 0);
  k_pool<<<dim3(16, 64, 4), blk, 0, stream>>>(f2, p2, 64, 128, 128);
  k_convh<2, 1, 2, 4, 0, 0><<<dim3(64, 2, 4), dim3(128), 0, stream>>>(p2, wc3p, c3b, nullptr, f3, 64, 64, 128, 0, 128, 0);
  k_pool<<<dim3(4, 128, 4), blk, 0, stream>>>(f3, p3, 128, 64, 64);
  k_convh<2, 1, 2, 8, 0, 0><<<dim3(16, 4, 4), dim3(128), 0, stream>>>(p3, wc4p, c4b, nullptr, f4, 32, 32, 256, 0, 256, 0);
  k_conv1x1<<<dim3(4, 128, 4), blk, 0, stream>>>(f4, d0w, d0b, o0, 256, 128, 32, 32);

  // Decoder: up2 then MFMA conv (elu+skip fused)  [MODE=1, GATES=0]
  k_up2<<<dim3(16, 128, 4), blk, 0, stream>>>(o0, u0, 128, 32, 32);
  k_convh<2, 1, 2, 8, 1, 0><<<dim3(64, 2, 4), dim3(128), 0, stream>>>(u0, wd2p, d2b, f3, o1, 64, 64, 128, 0, 128, 0);
  k_up2<<<dim3(64, 128, 4), blk, 0, stream>>>(o1, u1, 128, 64, 64);
  k_convh<4, 1, 2, 8, 1, 0><<<dim3(128, 1, 4), dim3(256), 0, stream>>>(u1, wd4p, d4b, f2, o2, 128, 128, 64, 0, 64, 0);
  k_up2<<<dim3(256, 64, 4), blk, 0, stream>>>(o2, u2, 64, 128, 128);
  k_convh<4, 1, 1, 4, 1, 0><<<dim3(512, 1, 4), dim3(256), 0, stream>>>(u2, wd6p, d6b, f1, o3, 256, 256, 32, 0, 32, 0);

  // Guide conv (d7) per direction (gates normalized + fp16) + scans.
  // k=2 vert fwd, k=3 vert rev (MODE 0), then k=0/k=1 horizontal (MODE 2).
  k_convh<4, 1, 3, 2, 0, 1><<<dim3(512, 1, 4), dim3(256), 0, stream>>>(o3, wd7p, d7b, nullptr, ghalf, 256, 256, 384, 192, 96, 0);
  k_propv<0, 1><<<dim3(128), dim3(64), 0, stream>>>(X, ghalf, om, 256, 256);
  k_convh<4, 1, 3, 2, 0, 1><<<dim3(512, 1, 4), dim3(256), 0, stream>>>(o3, wd7p, d7b, nullptr, ghalf, 256, 256, 384, 288, 96, 0);
  k_propv<1, 0><<<dim3(128), dim3(64), 0, stream>>>(X, ghalf, om, 256, 256);
  k_convh<4, 1, 3, 2, 2, 1><<<dim3(512, 1, 4), dim3(256), 0, stream>>>(o3, wd7p, d7b, nullptr, ghalf, 256, 256, 384, 0, 96, 0);
  k_proph<0><<<dim3(128), dim3(64), 0, stream>>>(X, ghalf, om, 256, 256);
  k_convh<4, 1, 3, 2, 2, 1><<<dim3(512, 1, 4), dim3(256), 0, stream>>>(o3, wd7p, d7b, nullptr, ghalf, 256, 256, 384, 96, 96, 0);
  k_proph<1><<<dim3(128), dim3(64), 0, stream>>>(X, ghalf, om, 256, 256);

  // Final conv (f32, Cout=3)
  k_conv3x3f<32, 3><<<dim3(256, 1, 4), blk, 0, stream>>>(om, wpkf, pb, (float*)d_out, 32, 256, 256, 3, 3);
}

// Round 9
// 1196.317 us; speedup vs baseline: 10.6114x; 1.2980x over previous
//
#include <hip/hip_runtime.h>
#include <cstddef>
#include <cstdint>

#define DEVINL __device__ __forceinline__

typedef __attribute__((ext_vector_type(8))) _Float16 half8v;
typedef __attribute__((ext_vector_type(16))) float f32x16;

constexpr int cmax(int a, int b) { return a > b ? a : b; }

// ---------------------------------------------------------------------------
// SPN forward, MI355X gfx950. B=4, H=W=256, NF=32.
// Round 9: LDS-staged coalesced epilogues (f32 rows = 64B lines, gate rows
// 16-32B) replacing 2-4B scattered stores. Conv core unchanged from round 8.
// ---------------------------------------------------------------------------

// ---------- f32 weight repack: OIHW -> [ci*9+k][Cout] (small convs) ----------
__global__ __launch_bounds__(256) void k_repack(
    const float* __restrict__ src, float* __restrict__ dst, int Cin, int Cout)
{
  int n = Cout * Cin * 9;
  int e = blockIdx.x * 256 + threadIdx.x;
  if (e >= n) return;
  int co = e / (Cin * 9);
  int r  = e - co * Cin * 9;
  int ci = r / 9;
  int k  = r - ci * 9;
  dst[(ci * 9 + k) * Cout + co] = src[e];
}

// ---------- fp16 weight pack: OIHW -> [cb][n][152], k = tap*16 + ci ----------
__global__ __launch_bounds__(256) void k_packwh(
    const float* __restrict__ src, _Float16* __restrict__ dst, int Cin, int Cout)
{
  int chunks = Cin >> 4;
  int total = Cout * chunks * 144;
  int e = blockIdx.x * 256 + threadIdx.x;
  if (e >= total) return;
  int n  = e / (chunks * 144);
  int r2 = e - n * chunks * 144;
  int cb = r2 / 144;
  int k  = r2 - cb * 144;
  int tap = k >> 4, ci = k & 15;
  float v = src[((size_t)n * Cin + cb * 16 + ci) * 9 + tap];
  dst[((size_t)cb * Cout + n) * 152 + k] = (_Float16)v;
}

// ---------- fp16 MFMA implicit-GEMM conv 3x3 pad 1, stage-once halo ----------
// M tile = NWM*32 px = (NWM*2) rows x 16 cols. N_BLK = NACC*32 (NWN==1).
// MODE 0: f32 out = conv+bias. MODE 1: f32 out = elu(conv+bias)+skip.
// MODE 2 (+GATES): transposed per-plane store out[ch][x][y].
// GATES=1 (NACC==3): per-lane g1,g2,g3 -> normalize -> fp16 store.
// All epilogues staged through LDS for coalesced global stores.
template<int NWM, int NACC, int CHUNKS, int MODE, int GATES>
__global__ __launch_bounds__(NWM * 64) void k_convh(
    const float* __restrict__ in, const _Float16* __restrict__ wpk,
    const float* __restrict__ bias, const float* __restrict__ skip,
    void* __restrict__ outv,
    int H, int W, int wCout, int n0, int outC, int oco0)
{
  static_assert(GATES == 0 || NACC == 3, "GATES needs NACC==3");
  constexpr int NTHR = NWM * 64;
  constexpr int ROWS = NWM * 2;
  constexpr int RH = ROWS + 2;
  constexpr int N_BLK = NACC * 32;
  constexpr int MT = NWM * 32;
  constexpr int A_BYTES = RH * 18 * 16 * 2;
  constexpr int B_BYTES = N_BLK * 152 * 2;
  constexpr int MPF = MT + 1;                       // f32 EP row stride (floats)
  constexpr int MPH = 132;                          // gates EP row stride (halves)
  constexpr int EP_BYTES = GATES ? (96 * MPH * 2) : (N_BLK * MPF * 4);
  constexpr int SMEM = cmax(A_BYTES + B_BYTES, EP_BYTES);

  const int tid = threadIdx.x;
  const int wave = tid >> 6, lane = tid & 63;
  const int wm = wave;
  const int tiles_x = W >> 4;
  const int tx0 = (blockIdx.x % tiles_x) << 4;
  const int ty0 = (blockIdx.x / tiles_x) * ROWS;
  const int b = blockIdx.z;
  const int nb = n0 + blockIdx.y * N_BLK;
  const int ocb = oco0 + blockIdx.y * N_BLK;

  __shared__ __align__(16) char smem[SMEM];
  _Float16* Ah = (_Float16*)smem;
  _Float16* Bh = (_Float16*)(smem + A_BYTES);

  f32x16 acc[NACC] = {};

  const size_t ps = (size_t)H * W;
  const float* inb = in + (size_t)b * (CHUNKS * 16) * ps;

  for (int cb = 0; cb < CHUNKS; ++cb) {
    __syncthreads();
    // ---- stage A: halo tile, 16 channels, natural layout ----
    for (int e = tid; e < RH * 18; e += NTHR) {
      int r = e / 18, c = e - r * 18;
      int gy = ty0 + r - 1, gx = tx0 + c - 1;
      bool ok = (unsigned)gy < (unsigned)H && (unsigned)gx < (unsigned)W;
      const float* src = inb + (size_t)(cb * 16) * ps + (size_t)gy * W + gx;
      half8v v0, v1;
#pragma unroll
      for (int j = 0; j < 8; ++j)
        v0[j] = ok ? (_Float16)src[(size_t)j * ps] : (_Float16)0.f;
#pragma unroll
      for (int j = 0; j < 8; ++j)
        v1[j] = ok ? (_Float16)src[(size_t)(j + 8) * ps] : (_Float16)0.f;
      *(half8v*)&Ah[e * 16] = v0;
      *(half8v*)&Ah[e * 16 + 8] = v1;
    }
    // ---- stage B (per chunk) ----
    {
      const _Float16* wsrc = wpk + ((size_t)cb * wCout + nb) * 152;
      for (int e = tid; e < N_BLK * 19; e += NTHR)
        *(uint4*)&Bh[e * 8] = *(const uint4*)(wsrc + e * 8);
    }
    __syncthreads();
    // ---- MFMA: 9 shifted tap-reads x NACC ----
    const int am = wm * 32 + (lane & 31);
    const int r0 = am >> 4, c0 = am & 15;
    const int kh = lane >> 5;
    const _Float16* Ab = Ah + kh * 8;
    const _Float16* Bb = Bh + kh * 8;
#pragma unroll
    for (int ks = 0; ks < 9; ++ks) {
      const int dy = ks / 3, dx = ks - dy * 3;
      half8v af = *(const half8v*)(Ab + ((r0 + dy) * 18 + (c0 + dx)) * 16);
#pragma unroll
      for (int na = 0; na < NACC; ++na) {
        const int bn = na * 32 + (lane & 31);
        half8v bf = *(const half8v*)(Bb + bn * 152 + ks * 16);
        acc[na] = __builtin_amdgcn_mfma_f32_32x32x16_f16(af, bf, acc[na], 0, 0, 0);
      }
    }
  }

  __syncthreads();  // staging buffers dead; reuse as epilogue buffer

  if (GATES) {
    _Float16* EPH = (_Float16*)smem;
    const int c = lane & 31;
    const float bv0 = bias[nb + c];
    const float bv1 = bias[nb + 32 + c];
    const float bv2 = bias[nb + 64 + c];
#pragma unroll
    for (int i = 0; i < 16; ++i) {
      int m = wm * 32 + (i & 3) + 8 * (i >> 2) + 4 * (lane >> 5);
      float g1 = acc[0][i] + bv0;
      float g2 = acc[GATES ? 1 : 0][i] + bv1;
      float g3 = acc[GATES ? 2 : 0][i] + bv2;
      float s = fabsf(g1) + fabsf(g2) + fabsf(g3);
      if (s >= 1.f) { float r = 1.f / s; g1 *= r; g2 *= r; g3 *= r; }
      EPH[(size_t)(0 * 32 + c) * MPH + m] = (_Float16)g1;
      EPH[(size_t)(1 * 32 + c) * MPH + m] = (_Float16)g2;
      EPH[(size_t)(2 * 32 + c) * MPH + m] = (_Float16)g3;
    }
    __syncthreads();
    _Float16* outh = (_Float16*)outv;
    if (MODE == 2) {
      // transposed plane [gc][x][y]: per row 8 y contiguous (16 B)
      const int TOT = 96 * 16;
      for (int r = tid; r < TOT; r += NTHR) {
        int gc = r >> 4, x = r & 15;
        const _Float16* ep = EPH + (size_t)gc * MPH + x;
        _Float16 v[8];
#pragma unroll
        for (int y = 0; y < 8; ++y) v[y] = ep[y * 16];
        size_t base = ((size_t)(b * 96 + gc) * W + tx0 + x) * (size_t)H + ty0;
        *(uint4*)(outh + base) = *(const uint4*)v;
      }
    } else {
      // natural plane [gc][y][x]: per row 16 x contiguous (32 B)
      const int TOT = 96 * ROWS;
      for (int r = tid; r < TOT; r += NTHR) {
        int gc = r / ROWS, y = r - gc * ROWS;
        const _Float16* ep = EPH + (size_t)gc * MPH + y * 16;
        _Float16 v[16];
#pragma unroll
        for (int x = 0; x < 16; ++x) v[x] = ep[x];
        size_t base = ((size_t)(b * 96 + gc) * H + ty0 + y) * (size_t)W + tx0;
        *(uint4*)(outh + base) = *(const uint4*)v;
        *(uint4*)(outh + base + 8) = *(const uint4*)(v + 8);
      }
    }
  } else {
    float* EP = (float*)smem;
    float bv[NACC];
#pragma unroll
    for (int na = 0; na < NACC; ++na) bv[na] = bias[nb + na * 32 + (lane & 31)];
#pragma unroll
    for (int na = 0; na < NACC; ++na) {
      const int c = na * 32 + (lane & 31);
#pragma unroll
      for (int i = 0; i < 16; ++i) {
        int m = wm * 32 + (i & 3) + 8 * (i >> 2) + 4 * (lane >> 5);
        EP[(size_t)c * MPF + m] = acc[na][i] + bv[na];
      }
    }
    __syncthreads();
    float* out = (float*)outv;
    const int TOT = N_BLK * ROWS;
    for (int r = tid; r < TOT; r += NTHR) {
      int c = r / ROWS, y = r - c * ROWS;
      const float* ep = EP + (size_t)c * MPF + y * 16;
      float v[16];
#pragma unroll
      for (int x = 0; x < 16; ++x) v[x] = ep[x];
      size_t base = (((size_t)b * outC + ocb + c) * H + ty0 + y) * (size_t)W + tx0;
      if (MODE == 1) {
#pragma unroll
        for (int j = 0; j < 4; ++j) {
          float4 sk = *(const float4*)(skip + base + 4 * j);
          float e0 = v[4*j+0] > 0.f ? v[4*j+0] : expm1f(v[4*j+0]);
          float e1 = v[4*j+1] > 0.f ? v[4*j+1] : expm1f(v[4*j+1]);
          float e2 = v[4*j+2] > 0.f ? v[4*j+2] : expm1f(v[4*j+2]);
          float e3 = v[4*j+3] > 0.f ? v[4*j+3] : expm1f(v[4*j+3]);
          v[4*j+0] = e0 + sk.x; v[4*j+1] = e1 + sk.y;
          v[4*j+2] = e2 + sk.z; v[4*j+3] = e3 + sk.w;
        }
      }
#pragma unroll
      for (int j = 0; j < 4; ++j)
        *(float4*)(out + base + 4 * j) = *(const float4*)(v + 4 * j);
    }
  }
}

// ---------- f32 tiled conv 3x3 (Cin=3 or Cout=3 small convs) ----------
template<int CI, int CO>
__global__ __launch_bounds__(256) void k_conv3x3f(
    const float* __restrict__ in, const float* __restrict__ wr,
    const float* __restrict__ bias, float* __restrict__ out,
    int Cin, int H, int W, int wstride, int outC)
{
  const int ntx = W >> 4;
  const int tid = threadIdx.x;
  const int tx = tid & 15, ty = tid >> 4;
  const int tx0 = (blockIdx.x % ntx) << 4, ty0 = (blockIdx.x / ntx) << 4;
  const int b = blockIdx.z;

  __shared__ float sh[CI * 324];

  float acc[CO];
#pragma unroll
  for (int co = 0; co < CO; ++co) acc[co] = bias[co];

  const float* inb = in + (size_t)b * Cin * H * W;

  for (int cb = 0; cb < Cin; cb += CI) {
    __syncthreads();
    for (int e = tid; e < CI * 324; e += 256) {
      int ci = e / 324;
      int rr = e - ci * 324;
      int r = rr / 18, c = rr - r * 18;
      int gh = ty0 + r - 1, gw = tx0 + c - 1;
      float v = 0.f;
      if ((unsigned)gh < (unsigned)H && (unsigned)gw < (unsigned)W)
        v = inb[(size_t)(cb + ci) * H * W + (size_t)gh * W + gw];
      sh[e] = v;
    }
    __syncthreads();
#pragma unroll 1
    for (int ci = 0; ci < CI; ++ci) {
      float v[9];
      const float* sp = sh + ci * 324 + ty * 18 + tx;
#pragma unroll
      for (int kh = 0; kh < 3; ++kh)
#pragma unroll
        for (int kw = 0; kw < 3; ++kw)
          v[kh * 3 + kw] = sp[kh * 18 + kw];
      const float* wp = wr + (size_t)((cb + ci) * 9) * wstride;
#pragma unroll
      for (int k = 0; k < 9; ++k)
#pragma unroll
        for (int co = 0; co < CO; ++co)
          acc[co] = fmaf(wp[(size_t)k * wstride + co], v[k], acc[co]);
    }
  }
#pragma unroll
  for (int co = 0; co < CO; ++co)
    out[(((size_t)b * outC + co) * H + ty0 + ty) * W + tx0 + tx] = acc[co];
}

// ---------- conv 1x1 (f32) ----------
__global__ __launch_bounds__(256) void k_conv1x1(
    const float* __restrict__ in, const float* __restrict__ wgt,
    const float* __restrict__ bias, float* __restrict__ out,
    int Cin, int Cout, int H, int W)
{
  int hw = blockIdx.x * 256 + threadIdx.x;
  if (hw >= H * W) return;
  int co = blockIdx.y, b = blockIdx.z;
  const float* ip = in + (size_t)b * Cin * H * W + hw;
  const float* wp = wgt + (size_t)co * Cin;
  float acc = bias[co];
  for (int ci = 0; ci < Cin; ++ci) acc += wp[ci] * ip[(size_t)ci * H * W];
  out[((size_t)b * Cout + co) * H * W + hw] = acc;
}

// ---------- relu + maxpool 3x3 stride 2 pad 1 ----------
__global__ __launch_bounds__(256) void k_pool(
    const float* __restrict__ in, float* __restrict__ out, int C, int H, int W)
{
  int Ho = H >> 1, Wo = W >> 1;
  int hw = blockIdx.x * 256 + threadIdx.x;
  if (hw >= Ho * Wo) return;
  int ow = hw % Wo, oh = hw / Wo;
  int c = blockIdx.y, b = blockIdx.z;
  const float* p = in + ((size_t)(b * C + c) * H) * W;
  float m = 0.f;
#pragma unroll
  for (int dh = -1; dh <= 1; ++dh) {
    int ih = 2 * oh + dh;
    if ((unsigned)ih >= (unsigned)H) continue;
    const float* r = p + (size_t)ih * W;
#pragma unroll
    for (int dw = -1; dw <= 1; ++dw) {
      int iw = 2 * ow + dw;
      if ((unsigned)iw >= (unsigned)W) continue;
      m = fmaxf(m, r[iw]);
    }
  }
  out[((size_t)(b * C + c) * Ho + oh) * Wo + ow] = m;
}

// ---------- bilinear 2x upsample ----------
__global__ __launch_bounds__(256) void k_up2(
    const float* __restrict__ in, float* __restrict__ out, int C, int H, int W)
{
  int Ho = H * 2, Wo = W * 2;
  int hw = blockIdx.x * 256 + threadIdx.x;
  if (hw >= Ho * Wo) return;
  int ow = hw % Wo, oh = hw / Wo;
  int c = blockIdx.y, b = blockIdx.z;
  int ih = oh >> 1, iw = ow >> 1;
  int ih0, ih1, iw0, iw1; float fh0, fw0;
  if (oh & 1) { ih0 = ih; ih1 = min(ih + 1, H - 1); fh0 = 0.75f; }
  else        { ih0 = max(ih - 1, 0); ih1 = ih;     fh0 = 0.25f; }
  if (ow & 1) { iw0 = iw; iw1 = min(iw + 1, W - 1); fw0 = 0.75f; }
  else        { iw0 = max(iw - 1, 0); iw1 = iw;     fw0 = 0.25f; }
  const float* p = in + ((size_t)(b * C + c) * H) * W;
  float v = fh0 * (fw0 * p[(size_t)ih0 * W + iw0] + (1.f - fw0) * p[(size_t)ih0 * W + iw1])
          + (1.f - fh0) * (fw0 * p[(size_t)ih1 * W + iw0] + (1.f - fw0) * p[(size_t)ih1 * W + iw1]);
  out[((size_t)(b * C + c) * Ho + oh) * Wo + ow] = v;
}

// ---------- gated scan helpers ----------
DEVINL void gl_lds16p(const void* g, void* lds) {
  __builtin_amdgcn_global_load_lds(
      (const __attribute__((address_space(1))) unsigned int*)g,
      (__attribute__((address_space(3))) unsigned int*)lds, 16, 0, 0);
}

DEVINL float prop_step(float xv, float a1, float a2, float a3,
                       float hu, float hc, float hd) {
  return (1.f - a1 - a2 - a3) * xv + a1 * hu + a2 * hc + a3 * hd;
}

// ---------- vertical scan (natural layout), fp16 pre-normalized gates ----------
template<int REV, int FIRST>
__global__ __launch_bounds__(64) void k_propv(
    const float* __restrict__ X, const _Float16* __restrict__ G,
    float* __restrict__ out, int S, int P)
{
  const int plane = blockIdx.x;
  const int b = plane >> 5, c = plane & 31;
  const int lane = threadIdx.x;
  const size_t ps = (size_t)S * P;
  const float* xp = X + (size_t)plane * ps;
  const _Float16* g1 = G + ((size_t)b * 96 + c) * ps;
  const _Float16* g2 = g1 + (size_t)32 * ps;
  const _Float16* g3 = g1 + (size_t)64 * ps;
  float* op = out + (size_t)plane * ps;

  __shared__ __align__(16) float bx[2][4096];
  __shared__ __align__(16) _Float16 h1[2][4096];
  __shared__ __align__(16) _Float16 h2[2][4096];
  __shared__ __align__(16) _Float16 h3[2][4096];
  __shared__ __align__(16) float bo[4096];

  float r0 = 0.f, r1 = 0.f, r2 = 0.f, r3 = 0.f;
  int cur = 0;

  auto stage = [&](int buf, int s0) {
#pragma unroll
    for (int u = 0; u < 16; ++u)
      gl_lds16p(xp + (size_t)(s0 + u) * P + lane * 4, &bx[buf][u * 256]);
#pragma unroll
    for (int v = 0; v < 8; ++v) {
      size_t ro = (size_t)(s0 + 2 * v) * P + lane * 8;
      gl_lds16p(g1 + ro, &h1[buf][v * 512]);
      gl_lds16p(g2 + ro, &h2[buf][v * 512]);
      gl_lds16p(g3 + ro, &h3[buf][v * 512]);
    }
  };

  stage(0, REV ? (S - 16) : 0);
  const int NT = S / 16;
  for (int t = 0; t < NT; ++t) {
    const int s0 = REV ? (S - 16 - t * 16) : (t * 16);
    asm volatile("s_waitcnt vmcnt(0)" ::: "memory");
    if (t + 1 < NT) stage(cur ^ 1, REV ? (s0 - 16) : (s0 + 16));

    for (int u = 0; u < 16; ++u) {
      const int e = REV ? (15 - u) : u;
      const float* px = &bx[cur][e * 256];
      const _Float16* p1 = &h1[cur][e * 256];
      const _Float16* p2 = &h2[cur][e * 256];
      const _Float16* p3 = &h3[cur][e * 256];
      float x0 = px[lane], x1 = px[lane + 64], x2 = px[lane + 128], x3 = px[lane + 192];
      float a10 = p1[lane], a11 = p1[lane + 64], a12 = p1[lane + 128], a13 = p1[lane + 192];
      float a20 = p2[lane], a21 = p2[lane + 64], a22 = p2[lane + 128], a23 = p2[lane + 192];
      float a30 = p3[lane], a31 = p3[lane + 64], a32 = p3[lane + 128], a33 = p3[lane + 192];

      float su0 = __shfl_up(r0, 1), su1 = __shfl_up(r1, 1);
      float su2 = __shfl_up(r2, 1), su3 = __shfl_up(r3, 1);
      float sd0 = __shfl_down(r0, 1), sd1 = __shfl_down(r1, 1);
      float sd2 = __shfl_down(r2, 1), sd3 = __shfl_down(r3, 1);
      float t63_0 = __shfl(r0, 63), t63_1 = __shfl(r1, 63), t63_2 = __shfl(r2, 63);
      float t0_1 = __shfl(r1, 0), t0_2 = __shfl(r2, 0), t0_3 = __shfl(r3, 0);

      float hu0 = lane ? su0 : 0.f;
      float hu1 = lane ? su1 : t63_0;
      float hu2 = lane ? su2 : t63_1;
      float hu3 = lane ? su3 : t63_2;
      float hd0 = (lane < 63) ? sd0 : t0_1;
      float hd1 = (lane < 63) ? sd1 : t0_2;
      float hd2 = (lane < 63) ? sd2 : t0_3;
      float hd3 = (lane < 63) ? sd3 : 0.f;

      r0 = prop_step(x0, a10, a20, a30, hu0, r0, hd0);
      r1 = prop_step(x1, a11, a21, a31, hu1, r1, hd1);
      r2 = prop_step(x2, a12, a22, a32, hu2, r2, hd2);
      r3 = prop_step(x3, a13, a23, a33, hu3, r3, hd3);

      float* po = &bo[e * 256];
      po[lane] = r0; po[lane + 64] = r1; po[lane + 128] = r2; po[lane + 192] = r3;
    }

    for (int j = 0; j < 16; ++j) {
      float4 v = *(const float4*)&bo[j * 256 + lane * 4];
      float4* dst = (float4*)(op + (size_t)(s0 + j) * P + lane * 4);
      if (FIRST) {
        *dst = v;
      } else {
        float4 o = *dst;
        o.x = fmaxf(o.x, v.x); o.y = fmaxf(o.y, v.y);
        o.z = fmaxf(o.z, v.z); o.w = fmaxf(o.w, v.w);
        *dst = o;
      }
    }
    cur ^= 1;
  }
}

// ---------- horizontal scan: X/out natural, fp16 gates transposed [x][y] ----------
template<int REV>
__global__ __launch_bounds__(64) void k_proph(
    const float* __restrict__ X, const _Float16* __restrict__ G,
    float* __restrict__ out, int S, int P)
{
  const int plane = blockIdx.x;
  const int b = plane >> 5, c = plane & 31;
  const int lane = threadIdx.x;
  const size_t ps = (size_t)S * P;
  const float* xp = X + (size_t)plane * ps;
  const _Float16* g1 = G + ((size_t)b * 96 + c) * ps;
  const _Float16* g2 = g1 + (size_t)32 * ps;
  const _Float16* g3 = g1 + (size_t)64 * ps;
  float* op = out + (size_t)plane * ps;

  __shared__ __align__(16) _Float16 h1[2][4096];
  __shared__ __align__(16) _Float16 h2[2][4096];
  __shared__ __align__(16) _Float16 h3[2][4096];

  float r0 = 0.f, r1 = 0.f, r2 = 0.f, r3 = 0.f;
  int cur = 0;

  auto stage = [&](int buf, int s0) {
#pragma unroll
    for (int v = 0; v < 8; ++v) {
      size_t ro = (size_t)(s0 + 2 * v) * P + lane * 8;
      gl_lds16p(g1 + ro, &h1[buf][v * 512]);
      gl_lds16p(g2 + ro, &h2[buf][v * 512]);
      gl_lds16p(g3 + ro, &h3[buf][v * 512]);
    }
  };

  stage(0, REV ? (S - 16) : 0);
  const int NT = S / 16;
  for (int t = 0; t < NT; ++t) {
    const int s0 = REV ? (S - 16 - t * 16) : (t * 16);

    asm volatile("s_waitcnt vmcnt(0)" ::: "memory");
    if (t + 1 < NT) stage(cur ^ 1, REV ? (s0 - 16) : (s0 + 16));

    float xv[4][16];
#pragma unroll
    for (int q = 0; q < 4; ++q) {
      const float* row = xp + (size_t)(lane + 64 * q) * S + s0;
#pragma unroll
      for (int j = 0; j < 4; ++j) {
        float4 v = *(const float4*)(row + 4 * j);
        xv[q][4 * j + 0] = v.x; xv[q][4 * j + 1] = v.y;
        xv[q][4 * j + 2] = v.z; xv[q][4 * j + 3] = v.w;
      }
    }

    float vo[4][16];
#pragma unroll
    for (int u = 0; u < 16; ++u) {
      const int e = REV ? (15 - u) : u;
      const _Float16* p1 = &h1[cur][e * 256];
      const _Float16* p2 = &h2[cur][e * 256];
      const _Float16* p3 = &h3[cur][e * 256];
      float a10 = p1[lane], a11 = p1[lane + 64], a12 = p1[lane + 128], a13 = p1[lane + 192];
      float a20 = p2[lane], a21 = p2[lane + 64], a22 = p2[lane + 128], a23 = p2[lane + 192];
      float a30 = p3[lane], a31 = p3[lane + 64], a32 = p3[lane + 128], a33 = p3[lane + 192];

      float su0 = __shfl_up(r0, 1), su1 = __shfl_up(r1, 1);
      float su2 = __shfl_up(r2, 1), su3 = __shfl_up(r3, 1);
      float sd0 = __shfl_down(r0, 1), sd1 = __shfl_down(r1, 1);
      float sd2 = __shfl_down(r2, 1), sd3 = __shfl_down(r3, 1);
      float t63_0 = __shfl(r0, 63), t63_1 = __shfl(r1, 63), t63_2 = __shfl(r2, 63);
      float t0_1 = __shfl(r1, 0), t0_2 = __shfl(r2, 0), t0_3 = __shfl(r3, 0);

      float hu0 = lane ? su0 : 0.f;
      float hu1 = lane ? su1 : t63_0;
      float hu2 = lane ? su2 : t63_1;
      float hu3 = lane ? su3 : t63_2;
      float hd0 = (lane < 63) ? sd0 : t0_1;
      float hd1 = (lane < 63) ? sd1 : t0_2;
      float hd2 = (lane < 63) ? sd2 : t0_3;
      float hd3 = (lane < 63) ? sd3 : 0.f;

      r0 = prop_step(xv[0][e], a10, a20, a30, hu0, r0, hd0);
      r1 = prop_step(xv[1][e], a11, a21, a31, hu1, r1, hd1);
      r2 = prop_step(xv[2][e], a12, a22, a32, hu2, r2, hd2);
      r3 = prop_step(xv[3][e], a13, a23, a33, hu3, r3, hd3);

      vo[0][e] = r0; vo[1][e] = r1; vo[2][e] = r2; vo[3][e] = r3;
    }

#pragma unroll
    for (int q = 0; q < 4; ++q) {
      float* row = op + (size_t)(lane + 64 * q) * S + s0;
#pragma unroll
      for (int j = 0; j < 4; ++j) {
        float4 o = *(const float4*)(row + 4 * j);
        o.x = fmaxf(o.x, vo[q][4 * j + 0]);
        o.y = fmaxf(o.y, vo[q][4 * j + 1]);
        o.z = fmaxf(o.z, vo[q][4 * j + 2]);
        o.w = fmaxf(o.w, vo[q][4 * j + 3]);
        *(float4*)(row + 4 * j) = o;
      }
    }
    cur ^= 1;
  }
}

// ---------------------------------------------------------------------------
extern "C" void kernel_launch(void* const* d_in, const int* in_sizes, int n_in,
                              void* d_out, int out_size, void* d_ws, size_t ws_size,
                              hipStream_t stream)
{
  const float* x   = (const float*)d_in[0];
  const float* rgb = (const float*)d_in[1];
  const float* mw  = (const float*)d_in[2];
  const float* mb  = (const float*)d_in[3];
  const float* c1w = (const float*)d_in[4];
  const float* c1b = (const float*)d_in[5];
  const float* c2w = (const float*)d_in[6];
  const float* c2b = (const float*)d_in[7];
  const float* c3w = (const float*)d_in[8];
  const float* c3b = (const float*)d_in[9];
  const float* c4w = (const float*)d_in[10];
  const float* c4b = (const float*)d_in[11];
  const float* d0w = (const float*)d_in[12];
  const float* d0b = (const float*)d_in[13];
  const float* d2w = (const float*)d_in[14];
  const float* d2b = (const float*)d_in[15];
  const float* d4w = (const float*)d_in[16];
  const float* d4b = (const float*)d_in[17];
  const float* d6w = (const float*)d_in[18];
  const float* d6b = (const float*)d_in[19];
  const float* d7w = (const float*)d_in[20];
  const float* d7b = (const float*)d_in[21];
  const float* pw  = (const float*)d_in[22];
  const float* pb  = (const float*)d_in[23];

  char* ws = (char*)d_ws;
  const size_t MB = 1024 * 1024;
  // Workspace (peak 216 MiB, proven):
  float* X    = (float*)(ws + 0);          // (4,32,256,256)  0-32
  float* f1   = (float*)(ws + 32 * MB);    // skip for d6     32-64
  float* f2   = (float*)(ws + 64 * MB);    // skip for d4     64-80
  float* f3   = (float*)(ws + 80 * MB);    // skip for d2     80-88
  float* p1   = (float*)(ws + 88 * MB);    // 88-96
  float* p2   = (float*)(ws + 96 * MB);    // 96-100
  float* p3   = (float*)(ws + 100 * MB);   // 100-102
  float* f4   = (float*)(ws + 102 * MB);   // 102-106
  float* o0   = (float*)(ws + 106 * MB);   // 106-108
  float* u0   = (float*)(ws + 108 * MB);   // (4,128,64,64)   108-116
  float* o1   = (float*)(ws + 132 * MB);   // (4,128,64,64)   132-140
  float* u1   = (float*)(ws + 80 * MB);    // (4,128,128,128) 80-112
  float* o2   = (float*)(ws + 200 * MB);   // (4,64,128,128)  200-216
  float* u2   = (float*)(ws + 64 * MB);    // (4,64,256,256)  64-128
  float* o3   = (float*)(ws + 132 * MB);   // (4,32,256,256)  132-164
  _Float16* ghalf = (_Float16*)(ws + 32 * MB); // (4,96,256,256) fp16 32-80
  float* om   = (float*)(ws + 164 * MB);   // 164-196
  // pack zone @196 MiB (~1.6 MB)
  char* wz = ws + 196 * MB;
  float* wmf  = (float*)wz;
  float* wc1f = wmf + 864;
  float* wpkf = wc1f + 864;
  _Float16* wc2p = (_Float16*)(wpkf + 864);
  _Float16* wc3p = wc2p + 19456;   // 2*64*152
  _Float16* wc4p = wc3p + 77824;   // 4*128*152
  _Float16* wd2p = wc4p + 311296;  // 8*256*152
  _Float16* wd4p = wd2p + 155648;  // 8*128*152
  _Float16* wd6p = wd4p + 77824;   // 8*64*152
  _Float16* wd7p = wd6p + 19456;   // 4*32*152
  // wd7p: 2*384*152

  dim3 blk(256);
  auto repf = [&](const float* s, float* d, int ci, int co) {
    int n = co * ci * 9;
    k_repack<<<dim3((n + 255) / 256), blk, 0, stream>>>(s, d, ci, co);
  };
  auto packh = [&](const float* s, _Float16* d, int ci, int co) {
    int n = co * (ci / 16) * 144;
    k_packwh<<<dim3((n + 255) / 256), blk, 0, stream>>>(s, d, ci, co);
  };
  repf(mw, wmf, 3, 32);
  repf(c1w, wc1f, 3, 32);
  repf(pw, wpkf, 32, 3);
  packh(c2w, wc2p, 32, 64);
  packh(c3w, wc3p, 64, 128);
  packh(c4w, wc4p, 128, 256);
  packh(d2w, wd2p, 128, 128);
  packh(d4w, wd4p, 128, 64);
  packh(d6w, wd6p, 64, 32);
  packh(d7w, wd7p, 32, 384);

  // X = conv(x); f1 = conv(rgb)  (f32, Cin=3)
  k_conv3x3f<3, 32><<<dim3(256, 1, 4), blk, 0, stream>>>(x,   wmf,  mb,  X,  3, 256, 256, 32, 32);
  k_conv3x3f<3, 32><<<dim3(256, 1, 4), blk, 0, stream>>>(rgb, wc1f, c1b, f1, 3, 256, 256, 32, 32);

  // Encoder (fp16 MFMA)
  k_pool<<<dim3(64, 32, 4), blk, 0, stream>>>(f1, p1, 32, 256, 256);
  k_convh<4, 2, 2, 0, 0><<<dim3(128, 1, 4), dim3(256), 0, stream>>>(p1, wc2p, c2b, nullptr, f2, 128, 128, 64, 0, 64, 0);
  k_pool<<<dim3(16, 64, 4), blk, 0, stream>>>(f2, p2, 64, 128, 128);
  k_convh<2, 2, 4, 0, 0><<<dim3(64, 2, 4), dim3(128), 0, stream>>>(p2, wc3p, c3b, nullptr, f3, 64, 64, 128, 0, 128, 0);
  k_pool<<<dim3(4, 128, 4), blk, 0, stream>>>(f3, p3, 128, 64, 64);
  k_convh<2, 2, 8, 0, 0><<<dim3(16, 4, 4), dim3(128), 0, stream>>>(p3, wc4p, c4b, nullptr, f4, 32, 32, 256, 0, 256, 0);
  k_conv1x1<<<dim3(4, 128, 4), blk, 0, stream>>>(f4, d0w, d0b, o0, 256, 128, 32, 32);

  // Decoder: up2 then MFMA conv (elu+skip fused)  [MODE=1, GATES=0]
  k_up2<<<dim3(16, 128, 4), blk, 0, stream>>>(o0, u0, 128, 32, 32);
  k_convh<2, 2, 8, 1, 0><<<dim3(64, 2, 4), dim3(128), 0, stream>>>(u0, wd2p, d2b, f3, o1, 64, 64, 128, 0, 128, 0);
  k_up2<<<dim3(64, 128, 4), blk, 0, stream>>>(o1, u1, 128, 64, 64);
  k_convh<4, 2, 8, 1, 0><<<dim3(128, 1, 4), dim3(256), 0, stream>>>(u1, wd4p, d4b, f2, o2, 128, 128, 64, 0, 64, 0);
  k_up2<<<dim3(256, 64, 4), blk, 0, stream>>>(o2, u2, 64, 128, 128);
  k_convh<4, 1, 4, 1, 0><<<dim3(512, 1, 4), dim3(256), 0, stream>>>(u2, wd6p, d6b, f1, o3, 256, 256, 32, 0, 32, 0);

  // Guide conv (d7) per direction (gates normalized + fp16) + scans.
  // k=2 vert fwd, k=3 vert rev (MODE 0), then k=0/k=1 horizontal (MODE 2).
  k_convh<4, 3, 2, 0, 1><<<dim3(512, 1, 4), dim3(256), 0, stream>>>(o3, wd7p, d7b, nullptr, ghalf, 256, 256, 384, 192, 96, 0);
  k_propv<0, 1><<<dim3(128), dim3(64), 0, stream>>>(X, ghalf, om, 256, 256);
  k_convh<4, 3, 2, 0, 1><<<dim3(512, 1, 4), dim3(256), 0, stream>>>(o3, wd7p, d7b, nullptr, ghalf, 256, 256, 384, 288, 96, 0);
  k_propv<1, 0><<<dim3(128), dim3(64), 0, stream>>>(X, ghalf, om, 256, 256);
  k_convh<4, 3, 2, 2, 1><<<dim3(512, 1, 4), dim3(256), 0, stream>>>(o3, wd7p, d7b, nullptr, ghalf, 256, 256, 384, 0, 96, 0);
  k_proph<0><<<dim3(128), dim3(64), 0, stream>>>(X, ghalf, om, 256, 256);
  k_convh<4, 3, 2, 2, 1><<<dim3(512, 1, 4), dim3(256), 0, stream>>>(o3, wd7p, d7b, nullptr, ghalf, 256, 256, 384, 96, 96, 0);
  k_proph<1><<<dim3(128), dim3(64), 0, stream>>>(X, ghalf, om, 256, 256);

  // Final conv (f32, Cout=3)
  k_conv3x3f<32, 3><<<dim3(256, 1, 4), blk, 0, stream>>>(om, wpkf, pb, (float*)d_out, 32, 256, 256, 3, 3);
}

// Round 11
// 972.619 us; speedup vs baseline: 13.0519x; 1.2300x over previous
//
#include <hip/hip_runtime.h>
#include <cstddef>
#include <cstdint>

#define DEVINL __device__ __forceinline__

typedef __attribute__((ext_vector_type(8))) _Float16 half8v;
typedef __attribute__((ext_vector_type(16))) float f32x16;

constexpr int cmax(int a, int b) { return a > b ? a : b; }

// ---------------------------------------------------------------------------
// SPN forward, MI355X gfx950. B=4, H=W=256, NF=32.
// Round 11: round-10 structure + airtight workspace relayout + full ws
// zero-init each call (hipMemsetAsync) to guarantee replay determinism.
// ---------------------------------------------------------------------------

// ---------- f32 weight repack: OIHW -> [ci*9+k][Cout] (small convs) ----------
__global__ __launch_bounds__(256) void k_repack(
    const float* __restrict__ src, float* __restrict__ dst, int Cin, int Cout)
{
  int n = Cout * Cin * 9;
  int e = blockIdx.x * 256 + threadIdx.x;
  if (e >= n) return;
  int co = e / (Cin * 9);
  int r  = e - co * Cin * 9;
  int ci = r / 9;
  int k  = r - ci * 9;
  dst[(ci * 9 + k) * Cout + co] = src[e];
}

// ---------- fp16 weight pack: OIHW -> [cb][n][152], k = tap*16 + ci ----------
__global__ __launch_bounds__(256) void k_packwh(
    const float* __restrict__ src, _Float16* __restrict__ dst, int Cin, int Cout)
{
  int chunks = Cin >> 4;
  int total = Cout * chunks * 144;
  int e = blockIdx.x * 256 + threadIdx.x;
  if (e >= total) return;
  int n  = e / (chunks * 144);
  int r2 = e - n * chunks * 144;
  int cb = r2 / 144;
  int k  = r2 - cb * 144;
  int tap = k >> 4, ci = k & 15;
  float v = src[((size_t)n * Cin + cb * 16 + ci) * 9 + tap];
  dst[((size_t)cb * Cout + n) * 152 + k] = (_Float16)v;
}

// ---------- fp16 MFMA implicit-GEMM conv 3x3 pad 1, stage-once halo ----------
template<int NWM, int NACC, int CHUNKS, int MODE, int GATES>
__global__ __launch_bounds__(NWM * 64) void k_convh(
    const float* __restrict__ in, const _Float16* __restrict__ wpk,
    const float* __restrict__ bias, const float* __restrict__ skip,
    void* __restrict__ outv,
    int H, int W, int wCout, int n0, int outC, int oco0)
{
  static_assert(GATES == 0 || NACC == 3, "GATES needs NACC==3");
  constexpr int NTHR = NWM * 64;
  constexpr int ROWS = NWM * 2;
  constexpr int RH = ROWS + 2;
  constexpr int N_BLK = NACC * 32;
  constexpr int MT = NWM * 32;
  constexpr int A_BYTES = RH * 18 * 16 * 2;
  constexpr int B_BYTES = N_BLK * 152 * 2;
  constexpr int MPF = MT + 1;
  constexpr int MPH = 132;
  constexpr int EP_BYTES = GATES ? (96 * MPH * 2) : (N_BLK * MPF * 4);
  constexpr int SMEM = cmax(A_BYTES + B_BYTES, EP_BYTES);

  const int tid = threadIdx.x;
  const int wave = tid >> 6, lane = tid & 63;
  const int wm = wave;
  const int tiles_x = W >> 4;
  const int tx0 = (blockIdx.x % tiles_x) << 4;
  const int ty0 = (blockIdx.x / tiles_x) * ROWS;
  const int b = blockIdx.z;
  const int nb = n0 + blockIdx.y * N_BLK;
  const int ocb = oco0 + blockIdx.y * N_BLK;

  __shared__ __align__(16) char smem[SMEM];
  _Float16* Ah = (_Float16*)smem;
  _Float16* Bh = (_Float16*)(smem + A_BYTES);

  f32x16 acc[NACC] = {};

  const size_t ps = (size_t)H * W;
  const float* inb = in + (size_t)b * (CHUNKS * 16) * ps;

  for (int cb = 0; cb < CHUNKS; ++cb) {
    __syncthreads();
    for (int e = tid; e < RH * 18; e += NTHR) {
      int r = e / 18, c = e - r * 18;
      int gy = ty0 + r - 1, gx = tx0 + c - 1;
      bool ok = (unsigned)gy < (unsigned)H && (unsigned)gx < (unsigned)W;
      const float* src = inb + (size_t)(cb * 16) * ps + (size_t)gy * W + gx;
      half8v v0, v1;
#pragma unroll
      for (int j = 0; j < 8; ++j)
        v0[j] = ok ? (_Float16)src[(size_t)j * ps] : (_Float16)0.f;
#pragma unroll
      for (int j = 0; j < 8; ++j)
        v1[j] = ok ? (_Float16)src[(size_t)(j + 8) * ps] : (_Float16)0.f;
      *(half8v*)&Ah[e * 16] = v0;
      *(half8v*)&Ah[e * 16 + 8] = v1;
    }
    {
      const _Float16* wsrc = wpk + ((size_t)cb * wCout + nb) * 152;
      for (int e = tid; e < N_BLK * 19; e += NTHR)
        *(uint4*)&Bh[e * 8] = *(const uint4*)(wsrc + e * 8);
    }
    __syncthreads();
    const int am = wm * 32 + (lane & 31);
    const int r0 = am >> 4, c0 = am & 15;
    const int kh = lane >> 5;
    const _Float16* Ab = Ah + kh * 8;
    const _Float16* Bb = Bh + kh * 8;
#pragma unroll
    for (int ks = 0; ks < 9; ++ks) {
      const int dy = ks / 3, dx = ks - dy * 3;
      half8v af = *(const half8v*)(Ab + ((r0 + dy) * 18 + (c0 + dx)) * 16);
#pragma unroll
      for (int na = 0; na < NACC; ++na) {
        const int bn = na * 32 + (lane & 31);
        half8v bf = *(const half8v*)(Bb + bn * 152 + ks * 16);
        acc[na] = __builtin_amdgcn_mfma_f32_32x32x16_f16(af, bf, acc[na], 0, 0, 0);
      }
    }
  }

  __syncthreads();

  if (GATES) {
    _Float16* EPH = (_Float16*)smem;
    const int c = lane & 31;
    const float bv0 = bias[nb + c];
    const float bv1 = bias[nb + 32 + c];
    const float bv2 = bias[nb + 64 + c];
#pragma unroll
    for (int i = 0; i < 16; ++i) {
      int m = wm * 32 + (i & 3) + 8 * (i >> 2) + 4 * (lane >> 5);
      float g1 = acc[0][i] + bv0;
      float g2 = acc[GATES ? 1 : 0][i] + bv1;
      float g3 = acc[GATES ? 2 : 0][i] + bv2;
      float s = fabsf(g1) + fabsf(g2) + fabsf(g3);
      if (s >= 1.f) { float r = 1.f / s; g1 *= r; g2 *= r; g3 *= r; }
      EPH[(size_t)(0 * 32 + c) * MPH + m] = (_Float16)g1;
      EPH[(size_t)(1 * 32 + c) * MPH + m] = (_Float16)g2;
      EPH[(size_t)(2 * 32 + c) * MPH + m] = (_Float16)g3;
    }
    __syncthreads();
    _Float16* outh = (_Float16*)outv;
    if (MODE == 2) {
      const int TOT = 96 * 16;
      for (int r = tid; r < TOT; r += NTHR) {
        int gc = r >> 4, x = r & 15;
        const _Float16* ep = EPH + (size_t)gc * MPH + x;
        _Float16 v[8];
#pragma unroll
        for (int y = 0; y < 8; ++y) v[y] = ep[y * 16];
        size_t base = ((size_t)(b * 96 + gc) * W + tx0 + x) * (size_t)H + ty0;
        *(uint4*)(outh + base) = *(const uint4*)v;
      }
    } else {
      const int TOT = 96 * ROWS;
      for (int r = tid; r < TOT; r += NTHR) {
        int gc = r / ROWS, y = r - gc * ROWS;
        const _Float16* ep = EPH + (size_t)gc * MPH + y * 16;
        _Float16 v[16];
#pragma unroll
        for (int x = 0; x < 16; ++x) v[x] = ep[x];
        size_t base = ((size_t)(b * 96 + gc) * H + ty0 + y) * (size_t)W + tx0;
        *(uint4*)(outh + base) = *(const uint4*)v;
        *(uint4*)(outh + base + 8) = *(const uint4*)(v + 8);
      }
    }
  } else {
    float* EP = (float*)smem;
    float bv[NACC];
#pragma unroll
    for (int na = 0; na < NACC; ++na) bv[na] = bias[nb + na * 32 + (lane & 31)];
#pragma unroll
    for (int na = 0; na < NACC; ++na) {
      const int c = na * 32 + (lane & 31);
#pragma unroll
      for (int i = 0; i < 16; ++i) {
        int m = wm * 32 + (i & 3) + 8 * (i >> 2) + 4 * (lane >> 5);
        EP[(size_t)c * MPF + m] = acc[na][i] + bv[na];
      }
    }
    __syncthreads();
    float* out = (float*)outv;
    const int TOT = N_BLK * ROWS;
    for (int r = tid; r < TOT; r += NTHR) {
      int c = r / ROWS, y = r - c * ROWS;
      const float* ep = EP + (size_t)c * MPF + y * 16;
      float v[16];
#pragma unroll
      for (int x = 0; x < 16; ++x) v[x] = ep[x];
      size_t base = (((size_t)b * outC + ocb + c) * H + ty0 + y) * (size_t)W + tx0;
      if (MODE == 1) {
#pragma unroll
        for (int j = 0; j < 4; ++j) {
          float4 sk = *(const float4*)(skip + base + 4 * j);
          float e0 = v[4*j+0] > 0.f ? v[4*j+0] : expm1f(v[4*j+0]);
          float e1 = v[4*j+1] > 0.f ? v[4*j+1] : expm1f(v[4*j+1]);
          float e2 = v[4*j+2] > 0.f ? v[4*j+2] : expm1f(v[4*j+2]);
          float e3 = v[4*j+3] > 0.f ? v[4*j+3] : expm1f(v[4*j+3]);
          v[4*j+0] = e0 + sk.x; v[4*j+1] = e1 + sk.y;
          v[4*j+2] = e2 + sk.z; v[4*j+3] = e3 + sk.w;
        }
      }
#pragma unroll
      for (int j = 0; j < 4; ++j)
        *(float4*)(out + base + 4 * j) = *(const float4*)(v + 4 * j);
    }
  }
}

// ---------- f32 tiled conv 3x3 (Cin=3 convs) ----------
template<int CI, int CO>
__global__ __launch_bounds__(256) void k_conv3x3f(
    const float* __restrict__ in, const float* __restrict__ wr,
    const float* __restrict__ bias, float* __restrict__ out,
    int Cin, int H, int W, int wstride, int outC)
{
  const int ntx = W >> 4;
  const int tid = threadIdx.x;
  const int tx = tid & 15, ty = tid >> 4;
  const int tx0 = (blockIdx.x % ntx) << 4, ty0 = (blockIdx.x / ntx) << 4;
  const int b = blockIdx.z;

  __shared__ float sh[CI * 324];

  float acc[CO];
#pragma unroll
  for (int co = 0; co < CO; ++co) acc[co] = bias[co];

  const float* inb = in + (size_t)b * Cin * H * W;

  for (int cb = 0; cb < Cin; cb += CI) {
    __syncthreads();
    for (int e = tid; e < CI * 324; e += 256) {
      int ci = e / 324;
      int rr = e - ci * 324;
      int r = rr / 18, c = rr - r * 18;
      int gh = ty0 + r - 1, gw = tx0 + c - 1;
      float v = 0.f;
      if ((unsigned)gh < (unsigned)H && (unsigned)gw < (unsigned)W)
        v = inb[(size_t)(cb + ci) * H * W + (size_t)gh * W + gw];
      sh[e] = v;
    }
    __syncthreads();
#pragma unroll 1
    for (int ci = 0; ci < CI; ++ci) {
      float v[9];
      const float* sp = sh + ci * 324 + ty * 18 + tx;
#pragma unroll
      for (int kh = 0; kh < 3; ++kh)
#pragma unroll
        for (int kw = 0; kw < 3; ++kw)
          v[kh * 3 + kw] = sp[kh * 18 + kw];
      const float* wp = wr + (size_t)((cb + ci) * 9) * wstride;
#pragma unroll
      for (int k = 0; k < 9; ++k)
#pragma unroll
        for (int co = 0; co < CO; ++co)
          acc[co] = fmaf(wp[(size_t)k * wstride + co], v[k], acc[co]);
    }
  }
#pragma unroll
  for (int co = 0; co < CO; ++co)
    out[(((size_t)b * outC + co) * H + ty0 + ty) * W + tx0 + tx] = acc[co];
}

// ---------- final conv: in = max(om1,om2, omT1^T,omT2^T) fp16, out f32 ----------
__global__ __launch_bounds__(256) void k_convfin(
    const _Float16* __restrict__ om1, const _Float16* __restrict__ om2,
    const _Float16* __restrict__ omT1, const _Float16* __restrict__ omT2,
    const float* __restrict__ wr, const float* __restrict__ bias,
    float* __restrict__ out)
{
  const int H = 256, W = 256;
  const int tid = threadIdx.x;
  const int tx = tid & 15, ty = tid >> 4;
  const int tx0 = (blockIdx.x & 15) << 4, ty0 = (blockIdx.x >> 4) << 4;
  const int b = blockIdx.z;

  __shared__ float sh[32 * 324];

  for (int e = tid; e < 32 * 324; e += 256) {
    int ci = e / 324, rr = e - ci * 324;
    int r = rr / 18, c = rr - r * 18;
    int gh = ty0 + r - 1, gw = tx0 + c - 1;
    float v = 0.f;
    if ((unsigned)gh < (unsigned)H && (unsigned)gw < (unsigned)W) {
      size_t p = ((size_t)(b * 32 + ci) * H + gh) * W + gw;
      v = fmaxf((float)om1[p], (float)om2[p]);
    }
    sh[ci * 324 + r * 18 + c] = v;
  }
  __syncthreads();
  for (int e = tid; e < 32 * 324; e += 256) {
    int ci = e / 324, rr = e - ci * 324;
    int c = rr / 18, r = rr - c * 18;
    int gh = ty0 + r - 1, gw = tx0 + c - 1;
    if ((unsigned)gh < (unsigned)H && (unsigned)gw < (unsigned)W) {
      size_t p = ((size_t)(b * 32 + ci) * W + gw) * (size_t)H + gh;
      float t = fmaxf((float)omT1[p], (float)omT2[p]);
      int si = ci * 324 + r * 18 + c;
      sh[si] = fmaxf(sh[si], t);
    }
  }
  __syncthreads();

  float acc[3] = {bias[0], bias[1], bias[2]};
#pragma unroll 1
  for (int ci = 0; ci < 32; ++ci) {
    float v[9];
    const float* sp = sh + ci * 324 + ty * 18 + tx;
#pragma unroll
    for (int kh = 0; kh < 3; ++kh)
#pragma unroll
      for (int kw = 0; kw < 3; ++kw)
        v[kh * 3 + kw] = sp[kh * 18 + kw];
    const float* wp = wr + (size_t)(ci * 9) * 3;
#pragma unroll
    for (int k = 0; k < 9; ++k)
#pragma unroll
      for (int co = 0; co < 3; ++co)
        acc[co] = fmaf(wp[(size_t)k * 3 + co], v[k], acc[co]);
  }
#pragma unroll
  for (int co = 0; co < 3; ++co)
    out[(((size_t)b * 3 + co) * H + ty0 + ty) * W + tx0 + tx] = acc[co];
}

// ---------- conv 1x1 (f32) ----------
__global__ __launch_bounds__(256) void k_conv1x1(
    const float* __restrict__ in, const float* __restrict__ wgt,
    const float* __restrict__ bias, float* __restrict__ out,
    int Cin, int Cout, int H, int W)
{
  int hw = blockIdx.x * 256 + threadIdx.x;
  if (hw >= H * W) return;
  int co = blockIdx.y, b = blockIdx.z;
  const float* ip = in + (size_t)b * Cin * H * W + hw;
  const float* wp = wgt + (size_t)co * Cin;
  float acc = bias[co];
  for (int ci = 0; ci < Cin; ++ci) acc += wp[ci] * ip[(size_t)ci * H * W];
  out[((size_t)b * Cout + co) * H * W + hw] = acc;
}

// ---------- relu + maxpool 3x3 stride 2 pad 1 ----------
__global__ __launch_bounds__(256) void k_pool(
    const float* __restrict__ in, float* __restrict__ out, int C, int H, int W)
{
  int Ho = H >> 1, Wo = W >> 1;
  int hw = blockIdx.x * 256 + threadIdx.x;
  if (hw >= Ho * Wo) return;
  int ow = hw % Wo, oh = hw / Wo;
  int c = blockIdx.y, b = blockIdx.z;
  const float* p = in + ((size_t)(b * C + c) * H) * W;
  float m = 0.f;
#pragma unroll
  for (int dh = -1; dh <= 1; ++dh) {
    int ih = 2 * oh + dh;
    if ((unsigned)ih >= (unsigned)H) continue;
    const float* r = p + (size_t)ih * W;
#pragma unroll
    for (int dw = -1; dw <= 1; ++dw) {
      int iw = 2 * ow + dw;
      if ((unsigned)iw >= (unsigned)W) continue;
      m = fmaxf(m, r[iw]);
    }
  }
  out[((size_t)(b * C + c) * Ho + oh) * Wo + ow] = m;
}

// ---------- bilinear 2x upsample ----------
__global__ __launch_bounds__(256) void k_up2(
    const float* __restrict__ in, float* __restrict__ out, int C, int H, int W)
{
  int Ho = H * 2, Wo = W * 2;
  int hw = blockIdx.x * 256 + threadIdx.x;
  if (hw >= Ho * Wo) return;
  int ow = hw % Wo, oh = hw / Wo;
  int c = blockIdx.y, b = blockIdx.z;
  int ih = oh >> 1, iw = ow >> 1;
  int ih0, ih1, iw0, iw1; float fh0, fw0;
  if (oh & 1) { ih0 = ih; ih1 = min(ih + 1, H - 1); fh0 = 0.75f; }
  else        { ih0 = max(ih - 1, 0); ih1 = ih;     fh0 = 0.25f; }
  if (ow & 1) { iw0 = iw; iw1 = min(iw + 1, W - 1); fw0 = 0.75f; }
  else        { iw0 = max(iw - 1, 0); iw1 = iw;     fw0 = 0.25f; }
  const float* p = in + ((size_t)(b * C + c) * H) * W;
  float v = fh0 * (fw0 * p[(size_t)ih0 * W + iw0] + (1.f - fw0) * p[(size_t)ih0 * W + iw1])
          + (1.f - fh0) * (fw0 * p[(size_t)ih1 * W + iw0] + (1.f - fw0) * p[(size_t)ih1 * W + iw1]);
  out[((size_t)(b * C + c) * Ho + oh) * Wo + ow] = v;
}

// ---------- X f32 -> fp16 natural + fp16 transposed ----------
__global__ void k_xcvt(const float* __restrict__ in, _Float16* __restrict__ xn,
                       _Float16* __restrict__ xt)
{
  __shared__ _Float16 t[32][33];
  int z = blockIdx.z;
  int x0 = blockIdx.x * 32, y0 = blockIdx.y * 32;
  int tx = threadIdx.x, ty = threadIdx.y;
  const float* ip = in + (size_t)z * 65536;
#pragma unroll
  for (int j = 0; j < 32; j += 8) {
    float v = ip[(size_t)(y0 + ty + j) * 256 + x0 + tx];
    xn[(size_t)z * 65536 + (size_t)(y0 + ty + j) * 256 + x0 + tx] = (_Float16)v;
    t[ty + j][tx] = (_Float16)v;
  }
  __syncthreads();
#pragma unroll
  for (int j = 0; j < 32; j += 8)
    xt[(size_t)z * 65536 + (size_t)(x0 + ty + j) * 256 + y0 + tx] = t[tx][ty + j];
}

// ---------- gated scan core (fwd/rev), fp16 everywhere, pure writes ----------
DEVINL void gl_lds16p(const void* g, void* lds) {
  __builtin_amdgcn_global_load_lds(
      (const __attribute__((address_space(1))) unsigned int*)g,
      (__attribute__((address_space(3))) unsigned int*)lds, 16, 0, 0);
}

DEVINL float prop_step(float xv, float a1, float a2, float a3,
                       float hu, float hc, float hd) {
  return (1.f - a1 - a2 - a3) * xv + a1 * hu + a2 * hc + a3 * hd;
}

template<int REV>
DEVINL void prop_core(const _Float16* xp, const _Float16* g1,
                      const _Float16* g2, const _Float16* g3,
                      _Float16* op, int S, int P, int lane,
                      _Float16* bx, _Float16* h1, _Float16* h2, _Float16* h3,
                      _Float16* bo)
{
  float r0 = 0.f, r1 = 0.f, r2 = 0.f, r3 = 0.f;
  int cur = 0;

  auto stage = [&](int buf, int s0) {
#pragma unroll
    for (int v = 0; v < 8; ++v) {
      size_t ro = (size_t)(s0 + 2 * v) * P + lane * 8;
      gl_lds16p(xp + ro, bx + buf * 4096 + v * 512);
      gl_lds16p(g1 + ro, h1 + buf * 4096 + v * 512);
      gl_lds16p(g2 + ro, h2 + buf * 4096 + v * 512);
      gl_lds16p(g3 + ro, h3 + buf * 4096 + v * 512);
    }
  };

  stage(0, REV ? (S - 16) : 0);
  const int NT = S / 16;
  for (int t = 0; t < NT; ++t) {
    const int s0 = REV ? (S - 16 - t * 16) : (t * 16);
    asm volatile("s_waitcnt vmcnt(0)" ::: "memory");
    if (t + 1 < NT) stage(cur ^ 1, REV ? (s0 - 16) : (s0 + 16));

    for (int u = 0; u < 16; ++u) {
      const int e = REV ? (15 - u) : u;
      const _Float16* px = bx + cur * 4096 + e * 256;
      const _Float16* p1 = h1 + cur * 4096 + e * 256;
      const _Float16* p2 = h2 + cur * 4096 + e * 256;
      const _Float16* p3 = h3 + cur * 4096 + e * 256;
      float x0 = px[lane], x1 = px[lane + 64], x2 = px[lane + 128], x3 = px[lane + 192];
      float a10 = p1[lane], a11 = p1[lane + 64], a12 = p1[lane + 128], a13 = p1[lane + 192];
      float a20 = p2[lane], a21 = p2[lane + 64], a22 = p2[lane + 128], a23 = p2[lane + 192];
      float a30 = p3[lane], a31 = p3[lane + 64], a32 = p3[lane + 128], a33 = p3[lane + 192];

      float su0 = __shfl_up(r0, 1), su1 = __shfl_up(r1, 1);
      float su2 = __shfl_up(r2, 1), su3 = __shfl_up(r3, 1);
      float sd0 = __shfl_down(r0, 1), sd1 = __shfl_down(r1, 1);
      float sd2 = __shfl_down(r2, 1), sd3 = __shfl_down(r3, 1);
      float t63_0 = __shfl(r0, 63), t63_1 = __shfl(r1, 63), t63_2 = __shfl(r2, 63);
      float t0_1 = __shfl(r1, 0), t0_2 = __shfl(r2, 0), t0_3 = __shfl(r3, 0);

      float hu0 = lane ? su0 : 0.f;
      float hu1 = lane ? su1 : t63_0;
      float hu2 = lane ? su2 : t63_1;
      float hu3 = lane ? su3 : t63_2;
      float hd0 = (lane < 63) ? sd0 : t0_1;
      float hd1 = (lane < 63) ? sd1 : t0_2;
      float hd2 = (lane < 63) ? sd2 : t0_3;
      float hd3 = (lane < 63) ? sd3 : 0.f;

      r0 = prop_step(x0, a10, a20, a30, hu0, r0, hd0);
      r1 = prop_step(x1, a11, a21, a31, hu1, r1, hd1);
      r2 = prop_step(x2, a12, a22, a32, hu2, r2, hd2);
      r3 = prop_step(x3, a13, a23, a33, hu3, r3, hd3);

      _Float16* po = bo + e * 256;
      po[lane] = (_Float16)r0; po[lane + 64] = (_Float16)r1;
      po[lane + 128] = (_Float16)r2; po[lane + 192] = (_Float16)r3;
    }

    for (int j = 0; j < 16; ++j) {
      uint2 v = *(const uint2*)&bo[j * 256 + lane * 4];
      *(uint2*)(op + (size_t)(s0 + j) * P + lane * 4) = v;
    }
    cur ^= 1;
  }
}

// dir = blockIdx.x>>7: 0 -> fwd (GA -> omA), 1 -> rev (GB -> omB).
__global__ __launch_bounds__(64) void k_prop_pair(
    const _Float16* __restrict__ Xh,
    const _Float16* __restrict__ GA, const _Float16* __restrict__ GB,
    _Float16* __restrict__ omA, _Float16* __restrict__ omB, int S, int P)
{
  const int dir = blockIdx.x >> 7;
  const int plane = blockIdx.x & 127;
  const int b = plane >> 5, c = plane & 31;
  const int lane = threadIdx.x;
  const size_t ps = (size_t)S * P;

  __shared__ __align__(16) _Float16 bx[2 * 4096];
  __shared__ __align__(16) _Float16 h1[2 * 4096];
  __shared__ __align__(16) _Float16 h2[2 * 4096];
  __shared__ __align__(16) _Float16 h3[2 * 4096];
  __shared__ __align__(16) _Float16 bo[4096];

  const _Float16* xp = Xh + (size_t)plane * ps;
  const _Float16* G = dir ? GB : GA;
  const _Float16* g1 = G + ((size_t)b * 96 + c) * ps;
  const _Float16* g2 = g1 + (size_t)32 * ps;
  const _Float16* g3 = g1 + (size_t)64 * ps;
  _Float16* op = (dir ? omB : omA) + (size_t)plane * ps;

  if (dir == 0) prop_core<0>(xp, g1, g2, g3, op, S, P, lane, bx, h1, h2, h3, bo);
  else          prop_core<1>(xp, g1, g2, g3, op, S, P, lane, bx, h1, h2, h3, bo);
}

// ---------------------------------------------------------------------------
extern "C" void kernel_launch(void* const* d_in, const int* in_sizes, int n_in,
                              void* d_out, int out_size, void* d_ws, size_t ws_size,
                              hipStream_t stream)
{
  const float* x   = (const float*)d_in[0];
  const float* rgb = (const float*)d_in[1];
  const float* mw  = (const float*)d_in[2];
  const float* mb  = (const float*)d_in[3];
  const float* c1w = (const float*)d_in[4];
  const float* c1b = (const float*)d_in[5];
  const float* c2w = (const float*)d_in[6];
  const float* c2b = (const float*)d_in[7];
  const float* c3w = (const float*)d_in[8];
  const float* c3b = (const float*)d_in[9];
  const float* c4w = (const float*)d_in[10];
  const float* c4b = (const float*)d_in[11];
  const float* d0w = (const float*)d_in[12];
  const float* d0b = (const float*)d_in[13];
  const float* d2w = (const float*)d_in[14];
  const float* d2b = (const float*)d_in[15];
  const float* d4w = (const float*)d_in[16];
  const float* d4b = (const float*)d_in[17];
  const float* d6w = (const float*)d_in[18];
  const float* d6b = (const float*)d_in[19];
  const float* d7w = (const float*)d_in[20];
  const float* d7b = (const float*)d_in[21];
  const float* pw  = (const float*)d_in[22];
  const float* pb  = (const float*)d_in[23];

  char* ws = (char*)d_ws;
  const size_t MB = 1024 * 1024;
  // ---- Airtight layout (peak 194 MiB; ws >= 216 proven round 1) ----
  // Phase A: X32f(32-64), xcvt -> Xn16(0-16), Xt16(16-32); f1(64-96)
  // Phase B: f2(96-112), f3(112-120), p1(120-128), p2(128-132), p3(132-134),
  //          f4(134-138), o0(138-140)
  // Phase C: u0(140-148), o1(148-156), u1(32-64), o2(160-176), u2(96-160),
  //          o3(160-192)
  // Phase D: gbufA(32-80), gbufB(80-128) -> om1(128-144), om2(144-160)
  // Phase E: gbufA/B rewritten -> omT1(0-16 over dead Xn16),
  //          omT2(160-176 over dead o3 head)
  // Pack zone: 192-194.
  _Float16* Xn16 = (_Float16*)(ws + 0);
  _Float16* Xt16 = (_Float16*)(ws + 16 * MB);
  float* X32f = (float*)(ws + 32 * MB);
  float* f1   = (float*)(ws + 64 * MB);
  float* f2   = (float*)(ws + 96 * MB);
  float* f3   = (float*)(ws + 112 * MB);
  float* p1   = (float*)(ws + 120 * MB);
  float* p2   = (float*)(ws + 128 * MB);
  float* p3   = (float*)(ws + 132 * MB);
  float* f4   = (float*)(ws + 134 * MB);
  float* o0   = (float*)(ws + 138 * MB);
  float* u0   = (float*)(ws + 140 * MB);
  float* o1   = (float*)(ws + 148 * MB);
  float* u1   = (float*)(ws + 32 * MB);        // over dead X32f
  float* o2   = (float*)(ws + 160 * MB);
  float* u2   = (float*)(ws + 96 * MB);        // over dead f2,f3,p1,p2..o1
  float* o3   = (float*)(ws + 160 * MB);       // over dead o2
  _Float16* gbufA = (_Float16*)(ws + 32 * MB); // over dead u1/X32f + f1 head
  _Float16* gbufB = (_Float16*)(ws + 80 * MB); // over dead f1 tail + u2 head
  _Float16* om1  = (_Float16*)(ws + 128 * MB); // over dead u2 mid
  _Float16* om2  = (_Float16*)(ws + 144 * MB); // over dead u2 tail
  _Float16* omT1 = (_Float16*)(ws + 0);        // over dead Xn16
  _Float16* omT2 = (_Float16*)(ws + 160 * MB); // over dead o3 head
  char* wz = ws + 192 * MB;
  float* wmf  = (float*)wz;
  float* wc1f = wmf + 864;
  float* wpkf = wc1f + 864;
  _Float16* wc2p = (_Float16*)(wpkf + 864);
  _Float16* wc3p = wc2p + 19456;
  _Float16* wc4p = wc3p + 77824;
  _Float16* wd2p = wc4p + 311296;
  _Float16* wd4p = wd2p + 155648;
  _Float16* wd6p = wd4p + 77824;
  _Float16* wd7p = wd6p + 19456;

  // Determinism guard: zero the entire used workspace every call so any
  // residual read-before-write sees the same value on every replay.
  hipMemsetAsync(d_ws, 0, 194 * MB, stream);

  dim3 blk(256);
  auto repf = [&](const float* s, float* d, int ci, int co) {
    int n = co * ci * 9;
    k_repack<<<dim3((n + 255) / 256), blk, 0, stream>>>(s, d, ci, co);
  };
  auto packh = [&](const float* s, _Float16* d, int ci, int co) {
    int n = co * (ci / 16) * 144;
    k_packwh<<<dim3((n + 255) / 256), blk, 0, stream>>>(s, d, ci, co);
  };
  repf(mw, wmf, 3, 32);
  repf(c1w, wc1f, 3, 32);
  repf(pw, wpkf, 32, 3);
  packh(c2w, wc2p, 32, 64);
  packh(c3w, wc3p, 64, 128);
  packh(c4w, wc4p, 128, 256);
  packh(d2w, wd2p, 128, 128);
  packh(d4w, wd4p, 128, 64);
  packh(d6w, wd6p, 64, 32);
  packh(d7w, wd7p, 32, 384);

  // Phase A
  k_conv3x3f<3, 32><<<dim3(256, 1, 4), blk, 0, stream>>>(x, wmf, mb, X32f, 3, 256, 256, 32, 32);
  k_xcvt<<<dim3(8, 8, 128), dim3(32, 8), 0, stream>>>(X32f, Xn16, Xt16);
  k_conv3x3f<3, 32><<<dim3(256, 1, 4), blk, 0, stream>>>(rgb, wc1f, c1b, f1, 3, 256, 256, 32, 32);

  // Phase B: encoder
  k_pool<<<dim3(64, 32, 4), blk, 0, stream>>>(f1, p1, 32, 256, 256);
  k_convh<4, 2, 2, 0, 0><<<dim3(128, 1, 4), dim3(256), 0, stream>>>(p1, wc2p, c2b, nullptr, f2, 128, 128, 64, 0, 64, 0);
  k_pool<<<dim3(16, 64, 4), blk, 0, stream>>>(f2, p2, 64, 128, 128);
  k_convh<2, 2, 4, 0, 0><<<dim3(64, 2, 4), dim3(128), 0, stream>>>(p2, wc3p, c3b, nullptr, f3, 64, 64, 128, 0, 128, 0);
  k_pool<<<dim3(4, 128, 4), blk, 0, stream>>>(f3, p3, 128, 64, 64);
  k_convh<2, 2, 8, 0, 0><<<dim3(16, 4, 4), dim3(128), 0, stream>>>(p3, wc4p, c4b, nullptr, f4, 32, 32, 256, 0, 256, 0);
  k_conv1x1<<<dim3(4, 128, 4), blk, 0, stream>>>(f4, d0w, d0b, o0, 256, 128, 32, 32);

  // Phase C: decoder
  k_up2<<<dim3(16, 128, 4), blk, 0, stream>>>(o0, u0, 128, 32, 32);
  k_convh<2, 2, 8, 1, 0><<<dim3(64, 2, 4), dim3(128), 0, stream>>>(u0, wd2p, d2b, f3, o1, 64, 64, 128, 0, 128, 0);
  k_up2<<<dim3(64, 128, 4), blk, 0, stream>>>(o1, u1, 128, 64, 64);
  k_convh<4, 2, 8, 1, 0><<<dim3(128, 1, 4), dim3(256), 0, stream>>>(u1, wd4p, d4b, f2, o2, 128, 128, 64, 0, 64, 0);
  k_up2<<<dim3(256, 64, 4), blk, 0, stream>>>(o2, u2, 64, 128, 128);
  k_convh<4, 1, 4, 1, 0><<<dim3(512, 1, 4), dim3(256), 0, stream>>>(u2, wd6p, d6b, f1, o3, 256, 256, 32, 0, 32, 0);

  // Phase D: vertical (k=2 fwd -> gbufA, k=3 rev -> gbufB), pair scan
  k_convh<4, 3, 2, 0, 1><<<dim3(512, 1, 4), dim3(256), 0, stream>>>(o3, wd7p, d7b, nullptr, gbufA, 256, 256, 384, 192, 96, 0);
  k_convh<4, 3, 2, 0, 1><<<dim3(512, 1, 4), dim3(256), 0, stream>>>(o3, wd7p, d7b, nullptr, gbufB, 256, 256, 384, 288, 96, 0);
  k_prop_pair<<<dim3(256), dim3(64), 0, stream>>>(Xn16, gbufA, gbufB, om1, om2, 256, 256);

  // Phase E: horizontal (k=0 fwd, k=1 rev; MODE 2 transposed gates), pair scan
  k_convh<4, 3, 2, 2, 1><<<dim3(512, 1, 4), dim3(256), 0, stream>>>(o3, wd7p, d7b, nullptr, gbufA, 256, 256, 384, 0, 96, 0);
  k_convh<4, 3, 2, 2, 1><<<dim3(512, 1, 4), dim3(256), 0, stream>>>(o3, wd7p, d7b, nullptr, gbufB, 256, 256, 384, 96, 96, 0);
  k_prop_pair<<<dim3(256), dim3(64), 0, stream>>>(Xt16, gbufA, gbufB, omT1, omT2, 256, 256);

  // Final conv: max of 4 buffers, f32 out
  k_convfin<<<dim3(256, 1, 4), blk, 0, stream>>>(om1, om2, omT1, omT2, wpkf, pb, (float*)d_out);
}

// Round 12
// 934.938 us; speedup vs baseline: 13.5780x; 1.0403x over previous
//
#include <hip/hip_runtime.h>
#include <cstddef>
#include <cstdint>

#define DEVINL __device__ __forceinline__

typedef __attribute__((ext_vector_type(8))) _Float16 half8v;
typedef __attribute__((ext_vector_type(4))) _Float16 half4v;
typedef __attribute__((ext_vector_type(16))) float f32x16;

constexpr int cmax(int a, int b) { return a > b ? a : b; }

// ---------------------------------------------------------------------------
// SPN forward, MI355X gfx950. B=4, H=W=256, NF=32.
// Round 12: chunk-contiguous scan lanes (p = 4*lane+q): 2 shuffles/step
// instead of 16, ds_read_b64 gate loads, direct coalesced global stores.
// ---------------------------------------------------------------------------

// ---------- f32 weight repack: OIHW -> [ci*9+k][Cout] (small convs) ----------
__global__ __launch_bounds__(256) void k_repack(
    const float* __restrict__ src, float* __restrict__ dst, int Cin, int Cout)
{
  int n = Cout * Cin * 9;
  int e = blockIdx.x * 256 + threadIdx.x;
  if (e >= n) return;
  int co = e / (Cin * 9);
  int r  = e - co * Cin * 9;
  int ci = r / 9;
  int k  = r - ci * 9;
  dst[(ci * 9 + k) * Cout + co] = src[e];
}

// ---------- fp16 weight pack: OIHW -> [cb][n][152], k = tap*16 + ci ----------
__global__ __launch_bounds__(256) void k_packwh(
    const float* __restrict__ src, _Float16* __restrict__ dst, int Cin, int Cout)
{
  int chunks = Cin >> 4;
  int total = Cout * chunks * 144;
  int e = blockIdx.x * 256 + threadIdx.x;
  if (e >= total) return;
  int n  = e / (chunks * 144);
  int r2 = e - n * chunks * 144;
  int cb = r2 / 144;
  int k  = r2 - cb * 144;
  int tap = k >> 4, ci = k & 15;
  float v = src[((size_t)n * Cin + cb * 16 + ci) * 9 + tap];
  dst[((size_t)cb * Cout + n) * 152 + k] = (_Float16)v;
}

// ---------- fp16 MFMA implicit-GEMM conv 3x3 pad 1, stage-once halo ----------
template<int NWM, int NACC, int CHUNKS, int MODE, int GATES>
__global__ __launch_bounds__(NWM * 64) void k_convh(
    const float* __restrict__ in, const _Float16* __restrict__ wpk,
    const float* __restrict__ bias, const float* __restrict__ skip,
    void* __restrict__ outv,
    int H, int W, int wCout, int n0, int outC, int oco0)
{
  static_assert(GATES == 0 || NACC == 3, "GATES needs NACC==3");
  constexpr int NTHR = NWM * 64;
  constexpr int ROWS = NWM * 2;
  constexpr int RH = ROWS + 2;
  constexpr int N_BLK = NACC * 32;
  constexpr int MT = NWM * 32;
  constexpr int A_BYTES = RH * 18 * 16 * 2;
  constexpr int B_BYTES = N_BLK * 152 * 2;
  constexpr int MPF = MT + 1;
  constexpr int MPH = 132;
  constexpr int EP_BYTES = GATES ? (96 * MPH * 2) : (N_BLK * MPF * 4);
  constexpr int SMEM = cmax(A_BYTES + B_BYTES, EP_BYTES);

  const int tid = threadIdx.x;
  const int wave = tid >> 6, lane = tid & 63;
  const int wm = wave;
  const int tiles_x = W >> 4;
  const int tx0 = (blockIdx.x % tiles_x) << 4;
  const int ty0 = (blockIdx.x / tiles_x) * ROWS;
  const int b = blockIdx.z;
  const int nb = n0 + blockIdx.y * N_BLK;
  const int ocb = oco0 + blockIdx.y * N_BLK;

  __shared__ __align__(16) char smem[SMEM];
  _Float16* Ah = (_Float16*)smem;
  _Float16* Bh = (_Float16*)(smem + A_BYTES);

  f32x16 acc[NACC] = {};

  const size_t ps = (size_t)H * W;
  const float* inb = in + (size_t)b * (CHUNKS * 16) * ps;

  for (int cb = 0; cb < CHUNKS; ++cb) {
    __syncthreads();
    for (int e = tid; e < RH * 18; e += NTHR) {
      int r = e / 18, c = e - r * 18;
      int gy = ty0 + r - 1, gx = tx0 + c - 1;
      bool ok = (unsigned)gy < (unsigned)H && (unsigned)gx < (unsigned)W;
      const float* src = inb + (size_t)(cb * 16) * ps + (size_t)gy * W + gx;
      half8v v0, v1;
#pragma unroll
      for (int j = 0; j < 8; ++j)
        v0[j] = ok ? (_Float16)src[(size_t)j * ps] : (_Float16)0.f;
#pragma unroll
      for (int j = 0; j < 8; ++j)
        v1[j] = ok ? (_Float16)src[(size_t)(j + 8) * ps] : (_Float16)0.f;
      *(half8v*)&Ah[e * 16] = v0;
      *(half8v*)&Ah[e * 16 + 8] = v1;
    }
    {
      const _Float16* wsrc = wpk + ((size_t)cb * wCout + nb) * 152;
      for (int e = tid; e < N_BLK * 19; e += NTHR)
        *(uint4*)&Bh[e * 8] = *(const uint4*)(wsrc + e * 8);
    }
    __syncthreads();
    const int am = wm * 32 + (lane & 31);
    const int r0 = am >> 4, c0 = am & 15;
    const int kh = lane >> 5;
    const _Float16* Ab = Ah + kh * 8;
    const _Float16* Bb = Bh + kh * 8;
#pragma unroll
    for (int ks = 0; ks < 9; ++ks) {
      const int dy = ks / 3, dx = ks - dy * 3;
      half8v af = *(const half8v*)(Ab + ((r0 + dy) * 18 + (c0 + dx)) * 16);
#pragma unroll
      for (int na = 0; na < NACC; ++na) {
        const int bn = na * 32 + (lane & 31);
        half8v bf = *(const half8v*)(Bb + bn * 152 + ks * 16);
        acc[na] = __builtin_amdgcn_mfma_f32_32x32x16_f16(af, bf, acc[na], 0, 0, 0);
      }
    }
  }

  __syncthreads();

  if (GATES) {
    _Float16* EPH = (_Float16*)smem;
    const int c = lane & 31;
    const float bv0 = bias[nb + c];
    const float bv1 = bias[nb + 32 + c];
    const float bv2 = bias[nb + 64 + c];
#pragma unroll
    for (int i = 0; i < 16; ++i) {
      int m = wm * 32 + (i & 3) + 8 * (i >> 2) + 4 * (lane >> 5);
      float g1 = acc[0][i] + bv0;
      float g2 = acc[GATES ? 1 : 0][i] + bv1;
      float g3 = acc[GATES ? 2 : 0][i] + bv2;
      float s = fabsf(g1) + fabsf(g2) + fabsf(g3);
      if (s >= 1.f) { float r = 1.f / s; g1 *= r; g2 *= r; g3 *= r; }
      EPH[(size_t)(0 * 32 + c) * MPH + m] = (_Float16)g1;
      EPH[(size_t)(1 * 32 + c) * MPH + m] = (_Float16)g2;
      EPH[(size_t)(2 * 32 + c) * MPH + m] = (_Float16)g3;
    }
    __syncthreads();
    _Float16* outh = (_Float16*)outv;
    if (MODE == 2) {
      const int TOT = 96 * 16;
      for (int r = tid; r < TOT; r += NTHR) {
        int gc = r >> 4, x = r & 15;
        const _Float16* ep = EPH + (size_t)gc * MPH + x;
        _Float16 v[8];
#pragma unroll
        for (int y = 0; y < 8; ++y) v[y] = ep[y * 16];
        size_t base = ((size_t)(b * 96 + gc) * W + tx0 + x) * (size_t)H + ty0;
        *(uint4*)(outh + base) = *(const uint4*)v;
      }
    } else {
      const int TOT = 96 * ROWS;
      for (int r = tid; r < TOT; r += NTHR) {
        int gc = r / ROWS, y = r - gc * ROWS;
        const _Float16* ep = EPH + (size_t)gc * MPH + y * 16;
        _Float16 v[16];
#pragma unroll
        for (int x = 0; x < 16; ++x) v[x] = ep[x];
        size_t base = ((size_t)(b * 96 + gc) * H + ty0 + y) * (size_t)W + tx0;
        *(uint4*)(outh + base) = *(const uint4*)v;
        *(uint4*)(outh + base + 8) = *(const uint4*)(v + 8);
      }
    }
  } else {
    float* EP = (float*)smem;
    float bv[NACC];
#pragma unroll
    for (int na = 0; na < NACC; ++na) bv[na] = bias[nb + na * 32 + (lane & 31)];
#pragma unroll
    for (int na = 0; na < NACC; ++na) {
      const int c = na * 32 + (lane & 31);
#pragma unroll
      for (int i = 0; i < 16; ++i) {
        int m = wm * 32 + (i & 3) + 8 * (i >> 2) + 4 * (lane >> 5);
        EP[(size_t)c * MPF + m] = acc[na][i] + bv[na];
      }
    }
    __syncthreads();
    float* out = (float*)outv;
    const int TOT = N_BLK * ROWS;
    for (int r = tid; r < TOT; r += NTHR) {
      int c = r / ROWS, y = r - c * ROWS;
      const float* ep = EP + (size_t)c * MPF + y * 16;
      float v[16];
#pragma unroll
      for (int x = 0; x < 16; ++x) v[x] = ep[x];
      size_t base = (((size_t)b * outC + ocb + c) * H + ty0 + y) * (size_t)W + tx0;
      if (MODE == 1) {
#pragma unroll
        for (int j = 0; j < 4; ++j) {
          float4 sk = *(const float4*)(skip + base + 4 * j);
          float e0 = v[4*j+0] > 0.f ? v[4*j+0] : expm1f(v[4*j+0]);
          float e1 = v[4*j+1] > 0.f ? v[4*j+1] : expm1f(v[4*j+1]);
          float e2 = v[4*j+2] > 0.f ? v[4*j+2] : expm1f(v[4*j+2]);
          float e3 = v[4*j+3] > 0.f ? v[4*j+3] : expm1f(v[4*j+3]);
          v[4*j+0] = e0 + sk.x; v[4*j+1] = e1 + sk.y;
          v[4*j+2] = e2 + sk.z; v[4*j+3] = e3 + sk.w;
        }
      }
#pragma unroll
      for (int j = 0; j < 4; ++j)
        *(float4*)(out + base + 4 * j) = *(const float4*)(v + 4 * j);
    }
  }
}

// ---------- f32 tiled conv 3x3 (Cin=3 convs) ----------
template<int CI, int CO>
__global__ __launch_bounds__(256) void k_conv3x3f(
    const float* __restrict__ in, const float* __restrict__ wr,
    const float* __restrict__ bias, float* __restrict__ out,
    int Cin, int H, int W, int wstride, int outC)
{
  const int ntx = W >> 4;
  const int tid = threadIdx.x;
  const int tx = tid & 15, ty = tid >> 4;
  const int tx0 = (blockIdx.x % ntx) << 4, ty0 = (blockIdx.x / ntx) << 4;
  const int b = blockIdx.z;

  __shared__ float sh[CI * 324];

  float acc[CO];
#pragma unroll
  for (int co = 0; co < CO; ++co) acc[co] = bias[co];

  const float* inb = in + (size_t)b * Cin * H * W;

  for (int cb = 0; cb < Cin; cb += CI) {
    __syncthreads();
    for (int e = tid; e < CI * 324; e += 256) {
      int ci = e / 324;
      int rr = e - ci * 324;
      int r = rr / 18, c = rr - r * 18;
      int gh = ty0 + r - 1, gw = tx0 + c - 1;
      float v = 0.f;
      if ((unsigned)gh < (unsigned)H && (unsigned)gw < (unsigned)W)
        v = inb[(size_t)(cb + ci) * H * W + (size_t)gh * W + gw];
      sh[e] = v;
    }
    __syncthreads();
#pragma unroll 1
    for (int ci = 0; ci < CI; ++ci) {
      float v[9];
      const float* sp = sh + ci * 324 + ty * 18 + tx;
#pragma unroll
      for (int kh = 0; kh < 3; ++kh)
#pragma unroll
        for (int kw = 0; kw < 3; ++kw)
          v[kh * 3 + kw] = sp[kh * 18 + kw];
      const float* wp = wr + (size_t)((cb + ci) * 9) * wstride;
#pragma unroll
      for (int k = 0; k < 9; ++k)
#pragma unroll
        for (int co = 0; co < CO; ++co)
          acc[co] = fmaf(wp[(size_t)k * wstride + co], v[k], acc[co]);
    }
  }
#pragma unroll
  for (int co = 0; co < CO; ++co)
    out[(((size_t)b * outC + co) * H + ty0 + ty) * W + tx0 + tx] = acc[co];
}

// ---------- final conv: in = max(om1,om2, omT1^T,omT2^T) fp16, out f32 ----------
__global__ __launch_bounds__(256) void k_convfin(
    const _Float16* __restrict__ om1, const _Float16* __restrict__ om2,
    const _Float16* __restrict__ omT1, const _Float16* __restrict__ omT2,
    const float* __restrict__ wr, const float* __restrict__ bias,
    float* __restrict__ out)
{
  const int H = 256, W = 256;
  const int tid = threadIdx.x;
  const int tx = tid & 15, ty = tid >> 4;
  const int tx0 = (blockIdx.x & 15) << 4, ty0 = (blockIdx.x >> 4) << 4;
  const int b = blockIdx.z;

  __shared__ float sh[32 * 324];

  for (int e = tid; e < 32 * 324; e += 256) {
    int ci = e / 324, rr = e - ci * 324;
    int r = rr / 18, c = rr - r * 18;
    int gh = ty0 + r - 1, gw = tx0 + c - 1;
    float v = 0.f;
    if ((unsigned)gh < (unsigned)H && (unsigned)gw < (unsigned)W) {
      size_t p = ((size_t)(b * 32 + ci) * H + gh) * W + gw;
      v = fmaxf((float)om1[p], (float)om2[p]);
    }
    sh[ci * 324 + r * 18 + c] = v;
  }
  __syncthreads();
  for (int e = tid; e < 32 * 324; e += 256) {
    int ci = e / 324, rr = e - ci * 324;
    int c = rr / 18, r = rr - c * 18;
    int gh = ty0 + r - 1, gw = tx0 + c - 1;
    if ((unsigned)gh < (unsigned)H && (unsigned)gw < (unsigned)W) {
      size_t p = ((size_t)(b * 32 + ci) * W + gw) * (size_t)H + gh;
      float t = fmaxf((float)omT1[p], (float)omT2[p]);
      int si = ci * 324 + r * 18 + c;
      sh[si] = fmaxf(sh[si], t);
    }
  }
  __syncthreads();

  float acc[3] = {bias[0], bias[1], bias[2]};
#pragma unroll 1
  for (int ci = 0; ci < 32; ++ci) {
    float v[9];
    const float* sp = sh + ci * 324 + ty * 18 + tx;
#pragma unroll
    for (int kh = 0; kh < 3; ++kh)
#pragma unroll
      for (int kw = 0; kw < 3; ++kw)
        v[kh * 3 + kw] = sp[kh * 18 + kw];
    const float* wp = wr + (size_t)(ci * 9) * 3;
#pragma unroll
    for (int k = 0; k < 9; ++k)
#pragma unroll
      for (int co = 0; co < 3; ++co)
        acc[co] = fmaf(wp[(size_t)k * 3 + co], v[k], acc[co]);
  }
#pragma unroll
  for (int co = 0; co < 3; ++co)
    out[(((size_t)b * 3 + co) * H + ty0 + ty) * W + tx0 + tx] = acc[co];
}

// ---------- conv 1x1 (f32) ----------
__global__ __launch_bounds__(256) void k_conv1x1(
    const float* __restrict__ in, const float* __restrict__ wgt,
    const float* __restrict__ bias, float* __restrict__ out,
    int Cin, int Cout, int H, int W)
{
  int hw = blockIdx.x * 256 + threadIdx.x;
  if (hw >= H * W) return;
  int co = blockIdx.y, b = blockIdx.z;
  const float* ip = in + (size_t)b * Cin * H * W + hw;
  const float* wp = wgt + (size_t)co * Cin;
  float acc = bias[co];
  for (int ci = 0; ci < Cin; ++ci) acc += wp[ci] * ip[(size_t)ci * H * W];
  out[((size_t)b * Cout + co) * H * W + hw] = acc;
}

// ---------- relu + maxpool 3x3 stride 2 pad 1 ----------
__global__ __launch_bounds__(256) void k_pool(
    const float* __restrict__ in, float* __restrict__ out, int C, int H, int W)
{
  int Ho = H >> 1, Wo = W >> 1;
  int hw = blockIdx.x * 256 + threadIdx.x;
  if (hw >= Ho * Wo) return;
  int ow = hw % Wo, oh = hw / Wo;
  int c = blockIdx.y, b = blockIdx.z;
  const float* p = in + ((size_t)(b * C + c) * H) * W;
  float m = 0.f;
#pragma unroll
  for (int dh = -1; dh <= 1; ++dh) {
    int ih = 2 * oh + dh;
    if ((unsigned)ih >= (unsigned)H) continue;
    const float* r = p + (size_t)ih * W;
#pragma unroll
    for (int dw = -1; dw <= 1; ++dw) {
      int iw = 2 * ow + dw;
      if ((unsigned)iw >= (unsigned)W) continue;
      m = fmaxf(m, r[iw]);
    }
  }
  out[((size_t)(b * C + c) * Ho + oh) * Wo + ow] = m;
}

// ---------- bilinear 2x upsample ----------
__global__ __launch_bounds__(256) void k_up2(
    const float* __restrict__ in, float* __restrict__ out, int C, int H, int W)
{
  int Ho = H * 2, Wo = W * 2;
  int hw = blockIdx.x * 256 + threadIdx.x;
  if (hw >= Ho * Wo) return;
  int ow = hw % Wo, oh = hw / Wo;
  int c = blockIdx.y, b = blockIdx.z;
  int ih = oh >> 1, iw = ow >> 1;
  int ih0, ih1, iw0, iw1; float fh0, fw0;
  if (oh & 1) { ih0 = ih; ih1 = min(ih + 1, H - 1); fh0 = 0.75f; }
  else        { ih0 = max(ih - 1, 0); ih1 = ih;     fh0 = 0.25f; }
  if (ow & 1) { iw0 = iw; iw1 = min(iw + 1, W - 1); fw0 = 0.75f; }
  else        { iw0 = max(iw - 1, 0); iw1 = iw;     fw0 = 0.25f; }
  const float* p = in + ((size_t)(b * C + c) * H) * W;
  float v = fh0 * (fw0 * p[(size_t)ih0 * W + iw0] + (1.f - fw0) * p[(size_t)ih0 * W + iw1])
          + (1.f - fh0) * (fw0 * p[(size_t)ih1 * W + iw0] + (1.f - fw0) * p[(size_t)ih1 * W + iw1]);
  out[((size_t)(b * C + c) * Ho + oh) * Wo + ow] = v;
}

// ---------- X f32 -> fp16 natural + fp16 transposed ----------
__global__ void k_xcvt(const float* __restrict__ in, _Float16* __restrict__ xn,
                       _Float16* __restrict__ xt)
{
  __shared__ _Float16 t[32][33];
  int z = blockIdx.z;
  int x0 = blockIdx.x * 32, y0 = blockIdx.y * 32;
  int tx = threadIdx.x, ty = threadIdx.y;
  const float* ip = in + (size_t)z * 65536;
#pragma unroll
  for (int j = 0; j < 32; j += 8) {
    float v = ip[(size_t)(y0 + ty + j) * 256 + x0 + tx];
    xn[(size_t)z * 65536 + (size_t)(y0 + ty + j) * 256 + x0 + tx] = (_Float16)v;
    t[ty + j][tx] = (_Float16)v;
  }
  __syncthreads();
#pragma unroll
  for (int j = 0; j < 32; j += 8)
    xt[(size_t)z * 65536 + (size_t)(x0 + ty + j) * 256 + y0 + tx] = t[tx][ty + j];
}

// ---------- gated scan core: chunk-contiguous lanes, 2 shuffles/step ----------
DEVINL void gl_lds16p(const void* g, void* lds) {
  __builtin_amdgcn_global_load_lds(
      (const __attribute__((address_space(1))) unsigned int*)g,
      (__attribute__((address_space(3))) unsigned int*)lds, 16, 0, 0);
}

template<int REV>
DEVINL void prop_core(const _Float16* xp, const _Float16* g1,
                      const _Float16* g2, const _Float16* g3,
                      _Float16* op, int S, int P, int lane,
                      _Float16* bx, _Float16* h1, _Float16* h2, _Float16* h3)
{
  float r0 = 0.f, r1 = 0.f, r2 = 0.f, r3 = 0.f;
  int cur = 0;

  auto stage = [&](int buf, int s0) {
#pragma unroll
    for (int v = 0; v < 8; ++v) {
      size_t ro = (size_t)(s0 + 2 * v) * P + lane * 8;
      gl_lds16p(xp + ro, bx + buf * 4096 + v * 512);
      gl_lds16p(g1 + ro, h1 + buf * 4096 + v * 512);
      gl_lds16p(g2 + ro, h2 + buf * 4096 + v * 512);
      gl_lds16p(g3 + ro, h3 + buf * 4096 + v * 512);
    }
  };

  stage(0, REV ? (S - 16) : 0);
  const int NT = S / 16;
  for (int t = 0; t < NT; ++t) {
    const int s0 = REV ? (S - 16 - t * 16) : (t * 16);
    asm volatile("s_waitcnt vmcnt(0)" ::: "memory");
    if (t + 1 < NT) stage(cur ^ 1, REV ? (s0 - 16) : (s0 + 16));

#pragma unroll
    for (int u = 0; u < 16; ++u) {
      const int e = REV ? (15 - u) : u;
      // lane owns rows 4*lane .. 4*lane+3 (contiguous 8-byte vectors)
      half4v xv = *(const half4v*)(bx + cur * 4096 + e * 256 + 4 * lane);
      half4v a1 = *(const half4v*)(h1 + cur * 4096 + e * 256 + 4 * lane);
      half4v a2 = *(const half4v*)(h2 + cur * 4096 + e * 256 + 4 * lane);
      half4v a3 = *(const half4v*)(h3 + cur * 4096 + e * 256 + 4 * lane);

      float hu0 = __shfl_up(r3, 1);           // row 4L-1 = lane-1's r3
      float hd3 = __shfl_down(r0, 1);         // row 4L+4 = lane+1's r0
      if (lane == 0)  hu0 = 0.f;
      if (lane == 63) hd3 = 0.f;

      float o0 = r0, o1 = r1, o2 = r2, o3v = r3;   // previous-step h
      float x0 = xv[0], x1 = xv[1], x2 = xv[2], x3 = xv[3];
      float a10 = a1[0], a11 = a1[1], a12 = a1[2], a13 = a1[3];
      float a20 = a2[0], a21 = a2[1], a22 = a2[2], a23 = a2[3];
      float a30 = a3[0], a31 = a3[1], a32 = a3[2], a33 = a3[3];

      r0 = (1.f - a10 - a20 - a30) * x0 + a10 * hu0 + a20 * o0 + a30 * o1;
      r1 = (1.f - a11 - a21 - a31) * x1 + a11 * o0  + a21 * o1 + a31 * o2;
      r2 = (1.f - a12 - a22 - a32) * x2 + a12 * o1  + a22 * o2 + a32 * o3v;
      r3 = (1.f - a13 - a23 - a33) * x3 + a13 * o2  + a23 * o3v + a33 * hd3;

      half4v hv; hv[0] = (_Float16)r0; hv[1] = (_Float16)r1;
      hv[2] = (_Float16)r2; hv[3] = (_Float16)r3;
      *(half4v*)(op + (size_t)(s0 + e) * P + 4 * lane) = hv;
    }
    cur ^= 1;
  }
}

// dir = blockIdx.x>>7: 0 -> fwd (GA -> omA), 1 -> rev (GB -> omB).
__global__ __launch_bounds__(64) void k_prop_pair(
    const _Float16* __restrict__ Xh,
    const _Float16* __restrict__ GA, const _Float16* __restrict__ GB,
    _Float16* __restrict__ omA, _Float16* __restrict__ omB, int S, int P)
{
  const int dir = blockIdx.x >> 7;
  const int plane = blockIdx.x & 127;
  const int b = plane >> 5, c = plane & 31;
  const int lane = threadIdx.x;
  const size_t ps = (size_t)S * P;

  __shared__ __align__(16) _Float16 bx[2 * 4096];
  __shared__ __align__(16) _Float16 h1[2 * 4096];
  __shared__ __align__(16) _Float16 h2[2 * 4096];
  __shared__ __align__(16) _Float16 h3[2 * 4096];

  const _Float16* xp = Xh + (size_t)plane * ps;
  const _Float16* G = dir ? GB : GA;
  const _Float16* g1 = G + ((size_t)b * 96 + c) * ps;
  const _Float16* g2 = g1 + (size_t)32 * ps;
  const _Float16* g3 = g1 + (size_t)64 * ps;
  _Float16* op = (dir ? omB : omA) + (size_t)plane * ps;

  if (dir == 0) prop_core<0>(xp, g1, g2, g3, op, S, P, lane, bx, h1, h2, h3);
  else          prop_core<1>(xp, g1, g2, g3, op, S, P, lane, bx, h1, h2, h3);
}

// ---------------------------------------------------------------------------
extern "C" void kernel_launch(void* const* d_in, const int* in_sizes, int n_in,
                              void* d_out, int out_size, void* d_ws, size_t ws_size,
                              hipStream_t stream)
{
  const float* x   = (const float*)d_in[0];
  const float* rgb = (const float*)d_in[1];
  const float* mw  = (const float*)d_in[2];
  const float* mb  = (const float*)d_in[3];
  const float* c1w = (const float*)d_in[4];
  const float* c1b = (const float*)d_in[5];
  const float* c2w = (const float*)d_in[6];
  const float* c2b = (const float*)d_in[7];
  const float* c3w = (const float*)d_in[8];
  const float* c3b = (const float*)d_in[9];
  const float* c4w = (const float*)d_in[10];
  const float* c4b = (const float*)d_in[11];
  const float* d0w = (const float*)d_in[12];
  const float* d0b = (const float*)d_in[13];
  const float* d2w = (const float*)d_in[14];
  const float* d2b = (const float*)d_in[15];
  const float* d4w = (const float*)d_in[16];
  const float* d4b = (const float*)d_in[17];
  const float* d6w = (const float*)d_in[18];
  const float* d6b = (const float*)d_in[19];
  const float* d7w = (const float*)d_in[20];
  const float* d7b = (const float*)d_in[21];
  const float* pw  = (const float*)d_in[22];
  const float* pb  = (const float*)d_in[23];

  char* ws = (char*)d_ws;
  const size_t MB = 1024 * 1024;
  // Airtight layout (peak 194 MiB; identical to round 11):
  _Float16* Xn16 = (_Float16*)(ws + 0);
  _Float16* Xt16 = (_Float16*)(ws + 16 * MB);
  float* X32f = (float*)(ws + 32 * MB);
  float* f1   = (float*)(ws + 64 * MB);
  float* f2   = (float*)(ws + 96 * MB);
  float* f3   = (float*)(ws + 112 * MB);
  float* p1   = (float*)(ws + 120 * MB);
  float* p2   = (float*)(ws + 128 * MB);
  float* p3   = (float*)(ws + 132 * MB);
  float* f4   = (float*)(ws + 134 * MB);
  float* o0   = (float*)(ws + 138 * MB);
  float* u0   = (float*)(ws + 140 * MB);
  float* o1   = (float*)(ws + 148 * MB);
  float* u1   = (float*)(ws + 32 * MB);
  float* o2   = (float*)(ws + 160 * MB);
  float* u2   = (float*)(ws + 96 * MB);
  float* o3   = (float*)(ws + 160 * MB);
  _Float16* gbufA = (_Float16*)(ws + 32 * MB);
  _Float16* gbufB = (_Float16*)(ws + 80 * MB);
  _Float16* om1  = (_Float16*)(ws + 128 * MB);
  _Float16* om2  = (_Float16*)(ws + 144 * MB);
  _Float16* omT1 = (_Float16*)(ws + 0);
  _Float16* omT2 = (_Float16*)(ws + 160 * MB);
  char* wz = ws + 192 * MB;
  float* wmf  = (float*)wz;
  float* wc1f = wmf + 864;
  float* wpkf = wc1f + 864;
  _Float16* wc2p = (_Float16*)(wpkf + 864);
  _Float16* wc3p = wc2p + 19456;
  _Float16* wc4p = wc3p + 77824;
  _Float16* wd2p = wc4p + 311296;
  _Float16* wd4p = wd2p + 155648;
  _Float16* wd6p = wd4p + 77824;
  _Float16* wd7p = wd6p + 19456;

  // Determinism guard: zero all used workspace every call.
  hipMemsetAsync(d_ws, 0, 194 * MB, stream);

  dim3 blk(256);
  auto repf = [&](const float* s, float* d, int ci, int co) {
    int n = co * ci * 9;
    k_repack<<<dim3((n + 255) / 256), blk, 0, stream>>>(s, d, ci, co);
  };
  auto packh = [&](const float* s, _Float16* d, int ci, int co) {
    int n = co * (ci / 16) * 144;
    k_packwh<<<dim3((n + 255) / 256), blk, 0, stream>>>(s, d, ci, co);
  };
  repf(mw, wmf, 3, 32);
  repf(c1w, wc1f, 3, 32);
  repf(pw, wpkf, 32, 3);
  packh(c2w, wc2p, 32, 64);
  packh(c3w, wc3p, 64, 128);
  packh(c4w, wc4p, 128, 256);
  packh(d2w, wd2p, 128, 128);
  packh(d4w, wd4p, 128, 64);
  packh(d6w, wd6p, 64, 32);
  packh(d7w, wd7p, 32, 384);

  // Phase A
  k_conv3x3f<3, 32><<<dim3(256, 1, 4), blk, 0, stream>>>(x, wmf, mb, X32f, 3, 256, 256, 32, 32);
  k_xcvt<<<dim3(8, 8, 128), dim3(32, 8), 0, stream>>>(X32f, Xn16, Xt16);
  k_conv3x3f<3, 32><<<dim3(256, 1, 4), blk, 0, stream>>>(rgb, wc1f, c1b, f1, 3, 256, 256, 32, 32);

  // Phase B: encoder
  k_pool<<<dim3(64, 32, 4), blk, 0, stream>>>(f1, p1, 32, 256, 256);
  k_convh<4, 2, 2, 0, 0><<<dim3(128, 1, 4), dim3(256), 0, stream>>>(p1, wc2p, c2b, nullptr, f2, 128, 128, 64, 0, 64, 0);
  k_pool<<<dim3(16, 64, 4), blk, 0, stream>>>(f2, p2, 64, 128, 128);
  k_convh<2, 2, 4, 0, 0><<<dim3(64, 2, 4), dim3(128), 0, stream>>>(p2, wc3p, c3b, nullptr, f3, 64, 64, 128, 0, 128, 0);
  k_pool<<<dim3(4, 128, 4), blk, 0, stream>>>(f3, p3, 128, 64, 64);
  k_convh<2, 2, 8, 0, 0><<<dim3(16, 4, 4), dim3(128), 0, stream>>>(p3, wc4p, c4b, nullptr, f4, 32, 32, 256, 0, 256, 0);
  k_conv1x1<<<dim3(4, 128, 4), blk, 0, stream>>>(f4, d0w, d0b, o0, 256, 128, 32, 32);

  // Phase C: decoder
  k_up2<<<dim3(16, 128, 4), blk, 0, stream>>>(o0, u0, 128, 32, 32);
  k_convh<2, 2, 8, 1, 0><<<dim3(64, 2, 4), dim3(128), 0, stream>>>(u0, wd2p, d2b, f3, o1, 64, 64, 128, 0, 128, 0);
  k_up2<<<dim3(64, 128, 4), blk, 0, stream>>>(o1, u1, 128, 64, 64);
  k_convh<4, 2, 8, 1, 0><<<dim3(128, 1, 4), dim3(256), 0, stream>>>(u1, wd4p, d4b, f2, o2, 128, 128, 64, 0, 64, 0);
  k_up2<<<dim3(256, 64, 4), blk, 0, stream>>>(o2, u2, 64, 128, 128);
  k_convh<4, 1, 4, 1, 0><<<dim3(512, 1, 4), dim3(256), 0, stream>>>(u2, wd6p, d6b, f1, o3, 256, 256, 32, 0, 32, 0);

  // Phase D: vertical (k=2 fwd -> gbufA, k=3 rev -> gbufB), pair scan
  k_convh<4, 3, 2, 0, 1><<<dim3(512, 1, 4), dim3(256), 0, stream>>>(o3, wd7p, d7b, nullptr, gbufA, 256, 256, 384, 192, 96, 0);
  k_convh<4, 3, 2, 0, 1><<<dim3(512, 1, 4), dim3(256), 0, stream>>>(o3, wd7p, d7b, nullptr, gbufB, 256, 256, 384, 288, 96, 0);
  k_prop_pair<<<dim3(256), dim3(64), 0, stream>>>(Xn16, gbufA, gbufB, om1, om2, 256, 256);

  // Phase E: horizontal (k=0 fwd, k=1 rev; MODE 2 transposed gates), pair scan
  k_convh<4, 3, 2, 2, 1><<<dim3(512, 1, 4), dim3(256), 0, stream>>>(o3, wd7p, d7b, nullptr, gbufA, 256, 256, 384, 0, 96, 0);
  k_convh<4, 3, 2, 2, 1><<<dim3(512, 1, 4), dim3(256), 0, stream>>>(o3, wd7p, d7b, nullptr, gbufB, 256, 256, 384, 96, 96, 0);
  k_prop_pair<<<dim3(256), dim3(64), 0, stream>>>(Xt16, gbufA, gbufB, omT1, omT2, 256, 256);

  // Final conv: max of 4 buffers, f32 out
  k_convfin<<<dim3(256, 1, 4), blk, 0, stream>>>(om1, om2, omT1, omT2, wpkf, pb, (float*)d_out);
}

// Round 13
// 915.845 us; speedup vs baseline: 13.8610x; 1.0208x over previous
//
#include <hip/hip_runtime.h>
#include <cstddef>
#include <cstdint>

#define DEVINL __device__ __forceinline__

typedef __attribute__((ext_vector_type(8))) _Float16 half8v;
typedef __attribute__((ext_vector_type(4))) _Float16 half4v;
typedef __attribute__((ext_vector_type(16))) float f32x16;

constexpr int cmax(int a, int b) { return a > b ? a : b; }

// ---------------------------------------------------------------------------
// SPN forward, MI355X gfx950. B=4, H=W=256, NF=32.
// Round 13: split convfin -> k_max4 (coalesced, conflict-free) + f32 conv;
// merged guide-conv pairs (blockIdx.y selects direction A/B).
// ---------------------------------------------------------------------------

// ---------- f32 weight repack: OIHW -> [ci*9+k][Cout] (small convs) ----------
__global__ __launch_bounds__(256) void k_repack(
    const float* __restrict__ src, float* __restrict__ dst, int Cin, int Cout)
{
  int n = Cout * Cin * 9;
  int e = blockIdx.x * 256 + threadIdx.x;
  if (e >= n) return;
  int co = e / (Cin * 9);
  int r  = e - co * Cin * 9;
  int ci = r / 9;
  int k  = r - ci * 9;
  dst[(ci * 9 + k) * Cout + co] = src[e];
}

// ---------- fp16 weight pack: OIHW -> [cb][n][152], k = tap*16 + ci ----------
__global__ __launch_bounds__(256) void k_packwh(
    const float* __restrict__ src, _Float16* __restrict__ dst, int Cin, int Cout)
{
  int chunks = Cin >> 4;
  int total = Cout * chunks * 144;
  int e = blockIdx.x * 256 + threadIdx.x;
  if (e >= total) return;
  int n  = e / (chunks * 144);
  int r2 = e - n * chunks * 144;
  int cb = r2 / 144;
  int k  = r2 - cb * 144;
  int tap = k >> 4, ci = k & 15;
  float v = src[((size_t)n * Cin + cb * 16 + ci) * 9 + tap];
  dst[((size_t)cb * Cout + n) * 152 + k] = (_Float16)v;
}

// ---------- fp16 MFMA implicit-GEMM conv 3x3 pad 1, stage-once halo ----------
// GATES=1: blockIdx.y selects direction half: nb = n0 + y*96, out = y? outv2 : outv.
template<int NWM, int NACC, int CHUNKS, int MODE, int GATES>
__global__ __launch_bounds__(NWM * 64) void k_convh(
    const float* __restrict__ in, const _Float16* __restrict__ wpk,
    const float* __restrict__ bias, const float* __restrict__ skip,
    void* __restrict__ outv, void* __restrict__ outv2,
    int H, int W, int wCout, int n0, int outC, int oco0)
{
  static_assert(GATES == 0 || NACC == 3, "GATES needs NACC==3");
  constexpr int NTHR = NWM * 64;
  constexpr int ROWS = NWM * 2;
  constexpr int RH = ROWS + 2;
  constexpr int N_BLK = NACC * 32;
  constexpr int MT = NWM * 32;
  constexpr int A_BYTES = RH * 18 * 16 * 2;
  constexpr int B_BYTES = N_BLK * 152 * 2;
  constexpr int MPF = MT + 1;
  constexpr int MPH = 132;
  constexpr int EP_BYTES = GATES ? (96 * MPH * 2) : (N_BLK * MPF * 4);
  constexpr int SMEM = cmax(A_BYTES + B_BYTES, EP_BYTES);

  const int tid = threadIdx.x;
  const int wave = tid >> 6, lane = tid & 63;
  const int wm = wave;
  const int tiles_x = W >> 4;
  const int tx0 = (blockIdx.x % tiles_x) << 4;
  const int ty0 = (blockIdx.x / tiles_x) * ROWS;
  const int b = blockIdx.z;
  const int nb = n0 + blockIdx.y * N_BLK;
  const int ocb = oco0 + blockIdx.y * N_BLK;

  __shared__ __align__(16) char smem[SMEM];
  _Float16* Ah = (_Float16*)smem;
  _Float16* Bh = (_Float16*)(smem + A_BYTES);

  f32x16 acc[NACC] = {};

  const size_t ps = (size_t)H * W;
  const float* inb = in + (size_t)b * (CHUNKS * 16) * ps;

  for (int cb = 0; cb < CHUNKS; ++cb) {
    __syncthreads();
    for (int e = tid; e < RH * 18; e += NTHR) {
      int r = e / 18, c = e - r * 18;
      int gy = ty0 + r - 1, gx = tx0 + c - 1;
      bool ok = (unsigned)gy < (unsigned)H && (unsigned)gx < (unsigned)W;
      const float* src = inb + (size_t)(cb * 16) * ps + (size_t)gy * W + gx;
      half8v v0, v1;
#pragma unroll
      for (int j = 0; j < 8; ++j)
        v0[j] = ok ? (_Float16)src[(size_t)j * ps] : (_Float16)0.f;
#pragma unroll
      for (int j = 0; j < 8; ++j)
        v1[j] = ok ? (_Float16)src[(size_t)(j + 8) * ps] : (_Float16)0.f;
      *(half8v*)&Ah[e * 16] = v0;
      *(half8v*)&Ah[e * 16 + 8] = v1;
    }
    {
      const _Float16* wsrc = wpk + ((size_t)cb * wCout + nb) * 152;
      for (int e = tid; e < N_BLK * 19; e += NTHR)
        *(uint4*)&Bh[e * 8] = *(const uint4*)(wsrc + e * 8);
    }
    __syncthreads();
    const int am = wm * 32 + (lane & 31);
    const int r0 = am >> 4, c0 = am & 15;
    const int kh = lane >> 5;
    const _Float16* Ab = Ah + kh * 8;
    const _Float16* Bb = Bh + kh * 8;
#pragma unroll
    for (int ks = 0; ks < 9; ++ks) {
      const int dy = ks / 3, dx = ks - dy * 3;
      half8v af = *(const half8v*)(Ab + ((r0 + dy) * 18 + (c0 + dx)) * 16);
#pragma unroll
      for (int na = 0; na < NACC; ++na) {
        const int bn = na * 32 + (lane & 31);
        half8v bf = *(const half8v*)(Bb + bn * 152 + ks * 16);
        acc[na] = __builtin_amdgcn_mfma_f32_32x32x16_f16(af, bf, acc[na], 0, 0, 0);
      }
    }
  }

  __syncthreads();

  if (GATES) {
    _Float16* EPH = (_Float16*)smem;
    const int c = lane & 31;
    const float bv0 = bias[nb + c];
    const float bv1 = bias[nb + 32 + c];
    const float bv2 = bias[nb + 64 + c];
#pragma unroll
    for (int i = 0; i < 16; ++i) {
      int m = wm * 32 + (i & 3) + 8 * (i >> 2) + 4 * (lane >> 5);
      float g1 = acc[0][i] + bv0;
      float g2 = acc[GATES ? 1 : 0][i] + bv1;
      float g3 = acc[GATES ? 2 : 0][i] + bv2;
      float s = fabsf(g1) + fabsf(g2) + fabsf(g3);
      if (s >= 1.f) { float r = 1.f / s; g1 *= r; g2 *= r; g3 *= r; }
      EPH[(size_t)(0 * 32 + c) * MPH + m] = (_Float16)g1;
      EPH[(size_t)(1 * 32 + c) * MPH + m] = (_Float16)g2;
      EPH[(size_t)(2 * 32 + c) * MPH + m] = (_Float16)g3;
    }
    __syncthreads();
    _Float16* outh = (_Float16*)(blockIdx.y ? outv2 : outv);
    if (MODE == 2) {
      const int TOT = 96 * 16;
      for (int r = tid; r < TOT; r += NTHR) {
        int gc = r >> 4, x = r & 15;
        const _Float16* ep = EPH + (size_t)gc * MPH + x;
        _Float16 v[8];
#pragma unroll
        for (int y = 0; y < 8; ++y) v[y] = ep[y * 16];
        size_t base = ((size_t)(b * 96 + gc) * W + tx0 + x) * (size_t)H + ty0;
        *(uint4*)(outh + base) = *(const uint4*)v;
      }
    } else {
      const int TOT = 96 * ROWS;
      for (int r = tid; r < TOT; r += NTHR) {
        int gc = r / ROWS, y = r - gc * ROWS;
        const _Float16* ep = EPH + (size_t)gc * MPH + y * 16;
        _Float16 v[16];
#pragma unroll
        for (int x = 0; x < 16; ++x) v[x] = ep[x];
        size_t base = ((size_t)(b * 96 + gc) * H + ty0 + y) * (size_t)W + tx0;
        *(uint4*)(outh + base) = *(const uint4*)v;
        *(uint4*)(outh + base + 8) = *(const uint4*)(v + 8);
      }
    }
  } else {
    float* EP = (float*)smem;
    float bv[NACC];
#pragma unroll
    for (int na = 0; na < NACC; ++na) bv[na] = bias[nb + na * 32 + (lane & 31)];
#pragma unroll
    for (int na = 0; na < NACC; ++na) {
      const int c = na * 32 + (lane & 31);
#pragma unroll
      for (int i = 0; i < 16; ++i) {
        int m = wm * 32 + (i & 3) + 8 * (i >> 2) + 4 * (lane >> 5);
        EP[(size_t)c * MPF + m] = acc[na][i] + bv[na];
      }
    }
    __syncthreads();
    float* out = (float*)outv;
    const int TOT = N_BLK * ROWS;
    for (int r = tid; r < TOT; r += NTHR) {
      int c = r / ROWS, y = r - c * ROWS;
      const float* ep = EP + (size_t)c * MPF + y * 16;
      float v[16];
#pragma unroll
      for (int x = 0; x < 16; ++x) v[x] = ep[x];
      size_t base = (((size_t)b * outC + ocb + c) * H + ty0 + y) * (size_t)W + tx0;
      if (MODE == 1) {
#pragma unroll
        for (int j = 0; j < 4; ++j) {
          float4 sk = *(const float4*)(skip + base + 4 * j);
          float e0 = v[4*j+0] > 0.f ? v[4*j+0] : expm1f(v[4*j+0]);
          float e1 = v[4*j+1] > 0.f ? v[4*j+1] : expm1f(v[4*j+1]);
          float e2 = v[4*j+2] > 0.f ? v[4*j+2] : expm1f(v[4*j+2]);
          float e3 = v[4*j+3] > 0.f ? v[4*j+3] : expm1f(v[4*j+3]);
          v[4*j+0] = e0 + sk.x; v[4*j+1] = e1 + sk.y;
          v[4*j+2] = e2 + sk.z; v[4*j+3] = e3 + sk.w;
        }
      }
#pragma unroll
      for (int j = 0; j < 4; ++j)
        *(float4*)(out + base + 4 * j) = *(const float4*)(v + 4 * j);
    }
  }
}

// ---------- f32 tiled conv 3x3 (small convs + final) ----------
template<int CI, int CO>
__global__ __launch_bounds__(256) void k_conv3x3f(
    const float* __restrict__ in, const float* __restrict__ wr,
    const float* __restrict__ bias, float* __restrict__ out,
    int Cin, int H, int W, int wstride, int outC)
{
  const int ntx = W >> 4;
  const int tid = threadIdx.x;
  const int tx = tid & 15, ty = tid >> 4;
  const int tx0 = (blockIdx.x % ntx) << 4, ty0 = (blockIdx.x / ntx) << 4;
  const int b = blockIdx.z;

  __shared__ float sh[CI * 324];

  float acc[CO];
#pragma unroll
  for (int co = 0; co < CO; ++co) acc[co] = bias[co];

  const float* inb = in + (size_t)b * Cin * H * W;

  for (int cb = 0; cb < Cin; cb += CI) {
    __syncthreads();
    for (int e = tid; e < CI * 324; e += 256) {
      int ci = e / 324;
      int rr = e - ci * 324;
      int r = rr / 18, c = rr - r * 18;
      int gh = ty0 + r - 1, gw = tx0 + c - 1;
      float v = 0.f;
      if ((unsigned)gh < (unsigned)H && (unsigned)gw < (unsigned)W)
        v = inb[(size_t)(cb + ci) * H * W + (size_t)gh * W + gw];
      sh[e] = v;
    }
    __syncthreads();
#pragma unroll 1
    for (int ci = 0; ci < CI; ++ci) {
      float v[9];
      const float* sp = sh + ci * 324 + ty * 18 + tx;
#pragma unroll
      for (int kh = 0; kh < 3; ++kh)
#pragma unroll
        for (int kw = 0; kw < 3; ++kw)
          v[kh * 3 + kw] = sp[kh * 18 + kw];
      const float* wp = wr + (size_t)((cb + ci) * 9) * wstride;
#pragma unroll
      for (int k = 0; k < 9; ++k)
#pragma unroll
        for (int co = 0; co < CO; ++co)
          acc[co] = fmaf(wp[(size_t)k * wstride + co], v[k], acc[co]);
    }
  }
#pragma unroll
  for (int co = 0; co < CO; ++co)
    out[(((size_t)b * outC + co) * H + ty0 + ty) * W + tx0 + tx] = acc[co];
}

// ---------- max of 4 scan outputs -> f32 natural buffer ----------
// om1/om2 natural [p][y][x]; omT1/omT2 transposed [p][x][y].
__global__ __launch_bounds__(256) void k_max4(
    const _Float16* __restrict__ om1, const _Float16* __restrict__ om2,
    const _Float16* __restrict__ omT1, const _Float16* __restrict__ omT2,
    float* __restrict__ out)
{
  __shared__ float t[32][33];
  const int z = blockIdx.z;
  const int x0 = blockIdx.x * 32, y0 = blockIdx.y * 32;
  const int tx = threadIdx.x & 31, ty = threadIdx.x >> 5;  // 32x8
  const size_t ps = 65536;
  const size_t zb = (size_t)z * ps;
#pragma unroll
  for (int j = 0; j < 32; j += 8) {
    size_t p = zb + (size_t)(x0 + ty + j) * 256 + (y0 + tx);  // coalesced in omT
    t[ty + j][tx] = fmaxf((float)omT1[p], (float)omT2[p]);
  }
  __syncthreads();
#pragma unroll
  for (int j = 0; j < 32; j += 8) {
    size_t p = zb + (size_t)(y0 + ty + j) * 256 + (x0 + tx);  // coalesced natural
    float v = fmaxf((float)om1[p], (float)om2[p]);
    out[p] = fmaxf(v, t[tx][ty + j]);
  }
}

// ---------- conv 1x1 (f32) ----------
__global__ __launch_bounds__(256) void k_conv1x1(
    const float* __restrict__ in, const float* __restrict__ wgt,
    const float* __restrict__ bias, float* __restrict__ out,
    int Cin, int Cout, int H, int W)
{
  int hw = blockIdx.x * 256 + threadIdx.x;
  if (hw >= H * W) return;
  int co = blockIdx.y, b = blockIdx.z;
  const float* ip = in + (size_t)b * Cin * H * W + hw;
  const float* wp = wgt + (size_t)co * Cin;
  float acc = bias[co];
  for (int ci = 0; ci < Cin; ++ci) acc += wp[ci] * ip[(size_t)ci * H * W];
  out[((size_t)b * Cout + co) * H * W + hw] = acc;
}

// ---------- relu + maxpool 3x3 stride 2 pad 1 ----------
__global__ __launch_bounds__(256) void k_pool(
    const float* __restrict__ in, float* __restrict__ out, int C, int H, int W)
{
  int Ho = H >> 1, Wo = W >> 1;
  int hw = blockIdx.x * 256 + threadIdx.x;
  if (hw >= Ho * Wo) return;
  int ow = hw % Wo, oh = hw / Wo;
  int c = blockIdx.y, b = blockIdx.z;
  const float* p = in + ((size_t)(b * C + c) * H) * W;
  float m = 0.f;
#pragma unroll
  for (int dh = -1; dh <= 1; ++dh) {
    int ih = 2 * oh + dh;
    if ((unsigned)ih >= (unsigned)H) continue;
    const float* r = p + (size_t)ih * W;
#pragma unroll
    for (int dw = -1; dw <= 1; ++dw) {
      int iw = 2 * ow + dw;
      if ((unsigned)iw >= (unsigned)W) continue;
      m = fmaxf(m, r[iw]);
    }
  }
  out[((size_t)(b * C + c) * Ho + oh) * Wo + ow] = m;
}

// ---------- bilinear 2x upsample ----------
__global__ __launch_bounds__(256) void k_up2(
    const float* __restrict__ in, float* __restrict__ out, int C, int H, int W)
{
  int Ho = H * 2, Wo = W * 2;
  int hw = blockIdx.x * 256 + threadIdx.x;
  if (hw >= Ho * Wo) return;
  int ow = hw % Wo, oh = hw / Wo;
  int c = blockIdx.y, b = blockIdx.z;
  int ih = oh >> 1, iw = ow >> 1;
  int ih0, ih1, iw0, iw1; float fh0, fw0;
  if (oh & 1) { ih0 = ih; ih1 = min(ih + 1, H - 1); fh0 = 0.75f; }
  else        { ih0 = max(ih - 1, 0); ih1 = ih;     fh0 = 0.25f; }
  if (ow & 1) { iw0 = iw; iw1 = min(iw + 1, W - 1); fw0 = 0.75f; }
  else        { iw0 = max(iw - 1, 0); iw1 = iw;     fw0 = 0.25f; }
  const float* p = in + ((size_t)(b * C + c) * H) * W;
  float v = fh0 * (fw0 * p[(size_t)ih0 * W + iw0] + (1.f - fw0) * p[(size_t)ih0 * W + iw1])
          + (1.f - fh0) * (fw0 * p[(size_t)ih1 * W + iw0] + (1.f - fw0) * p[(size_t)ih1 * W + iw1]);
  out[((size_t)(b * C + c) * Ho + oh) * Wo + ow] = v;
}

// ---------- X f32 -> fp16 natural + fp16 transposed ----------
__global__ void k_xcvt(const float* __restrict__ in, _Float16* __restrict__ xn,
                       _Float16* __restrict__ xt)
{
  __shared__ _Float16 t[32][33];
  int z = blockIdx.z;
  int x0 = blockIdx.x * 32, y0 = blockIdx.y * 32;
  int tx = threadIdx.x, ty = threadIdx.y;
  const float* ip = in + (size_t)z * 65536;
#pragma unroll
  for (int j = 0; j < 32; j += 8) {
    float v = ip[(size_t)(y0 + ty + j) * 256 + x0 + tx];
    xn[(size_t)z * 65536 + (size_t)(y0 + ty + j) * 256 + x0 + tx] = (_Float16)v;
    t[ty + j][tx] = (_Float16)v;
  }
  __syncthreads();
#pragma unroll
  for (int j = 0; j < 32; j += 8)
    xt[(size_t)z * 65536 + (size_t)(x0 + ty + j) * 256 + y0 + tx] = t[tx][ty + j];
}

// ---------- gated scan core: chunk-contiguous lanes, 2 shuffles/step ----------
DEVINL void gl_lds16p(const void* g, void* lds) {
  __builtin_amdgcn_global_load_lds(
      (const __attribute__((address_space(1))) unsigned int*)g,
      (__attribute__((address_space(3))) unsigned int*)lds, 16, 0, 0);
}

template<int REV>
DEVINL void prop_core(const _Float16* xp, const _Float16* g1,
                      const _Float16* g2, const _Float16* g3,
                      _Float16* op, int S, int P, int lane,
                      _Float16* bx, _Float16* h1, _Float16* h2, _Float16* h3)
{
  float r0 = 0.f, r1 = 0.f, r2 = 0.f, r3 = 0.f;
  int cur = 0;

  auto stage = [&](int buf, int s0) {
#pragma unroll
    for (int v = 0; v < 8; ++v) {
      size_t ro = (size_t)(s0 + 2 * v) * P + lane * 8;
      gl_lds16p(xp + ro, bx + buf * 4096 + v * 512);
      gl_lds16p(g1 + ro, h1 + buf * 4096 + v * 512);
      gl_lds16p(g2 + ro, h2 + buf * 4096 + v * 512);
      gl_lds16p(g3 + ro, h3 + buf * 4096 + v * 512);
    }
  };

  stage(0, REV ? (S - 16) : 0);
  const int NT = S / 16;
  for (int t = 0; t < NT; ++t) {
    const int s0 = REV ? (S - 16 - t * 16) : (t * 16);
    asm volatile("s_waitcnt vmcnt(0)" ::: "memory");
    if (t + 1 < NT) stage(cur ^ 1, REV ? (s0 - 16) : (s0 + 16));

#pragma unroll
    for (int u = 0; u < 16; ++u) {
      const int e = REV ? (15 - u) : u;
      half4v xv = *(const half4v*)(bx + cur * 4096 + e * 256 + 4 * lane);
      half4v a1 = *(const half4v*)(h1 + cur * 4096 + e * 256 + 4 * lane);
      half4v a2 = *(const half4v*)(h2 + cur * 4096 + e * 256 + 4 * lane);
      half4v a3 = *(const half4v*)(h3 + cur * 4096 + e * 256 + 4 * lane);

      float hu0 = __shfl_up(r3, 1);
      float hd3 = __shfl_down(r0, 1);
      if (lane == 0)  hu0 = 0.f;
      if (lane == 63) hd3 = 0.f;

      float o0 = r0, o1 = r1, o2 = r2, o3v = r3;
      float x0 = xv[0], x1 = xv[1], x2 = xv[2], x3 = xv[3];
      float a10 = a1[0], a11 = a1[1], a12 = a1[2], a13 = a1[3];
      float a20 = a2[0], a21 = a2[1], a22 = a2[2], a23 = a2[3];
      float a30 = a3[0], a31 = a3[1], a32 = a3[2], a33 = a3[3];

      r0 = (1.f - a10 - a20 - a30) * x0 + a10 * hu0 + a20 * o0 + a30 * o1;
      r1 = (1.f - a11 - a21 - a31) * x1 + a11 * o0  + a21 * o1 + a31 * o2;
      r2 = (1.f - a12 - a22 - a32) * x2 + a12 * o1  + a22 * o2 + a32 * o3v;
      r3 = (1.f - a13 - a23 - a33) * x3 + a13 * o2  + a23 * o3v + a33 * hd3;

      half4v hv; hv[0] = (_Float16)r0; hv[1] = (_Float16)r1;
      hv[2] = (_Float16)r2; hv[3] = (_Float16)r3;
      *(half4v*)(op + (size_t)(s0 + e) * P + 4 * lane) = hv;
    }
    cur ^= 1;
  }
}

// dir = blockIdx.x>>7: 0 -> fwd (GA -> omA), 1 -> rev (GB -> omB).
__global__ __launch_bounds__(64) void k_prop_pair(
    const _Float16* __restrict__ Xh,
    const _Float16* __restrict__ GA, const _Float16* __restrict__ GB,
    _Float16* __restrict__ omA, _Float16* __restrict__ omB, int S, int P)
{
  const int dir = blockIdx.x >> 7;
  const int plane = blockIdx.x & 127;
  const int b = plane >> 5, c = plane & 31;
  const int lane = threadIdx.x;
  const size_t ps = (size_t)S * P;

  __shared__ __align__(16) _Float16 bx[2 * 4096];
  __shared__ __align__(16) _Float16 h1[2 * 4096];
  __shared__ __align__(16) _Float16 h2[2 * 4096];
  __shared__ __align__(16) _Float16 h3[2 * 4096];

  const _Float16* xp = Xh + (size_t)plane * ps;
  const _Float16* G = dir ? GB : GA;
  const _Float16* g1 = G + ((size_t)b * 96 + c) * ps;
  const _Float16* g2 = g1 + (size_t)32 * ps;
  const _Float16* g3 = g1 + (size_t)64 * ps;
  _Float16* op = (dir ? omB : omA) + (size_t)plane * ps;

  if (dir == 0) prop_core<0>(xp, g1, g2, g3, op, S, P, lane, bx, h1, h2, h3);
  else          prop_core<1>(xp, g1, g2, g3, op, S, P, lane, bx, h1, h2, h3);
}

// ---------------------------------------------------------------------------
extern "C" void kernel_launch(void* const* d_in, const int* in_sizes, int n_in,
                              void* d_out, int out_size, void* d_ws, size_t ws_size,
                              hipStream_t stream)
{
  const float* x   = (const float*)d_in[0];
  const float* rgb = (const float*)d_in[1];
  const float* mw  = (const float*)d_in[2];
  const float* mb  = (const float*)d_in[3];
  const float* c1w = (const float*)d_in[4];
  const float* c1b = (const float*)d_in[5];
  const float* c2w = (const float*)d_in[6];
  const float* c2b = (const float*)d_in[7];
  const float* c3w = (const float*)d_in[8];
  const float* c3b = (const float*)d_in[9];
  const float* c4w = (const float*)d_in[10];
  const float* c4b = (const float*)d_in[11];
  const float* d0w = (const float*)d_in[12];
  const float* d0b = (const float*)d_in[13];
  const float* d2w = (const float*)d_in[14];
  const float* d2b = (const float*)d_in[15];
  const float* d4w = (const float*)d_in[16];
  const float* d4b = (const float*)d_in[17];
  const float* d6w = (const float*)d_in[18];
  const float* d6b = (const float*)d_in[19];
  const float* d7w = (const float*)d_in[20];
  const float* d7b = (const float*)d_in[21];
  const float* pw  = (const float*)d_in[22];
  const float* pb  = (const float*)d_in[23];

  char* ws = (char*)d_ws;
  const size_t MB = 1024 * 1024;
  // Airtight layout (peak 194 MiB):
  _Float16* Xn16 = (_Float16*)(ws + 0);
  _Float16* Xt16 = (_Float16*)(ws + 16 * MB);
  float* X32f = (float*)(ws + 32 * MB);
  float* f1   = (float*)(ws + 64 * MB);
  float* f2   = (float*)(ws + 96 * MB);
  float* f3   = (float*)(ws + 112 * MB);
  float* p1   = (float*)(ws + 120 * MB);
  float* p2   = (float*)(ws + 128 * MB);
  float* p3   = (float*)(ws + 132 * MB);
  float* f4   = (float*)(ws + 134 * MB);
  float* o0   = (float*)(ws + 138 * MB);
  float* u0   = (float*)(ws + 140 * MB);
  float* o1   = (float*)(ws + 148 * MB);
  float* u1   = (float*)(ws + 32 * MB);
  float* o2   = (float*)(ws + 160 * MB);
  float* u2   = (float*)(ws + 96 * MB);
  float* o3   = (float*)(ws + 160 * MB);
  _Float16* gbufA = (_Float16*)(ws + 32 * MB);
  _Float16* gbufB = (_Float16*)(ws + 80 * MB);
  _Float16* om1  = (_Float16*)(ws + 128 * MB);
  _Float16* om2  = (_Float16*)(ws + 144 * MB);
  _Float16* omT1 = (_Float16*)(ws + 0);
  _Float16* omT2 = (_Float16*)(ws + 160 * MB);
  float* omfin = (float*)(ws + 32 * MB);   // over dead gbufA after scans
  char* wz = ws + 192 * MB;
  float* wmf  = (float*)wz;
  float* wc1f = wmf + 864;
  float* wpkf = wc1f + 864;
  _Float16* wc2p = (_Float16*)(wpkf + 864);
  _Float16* wc3p = wc2p + 19456;
  _Float16* wc4p = wc3p + 77824;
  _Float16* wd2p = wc4p + 311296;
  _Float16* wd4p = wd2p + 155648;
  _Float16* wd6p = wd4p + 77824;
  _Float16* wd7p = wd6p + 19456;

  // Determinism guard: zero all used workspace every call.
  hipMemsetAsync(d_ws, 0, 194 * MB, stream);

  dim3 blk(256);
  auto repf = [&](const float* s, float* d, int ci, int co) {
    int n = co * ci * 9;
    k_repack<<<dim3((n + 255) / 256), blk, 0, stream>>>(s, d, ci, co);
  };
  auto packh = [&](const float* s, _Float16* d, int ci, int co) {
    int n = co * (ci / 16) * 144;
    k_packwh<<<dim3((n + 255) / 256), blk, 0, stream>>>(s, d, ci, co);
  };
  repf(mw, wmf, 3, 32);
  repf(c1w, wc1f, 3, 32);
  repf(pw, wpkf, 32, 3);
  packh(c2w, wc2p, 32, 64);
  packh(c3w, wc3p, 64, 128);
  packh(c4w, wc4p, 128, 256);
  packh(d2w, wd2p, 128, 128);
  packh(d4w, wd4p, 128, 64);
  packh(d6w, wd6p, 64, 32);
  packh(d7w, wd7p, 32, 384);

  // Phase A
  k_conv3x3f<3, 32><<<dim3(256, 1, 4), blk, 0, stream>>>(x, wmf, mb, X32f, 3, 256, 256, 32, 32);
  k_xcvt<<<dim3(8, 8, 128), dim3(32, 8), 0, stream>>>(X32f, Xn16, Xt16);
  k_conv3x3f<3, 32><<<dim3(256, 1, 4), blk, 0, stream>>>(rgb, wc1f, c1b, f1, 3, 256, 256, 32, 32);

  // Phase B: encoder
  k_pool<<<dim3(64, 32, 4), blk, 0, stream>>>(f1, p1, 32, 256, 256);
  k_convh<4, 2, 2, 0, 0><<<dim3(128, 1, 4), dim3(256), 0, stream>>>(p1, wc2p, c2b, nullptr, f2, nullptr, 128, 128, 64, 0, 64, 0);
  k_pool<<<dim3(16, 64, 4), blk, 0, stream>>>(f2, p2, 64, 128, 128);
  k_convh<2, 2, 4, 0, 0><<<dim3(64, 2, 4), dim3(128), 0, stream>>>(p2, wc3p, c3b, nullptr, f3, nullptr, 64, 64, 128, 0, 128, 0);
  k_pool<<<dim3(4, 128, 4), blk, 0, stream>>>(f3, p3, 128, 64, 64);
  k_convh<2, 2, 8, 0, 0><<<dim3(16, 4, 4), dim3(128), 0, stream>>>(p3, wc4p, c4b, nullptr, f4, nullptr, 32, 32, 256, 0, 256, 0);
  k_conv1x1<<<dim3(4, 128, 4), blk, 0, stream>>>(f4, d0w, d0b, o0, 256, 128, 32, 32);

  // Phase C: decoder
  k_up2<<<dim3(16, 128, 4), blk, 0, stream>>>(o0, u0, 128, 32, 32);
  k_convh<2, 2, 8, 1, 0><<<dim3(64, 2, 4), dim3(128), 0, stream>>>(u0, wd2p, d2b, f3, o1, nullptr, 64, 64, 128, 0, 128, 0);
  k_up2<<<dim3(64, 128, 4), blk, 0, stream>>>(o1, u1, 128, 64, 64);
  k_convh<4, 2, 8, 1, 0><<<dim3(128, 1, 4), dim3(256), 0, stream>>>(u1, wd4p, d4b, f2, o2, nullptr, 128, 128, 64, 0, 64, 0);
  k_up2<<<dim3(256, 64, 4), blk, 0, stream>>>(o2, u2, 64, 128, 128);
  k_convh<4, 1, 4, 1, 0><<<dim3(512, 1, 4), dim3(256), 0, stream>>>(u2, wd6p, d6b, f1, o3, nullptr, 256, 256, 32, 0, 32, 0);

  // Phase D: vertical guide conv (k=2 -> gbufA, k=3 -> gbufB in one launch)
  k_convh<4, 3, 2, 0, 1><<<dim3(512, 2, 4), dim3(256), 0, stream>>>(o3, wd7p, d7b, nullptr, gbufA, gbufB, 256, 256, 384, 192, 96, 0);
  k_prop_pair<<<dim3(256), dim3(64), 0, stream>>>(Xn16, gbufA, gbufB, om1, om2, 256, 256);

  // Phase E: horizontal guide conv (k=0 -> gbufA, k=1 -> gbufB), pair scan
  k_convh<4, 3, 2, 2, 1><<<dim3(512, 2, 4), dim3(256), 0, stream>>>(o3, wd7p, d7b, nullptr, gbufA, gbufB, 256, 256, 384, 0, 96, 0);
  k_prop_pair<<<dim3(256), dim3(64), 0, stream>>>(Xt16, gbufA, gbufB, omT1, omT2, 256, 256);

  // Final: max of 4 buffers -> f32, then conv
  k_max4<<<dim3(8, 8, 128), blk, 0, stream>>>(om1, om2, omT1, omT2, omfin);
  k_conv3x3f<32, 3><<<dim3(256, 1, 4), blk, 0, stream>>>(omfin, wpkf, pb, (float*)d_out, 32, 256, 256, 3, 3);
}

// Round 14
// 914.255 us; speedup vs baseline: 13.8851x; 1.0017x over previous
//
#include <hip/hip_runtime.h>
#include <cstddef>
#include <cstdint>

#define DEVINL __device__ __forceinline__

typedef __attribute__((ext_vector_type(8))) _Float16 half8v;
typedef __attribute__((ext_vector_type(4))) _Float16 half4v;
typedef __attribute__((ext_vector_type(16))) float f32x16;

constexpr int cmax(int a, int b) { return a > b ? a : b; }

// ---------------------------------------------------------------------------
// SPN forward, MI355X gfx950. B=4, H=W=256, NF=32.
// Round 14: LDS bank-conflict fixes in k_convh (A-tile stride 24 halves ->
// 2-way max; vectorized epilogue LDS reads). Structure as round 13.
// ---------------------------------------------------------------------------

// ---------- f32 weight repack: OIHW -> [ci*9+k][Cout] (small convs) ----------
__global__ __launch_bounds__(256) void k_repack(
    const float* __restrict__ src, float* __restrict__ dst, int Cin, int Cout)
{
  int n = Cout * Cin * 9;
  int e = blockIdx.x * 256 + threadIdx.x;
  if (e >= n) return;
  int co = e / (Cin * 9);
  int r  = e - co * Cin * 9;
  int ci = r / 9;
  int k  = r - ci * 9;
  dst[(ci * 9 + k) * Cout + co] = src[e];
}

// ---------- fp16 weight pack: OIHW -> [cb][n][152], k = tap*16 + ci ----------
__global__ __launch_bounds__(256) void k_packwh(
    const float* __restrict__ src, _Float16* __restrict__ dst, int Cin, int Cout)
{
  int chunks = Cin >> 4;
  int total = Cout * chunks * 144;
  int e = blockIdx.x * 256 + threadIdx.x;
  if (e >= total) return;
  int n  = e / (chunks * 144);
  int r2 = e - n * chunks * 144;
  int cb = r2 / 144;
  int k  = r2 - cb * 144;
  int tap = k >> 4, ci = k & 15;
  float v = src[((size_t)n * Cin + cb * 16 + ci) * 9 + tap];
  dst[((size_t)cb * Cout + n) * 152 + k] = (_Float16)v;
}

// ---------- fp16 MFMA implicit-GEMM conv 3x3 pad 1, stage-once halo ----------
// A tile: pixel stride APS=24 halves (48B) -> 2-way LDS aliasing only.
// GATES=1: blockIdx.y selects direction half: nb = n0 + y*96, out = y? outv2 : outv.
template<int NWM, int NACC, int CHUNKS, int MODE, int GATES>
__global__ __launch_bounds__(NWM * 64) void k_convh(
    const float* __restrict__ in, const _Float16* __restrict__ wpk,
    const float* __restrict__ bias, const float* __restrict__ skip,
    void* __restrict__ outv, void* __restrict__ outv2,
    int H, int W, int wCout, int n0, int outC, int oco0)
{
  static_assert(GATES == 0 || NACC == 3, "GATES needs NACC==3");
  constexpr int NTHR = NWM * 64;
  constexpr int ROWS = NWM * 2;
  constexpr int RH = ROWS + 2;
  constexpr int N_BLK = NACC * 32;
  constexpr int MT = NWM * 32;
  constexpr int APS = 24;                       // A pixel stride (halves)
  constexpr int A_BYTES = RH * 18 * APS * 2;
  constexpr int B_BYTES = N_BLK * 152 * 2;
  constexpr int MPF = MT + 2;                   // f32 EP row stride (floats, 8B mult)
  constexpr int MPH = 132;                      // gates EP row stride (halves, 8B mult)
  constexpr int EP_BYTES = GATES ? (96 * MPH * 2) : (N_BLK * MPF * 4);
  constexpr int SMEM = cmax(A_BYTES + B_BYTES, EP_BYTES);

  const int tid = threadIdx.x;
  const int wave = tid >> 6, lane = tid & 63;
  const int wm = wave;
  const int tiles_x = W >> 4;
  const int tx0 = (blockIdx.x % tiles_x) << 4;
  const int ty0 = (blockIdx.x / tiles_x) * ROWS;
  const int b = blockIdx.z;
  const int nb = n0 + blockIdx.y * N_BLK;
  const int ocb = oco0 + blockIdx.y * N_BLK;

  __shared__ __align__(16) char smem[SMEM];
  _Float16* Ah = (_Float16*)smem;
  _Float16* Bh = (_Float16*)(smem + A_BYTES);

  f32x16 acc[NACC] = {};

  const size_t ps = (size_t)H * W;
  const float* inb = in + (size_t)b * (CHUNKS * 16) * ps;

  for (int cb = 0; cb < CHUNKS; ++cb) {
    __syncthreads();
    // ---- stage A: halo tile, 16 channels, padded pixel stride ----
    for (int e = tid; e < RH * 18; e += NTHR) {
      int r = e / 18, c = e - r * 18;
      int gy = ty0 + r - 1, gx = tx0 + c - 1;
      bool ok = (unsigned)gy < (unsigned)H && (unsigned)gx < (unsigned)W;
      const float* src = inb + (size_t)(cb * 16) * ps + (size_t)gy * W + gx;
      half8v v0, v1;
#pragma unroll
      for (int j = 0; j < 8; ++j)
        v0[j] = ok ? (_Float16)src[(size_t)j * ps] : (_Float16)0.f;
#pragma unroll
      for (int j = 0; j < 8; ++j)
        v1[j] = ok ? (_Float16)src[(size_t)(j + 8) * ps] : (_Float16)0.f;
      *(half8v*)&Ah[e * APS] = v0;
      *(half8v*)&Ah[e * APS + 8] = v1;
    }
    // ---- stage B (per chunk) ----
    {
      const _Float16* wsrc = wpk + ((size_t)cb * wCout + nb) * 152;
      for (int e = tid; e < N_BLK * 19; e += NTHR)
        *(uint4*)&Bh[e * 8] = *(const uint4*)(wsrc + e * 8);
    }
    __syncthreads();
    // ---- MFMA: 9 shifted tap-reads x NACC ----
    const int am = wm * 32 + (lane & 31);
    const int r0 = am >> 4, c0 = am & 15;
    const int kh = lane >> 5;
    const _Float16* Ab = Ah + kh * 8;
    const _Float16* Bb = Bh + kh * 8;
#pragma unroll
    for (int ks = 0; ks < 9; ++ks) {
      const int dy = ks / 3, dx = ks - dy * 3;
      half8v af = *(const half8v*)(Ab + ((r0 + dy) * 18 + (c0 + dx)) * APS);
#pragma unroll
      for (int na = 0; na < NACC; ++na) {
        const int bn = na * 32 + (lane & 31);
        half8v bf = *(const half8v*)(Bb + bn * 152 + ks * 16);
        acc[na] = __builtin_amdgcn_mfma_f32_32x32x16_f16(af, bf, acc[na], 0, 0, 0);
      }
    }
  }

  __syncthreads();

  if (GATES) {
    _Float16* EPH = (_Float16*)smem;
    const int c = lane & 31;
    const float bv0 = bias[nb + c];
    const float bv1 = bias[nb + 32 + c];
    const float bv2 = bias[nb + 64 + c];
#pragma unroll
    for (int i = 0; i < 16; ++i) {
      int m = wm * 32 + (i & 3) + 8 * (i >> 2) + 4 * (lane >> 5);
      float g1 = acc[0][i] + bv0;
      float g2 = acc[GATES ? 1 : 0][i] + bv1;
      float g3 = acc[GATES ? 2 : 0][i] + bv2;
      float s = fabsf(g1) + fabsf(g2) + fabsf(g3);
      if (s >= 1.f) { float r = 1.f / s; g1 *= r; g2 *= r; g3 *= r; }
      EPH[(size_t)(0 * 32 + c) * MPH + m] = (_Float16)g1;
      EPH[(size_t)(1 * 32 + c) * MPH + m] = (_Float16)g2;
      EPH[(size_t)(2 * 32 + c) * MPH + m] = (_Float16)g3;
    }
    __syncthreads();
    _Float16* outh = (_Float16*)(blockIdx.y ? outv2 : outv);
    if (MODE == 2) {
      const int TOT = 96 * 16;
      for (int r = tid; r < TOT; r += NTHR) {
        int gc = r >> 4, x = r & 15;
        const _Float16* ep = EPH + (size_t)gc * MPH + x;
        _Float16 v[8];
#pragma unroll
        for (int y = 0; y < 8; ++y) v[y] = ep[y * 16];
        size_t base = ((size_t)(b * 96 + gc) * W + tx0 + x) * (size_t)H + ty0;
        *(uint4*)(outh + base) = *(const uint4*)v;
      }
    } else {
      const int TOT = 96 * ROWS;
      for (int r = tid; r < TOT; r += NTHR) {
        int gc = r / ROWS, y = r - gc * ROWS;
        const uint2* ep = (const uint2*)(EPH + (size_t)gc * MPH + y * 16);
        uint2 v0 = ep[0], v1 = ep[1], v2 = ep[2], v3 = ep[3];
        size_t base = ((size_t)(b * 96 + gc) * H + ty0 + y) * (size_t)W + tx0;
        *(uint2*)(outh + base + 0)  = v0;
        *(uint2*)(outh + base + 4)  = v1;
        *(uint2*)(outh + base + 8)  = v2;
        *(uint2*)(outh + base + 12) = v3;
      }
    }
  } else {
    float* EP = (float*)smem;
    float bv[NACC];
#pragma unroll
    for (int na = 0; na < NACC; ++na) bv[na] = bias[nb + na * 32 + (lane & 31)];
#pragma unroll
    for (int na = 0; na < NACC; ++na) {
      const int c = na * 32 + (lane & 31);
#pragma unroll
      for (int i = 0; i < 16; ++i) {
        int m = wm * 32 + (i & 3) + 8 * (i >> 2) + 4 * (lane >> 5);
        EP[(size_t)c * MPF + m] = acc[na][i] + bv[na];
      }
    }
    __syncthreads();
    float* out = (float*)outv;
    const int TOT = N_BLK * ROWS;
    for (int r = tid; r < TOT; r += NTHR) {
      int c = r / ROWS, y = r - c * ROWS;
      const float2* ep = (const float2*)(EP + (size_t)c * MPF + y * 16);
      float v[16];
#pragma unroll
      for (int j = 0; j < 8; ++j) {
        float2 t = ep[j];
        v[2 * j] = t.x; v[2 * j + 1] = t.y;
      }
      size_t base = (((size_t)b * outC + ocb + c) * H + ty0 + y) * (size_t)W + tx0;
      if (MODE == 1) {
#pragma unroll
        for (int j = 0; j < 4; ++j) {
          float4 sk = *(const float4*)(skip + base + 4 * j);
          float e0 = v[4*j+0] > 0.f ? v[4*j+0] : expm1f(v[4*j+0]);
          float e1 = v[4*j+1] > 0.f ? v[4*j+1] : expm1f(v[4*j+1]);
          float e2 = v[4*j+2] > 0.f ? v[4*j+2] : expm1f(v[4*j+2]);
          float e3 = v[4*j+3] > 0.f ? v[4*j+3] : expm1f(v[4*j+3]);
          v[4*j+0] = e0 + sk.x; v[4*j+1] = e1 + sk.y;
          v[4*j+2] = e2 + sk.z; v[4*j+3] = e3 + sk.w;
        }
      }
#pragma unroll
      for (int j = 0; j < 4; ++j)
        *(float4*)(out + base + 4 * j) = *(const float4*)(v + 4 * j);
    }
  }
}

// ---------- f32 tiled conv 3x3 (small convs + final) ----------
template<int CI, int CO>
__global__ __launch_bounds__(256) void k_conv3x3f(
    const float* __restrict__ in, const float* __restrict__ wr,
    const float* __restrict__ bias, float* __restrict__ out,
    int Cin, int H, int W, int wstride, int outC)
{
  const int ntx = W >> 4;
  const int tid = threadIdx.x;
  const int tx = tid & 15, ty = tid >> 4;
  const int tx0 = (blockIdx.x % ntx) << 4, ty0 = (blockIdx.x / ntx) << 4;
  const int b = blockIdx.z;

  __shared__ float sh[CI * 324];

  float acc[CO];
#pragma unroll
  for (int co = 0; co < CO; ++co) acc[co] = bias[co];

  const float* inb = in + (size_t)b * Cin * H * W;

  for (int cb = 0; cb < Cin; cb += CI) {
    __syncthreads();
    for (int e = tid; e < CI * 324; e += 256) {
      int ci = e / 324;
      int rr = e - ci * 324;
      int r = rr / 18, c = rr - r * 18;
      int gh = ty0 + r - 1, gw = tx0 + c - 1;
      float v = 0.f;
      if ((unsigned)gh < (unsigned)H && (unsigned)gw < (unsigned)W)
        v = inb[(size_t)(cb + ci) * H * W + (size_t)gh * W + gw];
      sh[e] = v;
    }
    __syncthreads();
#pragma unroll 1
    for (int ci = 0; ci < CI; ++ci) {
      float v[9];
      const float* sp = sh + ci * 324 + ty * 18 + tx;
#pragma unroll
      for (int kh = 0; kh < 3; ++kh)
#pragma unroll
        for (int kw = 0; kw < 3; ++kw)
          v[kh * 3 + kw] = sp[kh * 18 + kw];
      const float* wp = wr + (size_t)((cb + ci) * 9) * wstride;
#pragma unroll
      for (int k = 0; k < 9; ++k)
#pragma unroll
        for (int co = 0; co < CO; ++co)
          acc[co] = fmaf(wp[(size_t)k * wstride + co], v[k], acc[co]);
    }
  }
#pragma unroll
  for (int co = 0; co < CO; ++co)
    out[(((size_t)b * outC + co) * H + ty0 + ty) * W + tx0 + tx] = acc[co];
}

// ---------- max of 4 scan outputs -> f32 natural buffer ----------
__global__ __launch_bounds__(256) void k_max4(
    const _Float16* __restrict__ om1, const _Float16* __restrict__ om2,
    const _Float16* __restrict__ omT1, const _Float16* __restrict__ omT2,
    float* __restrict__ out)
{
  __shared__ float t[32][33];
  const int z = blockIdx.z;
  const int x0 = blockIdx.x * 32, y0 = blockIdx.y * 32;
  const int tx = threadIdx.x & 31, ty = threadIdx.x >> 5;
  const size_t ps = 65536;
  const size_t zb = (size_t)z * ps;
#pragma unroll
  for (int j = 0; j < 32; j += 8) {
    size_t p = zb + (size_t)(x0 + ty + j) * 256 + (y0 + tx);
    t[ty + j][tx] = fmaxf((float)omT1[p], (float)omT2[p]);
  }
  __syncthreads();
#pragma unroll
  for (int j = 0; j < 32; j += 8) {
    size_t p = zb + (size_t)(y0 + ty + j) * 256 + (x0 + tx);
    float v = fmaxf((float)om1[p], (float)om2[p]);
    out[p] = fmaxf(v, t[tx][ty + j]);
  }
}

// ---------- conv 1x1 (f32) ----------
__global__ __launch_bounds__(256) void k_conv1x1(
    const float* __restrict__ in, const float* __restrict__ wgt,
    const float* __restrict__ bias, float* __restrict__ out,
    int Cin, int Cout, int H, int W)
{
  int hw = blockIdx.x * 256 + threadIdx.x;
  if (hw >= H * W) return;
  int co = blockIdx.y, b = blockIdx.z;
  const float* ip = in + (size_t)b * Cin * H * W + hw;
  const float* wp = wgt + (size_t)co * Cin;
  float acc = bias[co];
  for (int ci = 0; ci < Cin; ++ci) acc += wp[ci] * ip[(size_t)ci * H * W];
  out[((size_t)b * Cout + co) * H * W + hw] = acc;
}

// ---------- relu + maxpool 3x3 stride 2 pad 1 ----------
__global__ __launch_bounds__(256) void k_pool(
    const float* __restrict__ in, float* __restrict__ out, int C, int H, int W)
{
  int Ho = H >> 1, Wo = W >> 1;
  int hw = blockIdx.x * 256 + threadIdx.x;
  if (hw >= Ho * Wo) return;
  int ow = hw % Wo, oh = hw / Wo;
  int c = blockIdx.y, b = blockIdx.z;
  const float* p = in + ((size_t)(b * C + c) * H) * W;
  float m = 0.f;
#pragma unroll
  for (int dh = -1; dh <= 1; ++dh) {
    int ih = 2 * oh + dh;
    if ((unsigned)ih >= (unsigned)H) continue;
    const float* r = p + (size_t)ih * W;
#pragma unroll
    for (int dw = -1; dw <= 1; ++dw) {
      int iw = 2 * ow + dw;
      if ((unsigned)iw >= (unsigned)W) continue;
      m = fmaxf(m, r[iw]);
    }
  }
  out[((size_t)(b * C + c) * Ho + oh) * Wo + ow] = m;
}

// ---------- bilinear 2x upsample ----------
__global__ __launch_bounds__(256) void k_up2(
    const float* __restrict__ in, float* __restrict__ out, int C, int H, int W)
{
  int Ho = H * 2, Wo = W * 2;
  int hw = blockIdx.x * 256 + threadIdx.x;
  if (hw >= Ho * Wo) return;
  int ow = hw % Wo, oh = hw / Wo;
  int c = blockIdx.y, b = blockIdx.z;
  int ih = oh >> 1, iw = ow >> 1;
  int ih0, ih1, iw0, iw1; float fh0, fw0;
  if (oh & 1) { ih0 = ih; ih1 = min(ih + 1, H - 1); fh0 = 0.75f; }
  else        { ih0 = max(ih - 1, 0); ih1 = ih;     fh0 = 0.25f; }
  if (ow & 1) { iw0 = iw; iw1 = min(iw + 1, W - 1); fw0 = 0.75f; }
  else        { iw0 = max(iw - 1, 0); iw1 = iw;     fw0 = 0.25f; }
  const float* p = in + ((size_t)(b * C + c) * H) * W;
  float v = fh0 * (fw0 * p[(size_t)ih0 * W + iw0] + (1.f - fw0) * p[(size_t)ih0 * W + iw1])
          + (1.f - fh0) * (fw0 * p[(size_t)ih1 * W + iw0] + (1.f - fw0) * p[(size_t)ih1 * W + iw1]);
  out[((size_t)(b * C + c) * Ho + oh) * Wo + ow] = v;
}

// ---------- X f32 -> fp16 natural + fp16 transposed ----------
__global__ void k_xcvt(const float* __restrict__ in, _Float16* __restrict__ xn,
                       _Float16* __restrict__ xt)
{
  __shared__ _Float16 t[32][33];
  int z = blockIdx.z;
  int x0 = blockIdx.x * 32, y0 = blockIdx.y * 32;
  int tx = threadIdx.x, ty = threadIdx.y;
  const float* ip = in + (size_t)z * 65536;
#pragma unroll
  for (int j = 0; j < 32; j += 8) {
    float v = ip[(size_t)(y0 + ty + j) * 256 + x0 + tx];
    xn[(size_t)z * 65536 + (size_t)(y0 + ty + j) * 256 + x0 + tx] = (_Float16)v;
    t[ty + j][tx] = (_Float16)v;
  }
  __syncthreads();
#pragma unroll
  for (int j = 0; j < 32; j += 8)
    xt[(size_t)z * 65536 + (size_t)(x0 + ty + j) * 256 + y0 + tx] = t[tx][ty + j];
}

// ---------- gated scan core: chunk-contiguous lanes, 2 shuffles/step ----------
DEVINL void gl_lds16p(const void* g, void* lds) {
  __builtin_amdgcn_global_load_lds(
      (const __attribute__((address_space(1))) unsigned int*)g,
      (__attribute__((address_space(3))) unsigned int*)lds, 16, 0, 0);
}

template<int REV>
DEVINL void prop_core(const _Float16* xp, const _Float16* g1,
                      const _Float16* g2, const _Float16* g3,
                      _Float16* op, int S, int P, int lane,
                      _Float16* bx, _Float16* h1, _Float16* h2, _Float16* h3)
{
  float r0 = 0.f, r1 = 0.f, r2 = 0.f, r3 = 0.f;
  int cur = 0;

  auto stage = [&](int buf, int s0) {
#pragma unroll
    for (int v = 0; v < 8; ++v) {
      size_t ro = (size_t)(s0 + 2 * v) * P + lane * 8;
      gl_lds16p(xp + ro, bx + buf * 4096 + v * 512);
      gl_lds16p(g1 + ro, h1 + buf * 4096 + v * 512);
      gl_lds16p(g2 + ro, h2 + buf * 4096 + v * 512);
      gl_lds16p(g3 + ro, h3 + buf * 4096 + v * 512);
    }
  };

  stage(0, REV ? (S - 16) : 0);
  const int NT = S / 16;
  for (int t = 0; t < NT; ++t) {
    const int s0 = REV ? (S - 16 - t * 16) : (t * 16);
    asm volatile("s_waitcnt vmcnt(0)" ::: "memory");
    if (t + 1 < NT) stage(cur ^ 1, REV ? (s0 - 16) : (s0 + 16));

#pragma unroll
    for (int u = 0; u < 16; ++u) {
      const int e = REV ? (15 - u) : u;
      half4v xv = *(const half4v*)(bx + cur * 4096 + e * 256 + 4 * lane);
      half4v a1 = *(const half4v*)(h1 + cur * 4096 + e * 256 + 4 * lane);
      half4v a2 = *(const half4v*)(h2 + cur * 4096 + e * 256 + 4 * lane);
      half4v a3 = *(const half4v*)(h3 + cur * 4096 + e * 256 + 4 * lane);

      float hu0 = __shfl_up(r3, 1);
      float hd3 = __shfl_down(r0, 1);
      if (lane == 0)  hu0 = 0.f;
      if (lane == 63) hd3 = 0.f;

      float o0 = r0, o1 = r1, o2 = r2, o3v = r3;
      float x0 = xv[0], x1 = xv[1], x2 = xv[2], x3 = xv[3];
      float a10 = a1[0], a11 = a1[1], a12 = a1[2], a13 = a1[3];
      float a20 = a2[0], a21 = a2[1], a22 = a2[2], a23 = a2[3];
      float a30 = a3[0], a31 = a3[1], a32 = a3[2], a33 = a3[3];

      r0 = (1.f - a10 - a20 - a30) * x0 + a10 * hu0 + a20 * o0 + a30 * o1;
      r1 = (1.f - a11 - a21 - a31) * x1 + a11 * o0  + a21 * o1 + a31 * o2;
      r2 = (1.f - a12 - a22 - a32) * x2 + a12 * o1  + a22 * o2 + a32 * o3v;
      r3 = (1.f - a13 - a23 - a33) * x3 + a13 * o2  + a23 * o3v + a33 * hd3;

      half4v hv; hv[0] = (_Float16)r0; hv[1] = (_Float16)r1;
      hv[2] = (_Float16)r2; hv[3] = (_Float16)r3;
      *(half4v*)(op + (size_t)(s0 + e) * P + 4 * lane) = hv;
    }
    cur ^= 1;
  }
}

// dir = blockIdx.x>>7: 0 -> fwd (GA -> omA), 1 -> rev (GB -> omB).
__global__ __launch_bounds__(64) void k_prop_pair(
    const _Float16* __restrict__ Xh,
    const _Float16* __restrict__ GA, const _Float16* __restrict__ GB,
    _Float16* __restrict__ omA, _Float16* __restrict__ omB, int S, int P)
{
  const int dir = blockIdx.x >> 7;
  const int plane = blockIdx.x & 127;
  const int b = plane >> 5, c = plane & 31;
  const int lane = threadIdx.x;
  const size_t ps = (size_t)S * P;

  __shared__ __align__(16) _Float16 bx[2 * 4096];
  __shared__ __align__(16) _Float16 h1[2 * 4096];
  __shared__ __align__(16) _Float16 h2[2 * 4096];
  __shared__ __align__(16) _Float16 h3[2 * 4096];

  const _Float16* xp = Xh + (size_t)plane * ps;
  const _Float16* G = dir ? GB : GA;
  const _Float16* g1 = G + ((size_t)b * 96 + c) * ps;
  const _Float16* g2 = g1 + (size_t)32 * ps;
  const _Float16* g3 = g1 + (size_t)64 * ps;
  _Float16* op = (dir ? omB : omA) + (size_t)plane * ps;

  if (dir == 0) prop_core<0>(xp, g1, g2, g3, op, S, P, lane, bx, h1, h2, h3);
  else          prop_core<1>(xp, g1, g2, g3, op, S, P, lane, bx, h1, h2, h3);
}

// ---------------------------------------------------------------------------
extern "C" void kernel_launch(void* const* d_in, const int* in_sizes, int n_in,
                              void* d_out, int out_size, void* d_ws, size_t ws_size,
                              hipStream_t stream)
{
  const float* x   = (const float*)d_in[0];
  const float* rgb = (const float*)d_in[1];
  const float* mw  = (const float*)d_in[2];
  const float* mb  = (const float*)d_in[3];
  const float* c1w = (const float*)d_in[4];
  const float* c1b = (const float*)d_in[5];
  const float* c2w = (const float*)d_in[6];
  const float* c2b = (const float*)d_in[7];
  const float* c3w = (const float*)d_in[8];
  const float* c3b = (const float*)d_in[9];
  const float* c4w = (const float*)d_in[10];
  const float* c4b = (const float*)d_in[11];
  const float* d0w = (const float*)d_in[12];
  const float* d0b = (const float*)d_in[13];
  const float* d2w = (const float*)d_in[14];
  const float* d2b = (const float*)d_in[15];
  const float* d4w = (const float*)d_in[16];
  const float* d4b = (const float*)d_in[17];
  const float* d6w = (const float*)d_in[18];
  const float* d6b = (const float*)d_in[19];
  const float* d7w = (const float*)d_in[20];
  const float* d7b = (const float*)d_in[21];
  const float* pw  = (const float*)d_in[22];
  const float* pb  = (const float*)d_in[23];

  char* ws = (char*)d_ws;
  const size_t MB = 1024 * 1024;
  // Airtight layout (peak 194 MiB):
  _Float16* Xn16 = (_Float16*)(ws + 0);
  _Float16* Xt16 = (_Float16*)(ws + 16 * MB);
  float* X32f = (float*)(ws + 32 * MB);
  float* f1   = (float*)(ws + 64 * MB);
  float* f2   = (float*)(ws + 96 * MB);
  float* f3   = (float*)(ws + 112 * MB);
  float* p1   = (float*)(ws + 120 * MB);
  float* p2   = (float*)(ws + 128 * MB);
  float* p3   = (float*)(ws + 132 * MB);
  float* f4   = (float*)(ws + 134 * MB);
  float* o0   = (float*)(ws + 138 * MB);
  float* u0   = (float*)(ws + 140 * MB);
  float* o1   = (float*)(ws + 148 * MB);
  float* u1   = (float*)(ws + 32 * MB);
  float* o2   = (float*)(ws + 160 * MB);
  float* u2   = (float*)(ws + 96 * MB);
  float* o3   = (float*)(ws + 160 * MB);
  _Float16* gbufA = (_Float16*)(ws + 32 * MB);
  _Float16* gbufB = (_Float16*)(ws + 80 * MB);
  _Float16* om1  = (_Float16*)(ws + 128 * MB);
  _Float16* om2  = (_Float16*)(ws + 144 * MB);
  _Float16* omT1 = (_Float16*)(ws + 0);
  _Float16* omT2 = (_Float16*)(ws + 160 * MB);
  float* omfin = (float*)(ws + 32 * MB);
  char* wz = ws + 192 * MB;
  float* wmf  = (float*)wz;
  float* wc1f = wmf + 864;
  float* wpkf = wc1f + 864;
  _Float16* wc2p = (_Float16*)(wpkf + 864);
  _Float16* wc3p = wc2p + 19456;
  _Float16* wc4p = wc3p + 77824;
  _Float16* wd2p = wc4p + 311296;
  _Float16* wd4p = wd2p + 155648;
  _Float16* wd6p = wd4p + 77824;
  _Float16* wd7p = wd6p + 19456;

  // Determinism guard: zero all used workspace every call.
  hipMemsetAsync(d_ws, 0, 194 * MB, stream);

  dim3 blk(256);
  auto repf = [&](const float* s, float* d, int ci, int co) {
    int n = co * ci * 9;
    k_repack<<<dim3((n + 255) / 256), blk, 0, stream>>>(s, d, ci, co);
  };
  auto packh = [&](const float* s, _Float16* d, int ci, int co) {
    int n = co * (ci / 16) * 144;
    k_packwh<<<dim3((n + 255) / 256), blk, 0, stream>>>(s, d, ci, co);
  };
  repf(mw, wmf, 3, 32);
  repf(c1w, wc1f, 3, 32);
  repf(pw, wpkf, 32, 3);
  packh(c2w, wc2p, 32, 64);
  packh(c3w, wc3p, 64, 128);
  packh(c4w, wc4p, 128, 256);
  packh(d2w, wd2p, 128, 128);
  packh(d4w, wd4p, 128, 64);
  packh(d6w, wd6p, 64, 32);
  packh(d7w, wd7p, 32, 384);

  // Phase A
  k_conv3x3f<3, 32><<<dim3(256, 1, 4), blk, 0, stream>>>(x, wmf, mb, X32f, 3, 256, 256, 32, 32);
  k_xcvt<<<dim3(8, 8, 128), dim3(32, 8), 0, stream>>>(X32f, Xn16, Xt16);
  k_conv3x3f<3, 32><<<dim3(256, 1, 4), blk, 0, stream>>>(rgb, wc1f, c1b, f1, 3, 256, 256, 32, 32);

  // Phase B: encoder
  k_pool<<<dim3(64, 32, 4), blk, 0, stream>>>(f1, p1, 32, 256, 256);
  k_convh<4, 2, 2, 0, 0><<<dim3(128, 1, 4), dim3(256), 0, stream>>>(p1, wc2p, c2b, nullptr, f2, nullptr, 128, 128, 64, 0, 64, 0);
  k_pool<<<dim3(16, 64, 4), blk, 0, stream>>>(f2, p2, 64, 128, 128);
  k_convh<2, 2, 4, 0, 0><<<dim3(64, 2, 4), dim3(128), 0, stream>>>(p2, wc3p, c3b, nullptr, f3, nullptr, 64, 64, 128, 0, 128, 0);
  k_pool<<<dim3(4, 128, 4), blk, 0, stream>>>(f3, p3, 128, 64, 64);
  k_convh<2, 2, 8, 0, 0><<<dim3(16, 4, 4), dim3(128), 0, stream>>>(p3, wc4p, c4b, nullptr, f4, nullptr, 32, 32, 256, 0, 256, 0);
  k_conv1x1<<<dim3(4, 128, 4), blk, 0, stream>>>(f4, d0w, d0b, o0, 256, 128, 32, 32);

  // Phase C: decoder
  k_up2<<<dim3(16, 128, 4), blk, 0, stream>>>(o0, u0, 128, 32, 32);
  k_convh<2, 2, 8, 1, 0><<<dim3(64, 2, 4), dim3(128), 0, stream>>>(u0, wd2p, d2b, f3, o1, nullptr, 64, 64, 128, 0, 128, 0);
  k_up2<<<dim3(64, 128, 4), blk, 0, stream>>>(o1, u1, 128, 64, 64);
  k_convh<4, 2, 8, 1, 0><<<dim3(128, 1, 4), dim3(256), 0, stream>>>(u1, wd4p, d4b, f2, o2, nullptr, 128, 128, 64, 0, 64, 0);
  k_up2<<<dim3(256, 64, 4), blk, 0, stream>>>(o2, u2, 64, 128, 128);
  k_convh<4, 1, 4, 1, 0><<<dim3(512, 1, 4), dim3(256), 0, stream>>>(u2, wd6p, d6b, f1, o3, nullptr, 256, 256, 32, 0, 32, 0);

  // Phase D: vertical guide conv (k=2 -> gbufA, k=3 -> gbufB), pair scan
  k_convh<4, 3, 2, 0, 1><<<dim3(512, 2, 4), dim3(256), 0, stream>>>(o3, wd7p, d7b, nullptr, gbufA, gbufB, 256, 256, 384, 192, 96, 0);
  k_prop_pair<<<dim3(256), dim3(64), 0, stream>>>(Xn16, gbufA, gbufB, om1, om2, 256, 256);

  // Phase E: horizontal guide conv (k=0 -> gbufA, k=1 -> gbufB), pair scan
  k_convh<4, 3, 2, 2, 1><<<dim3(512, 2, 4), dim3(256), 0, stream>>>(o3, wd7p, d7b, nullptr, gbufA, gbufB, 256, 256, 384, 0, 96, 0);
  k_prop_pair<<<dim3(256), dim3(64), 0, stream>>>(Xt16, gbufA, gbufB, omT1, omT2, 256, 256);

  // Final: max of 4 buffers -> f32, then conv
  k_max4<<<dim3(8, 8, 128), blk, 0, stream>>>(om1, om2, omT1, omT2, omfin);
  k_conv3x3f<32, 3><<<dim3(256, 1, 4), blk, 0, stream>>>(omfin, wpkf, pb, (float*)d_out, 32, 256, 256, 3, 3);
}